// Round 4
// baseline (5803.473 us; speedup 1.0000x reference)
//
#include <hip/hip_runtime.h>

// Problem dims
constexpr int VOC  = 50005;
constexpr int VOCP = 50048;   // 391*128, padded vocab
constexpr int NTM  = 391;     // vocab tiles (128) for big GEMMs
constexpr int NTMP = 400;     // padded partial stride
constexpr int KSN  = 8784;    // KNOW-1
constexpr int KSNP = 8832;    // 69*128
constexpr float NPAD = 41221.0f;

typedef unsigned short u16;
typedef __attribute__((ext_vector_type(4))) float f32x4;
typedef __attribute__((ext_vector_type(8))) short bf16x8;

__device__ __forceinline__ float dot4(float4 a, float4 b) {
    return a.x*b.x + a.y*b.y + a.z*b.z + a.w*b.w;
}
__device__ __forceinline__ float sigmoidf_(float x) { return 1.0f / (1.0f + expf(-x)); }
__device__ __forceinline__ u16 f2bf(float f) {
    unsigned x = __float_as_uint(f);
    return (u16)((x + 0x7FFFu + ((x >> 16) & 1u)) >> 16);
}
__device__ __forceinline__ float bf2f(u16 u) { return __uint_as_float(((unsigned)u) << 16); }
__device__ __forceinline__ void gload_lds16(const void* g, void* l) {
    __builtin_amdgcn_global_load_lds((const __attribute__((address_space(1))) unsigned int*)g,
                                     (__attribute__((address_space(3))) unsigned int*)l, 16, 0, 0);
}

// ---------------------------------------------------------------- cvt fp32 -> bf16 (strided)
__global__ __launch_bounds__(256) void k_cvt(const float* __restrict__ src, u16* __restrict__ dst,
                                             int ncols, int sld, int dld) {
    int row = blockIdx.x;
    int c = (blockIdx.y * 256 + threadIdx.x) * 4;
    if (c >= ncols) return;
    float4 v = *(const float4*)(src + (size_t)row * sld + c);
    unsigned lo = f2bf(v.x) | ((unsigned)f2bf(v.y) << 16);
    unsigned hi = f2bf(v.z) | ((unsigned)f2bf(v.w) << 16);
    *(uint2*)(dst + (size_t)row * dld + c) = make_uint2(lo, hi);
}

// zero pad rows 50005..50047 of Aemb / A34 / Awk
__global__ __launch_bounds__(256) void k_pad0(u16* __restrict__ Aemb, u16* __restrict__ A34,
                                              u16* __restrict__ Awk) {
    int r = VOC + blockIdx.x;
    unsigned* pe = (unsigned*)(Aemb + (size_t)r * 512);
    if (threadIdx.x < 256) pe[threadIdx.x] = 0;
    unsigned* p3 = (unsigned*)(A34 + (size_t)r * 1536);
    for (int i = threadIdx.x; i < 768; i += 256) p3[i] = 0;
    unsigned* pw = (unsigned*)(Awk + (size_t)r * 2048);
    for (int i = threadIdx.x; i < 1024; i += 256) pw[i] = 0;
}
// zero pad rows 8784..8831 of kvwb
__global__ __launch_bounds__(256) void k_padK(u16* __restrict__ kvwb) {
    int r = KSN + blockIdx.x;
    unsigned* p = (unsigned*)(kvwb + (size_t)r * 1024);
    for (int i = threadIdx.x; i < 512; i += 256) p[i] = 0;
}

// build Bsk [128][2048] bf16: rows 0..31 = [ses|know], rows 32..127 = 0
__global__ __launch_bounds__(256) void k_bsk(const float* __restrict__ ses,
                                             const float* __restrict__ know,
                                             u16* __restrict__ Bsk) {
    int row = blockIdx.x;
    for (int c0 = threadIdx.x * 4; c0 < 2048; c0 += 1024) {
        uint2 val = make_uint2(0, 0);
        if (row < 32) {
            const float* srcp = (c0 < 1024) ? ses + (size_t)row * 1024 + c0
                                            : know + (size_t)row * 1024 + (c0 - 1024);
            float4 v = *(const float4*)srcp;
            val = make_uint2(f2bf(v.x) | ((unsigned)f2bf(v.y) << 16),
                             f2bf(v.z) | ((unsigned)f2bf(v.w) << 16));
        }
        *(uint2*)(Bsk + (size_t)row * 2048 + c0) = val;
    }
}

// transpose Whh [3072][1024] -> WhhT [1024][3072]
__global__ __launch_bounds__(256) void k_tr(const float* __restrict__ src, float* __restrict__ dst) {
    __shared__ float t[32][33];
    int r0 = blockIdx.x * 32, c0 = blockIdx.y * 32;
    int tr = threadIdx.x & 31, tc = threadIdx.x >> 5;
    for (int i = 0; i < 32; i += 8)
        t[tc + i][tr] = src[(size_t)(r0 + tc + i) * 1024 + c0 + tr];
    __syncthreads();
    for (int i = 0; i < 32; i += 8)
        dst[(size_t)(c0 + tc + i) * 3072 + r0 + tr] = t[tr][tc + i];
}

// ---------------------------------------------------------------- gather target embeddings -> BG[:,1024:1536] bf16
__global__ __launch_bounds__(128) void k_gather(const float* __restrict__ embed,
                                                const int* __restrict__ target,
                                                u16* __restrict__ BG) {
    int n = blockIdx.x;
    int row = target[n];
    int c = threadIdx.x * 4;
    float4 v = *(const float4*)(embed + (size_t)row * 512 + c);
    unsigned lo = f2bf(v.x) | ((unsigned)f2bf(v.y) << 16);
    unsigned hi = f2bf(v.z) | ((unsigned)f2bf(v.w) << 16);
    *(uint2*)(BG + (size_t)n * 1536 + 1024 + c) = make_uint2(lo, hi);
}

// ------------------------------------------------- h0 + ses_inf_vec (fp32, small)
__global__ __launch_bounds__(256) void k_h0_sesinf(const float* __restrict__ ses,
                                                   const float* __restrict__ sdw,
                                                   const float* __restrict__ sdb,
                                                   const float* __restrict__ siw,
                                                   float* __restrict__ h0,
                                                   float* __restrict__ sesinf) {
    int g = blockIdx.x * 256 + threadIdx.x;
    int b = g & 31;
    int jg = g >> 5;
    int j0 = jg * 4;
    const float4* s4 = (const float4*)(ses + (size_t)b * 1024);
    const float4* wa[4];
    const float4* wc[4];
#pragma unroll
    for (int r = 0; r < 4; ++r) {
        wa[r] = (const float4*)(sdw + (size_t)(j0 + r) * 1024);
        wc[r] = (const float4*)(siw + (size_t)(j0 + r) * 1024);
    }
    float a[4] = {0, 0, 0, 0}, c[4] = {0, 0, 0, 0};
    for (int kq = 0; kq < 256; ++kq) {
        float4 sv = s4[kq];
#pragma unroll
        for (int r = 0; r < 4; ++r) { a[r] += dot4(sv, wa[r][kq]); c[r] += dot4(sv, wc[r][kq]); }
    }
#pragma unroll
    for (int r = 0; r < 4; ++r) {
        h0[b * 1024 + j0 + r] = tanhf(a[r] + sdb[j0 + r]);
        sesinf[b * 1024 + j0 + r] = c[r];
    }
}

// ------------------------------------------------- lse of padded know scores
__global__ __launch_bounds__(256) void k_lseknow(const float* __restrict__ ks,
                                                 float* __restrict__ lsek) {
    int b = blockIdx.x;
    int t = threadIdx.x;
    __shared__ float sm[256];
    float m = -1e30f;
    for (int j = t; j < KSN; j += 256) m = fmaxf(m, ks[(size_t)b * KSN + j]);
    sm[t] = m;
    __syncthreads();
    for (int s = 128; s > 0; s >>= 1) { if (t < s) sm[t] = fmaxf(sm[t], sm[t + s]); __syncthreads(); }
    m = fmaxf(sm[0], 0.0f);
    __syncthreads();
    float s = 0.0f;
    for (int j = t; j < KSN; j += 256) s += expf(ks[(size_t)b * KSN + j] - m);
    sm[t] = s;
    __syncthreads();
    for (int r = 128; r > 0; r >>= 1) { if (t < r) sm[t] += sm[t + r]; __syncthreads(); }
    if (t == 0) lsek[b] = m + logf(sm[0] + NPAD * expf(0.0f - m));
}

// ================================================= templated bf16 MFMA GEMM (C[m][n] = A[m]·B[n])
// EPI 0: GI (+bias, fp32)  EPI 1: MX maxout  EPI 2: gate (u8)  EPI 3: logits+partials
// EPI 4: gc fp32 [b][VOCP] (n<32)  EPI 5: ks fp32 [b][KSN] (n<32, m<KSN)
template<int EPI>
__global__ __launch_bounds__(256) void gemm_bt(
    const u16* __restrict__ A, int lda,
    const u16* __restrict__ B, int ldb, int K,
    const float* __restrict__ p0, const float* __restrict__ p1,
    float* __restrict__ q0, u16* __restrict__ q1,
    unsigned char* __restrict__ q2, float* __restrict__ q3)
{
    __shared__ u16 Asm[128 * 64];
    __shared__ u16 Bsm[128 * 64];
    const int tid = threadIdx.x;
    const int lane = tid & 63;
    const int w = tid >> 6;
    const int wm = w >> 1, wn = w & 1;
    const int nt = blockIdx.x, mt = blockIdx.y;

    f32x4 acc[4][4];
#pragma unroll
    for (int i = 0; i < 4; ++i)
#pragma unroll
        for (int j = 0; j < 4; ++j) acc[i][j] = (f32x4){0.f, 0.f, 0.f, 0.f};

    for (int kt = 0; kt < K; kt += 64) {
#pragma unroll
        for (int p = 0; p < 4; ++p) {
            int flat = (w * 4 + p) * 64 + lane;       // 0..1023 16B-slots
            int row = flat >> 3, slot = flat & 7;
            int ss = slot ^ (row & 7);                // inverse-swizzled source slot
            gload_lds16(A + (size_t)(mt * 128 + row) * lda + kt + ss * 8, Asm + flat * 8);
            gload_lds16(B + (size_t)(nt * 128 + row) * ldb + kt + ss * 8, Bsm + flat * 8);
        }
        __syncthreads();
#pragma unroll
        for (int kc = 0; kc < 2; ++kc) {
            bf16x8 af[4], bfr[4];
#pragma unroll
            for (int mi = 0; mi < 4; ++mi) {
                int row = wm * 64 + mi * 16 + (lane & 15);
                int bcol = kc * 64 + ((lane >> 4) << 4);
                af[mi] = *(const bf16x8*)((const char*)Asm + row * 128 + (bcol ^ ((row & 7) << 4)));
            }
#pragma unroll
            for (int ni = 0; ni < 4; ++ni) {
                int row = wn * 64 + ni * 16 + (lane & 15);
                int bcol = kc * 64 + ((lane >> 4) << 4);
                bfr[ni] = *(const bf16x8*)((const char*)Bsm + row * 128 + (bcol ^ ((row & 7) << 4)));
            }
#pragma unroll
            for (int mi = 0; mi < 4; ++mi)
#pragma unroll
                for (int ni = 0; ni < 4; ++ni)
                    acc[mi][ni] = __builtin_amdgcn_mfma_f32_16x16x32_bf16(af[mi], bfr[ni], acc[mi][ni], 0, 0, 0);
        }
        __syncthreads();
    }

    const int cl = lane & 15;           // n offset within fragment
    const int rg = (lane >> 4) << 2;    // m base within fragment

    if constexpr (EPI == 0) {           // GI = TE@Wih.T + bih  (fp32 [n][3072])
#pragma unroll
        for (int mi = 0; mi < 4; ++mi) {
            int m0 = mt * 128 + wm * 64 + mi * 16 + rg;
            float4 bias = *(const float4*)(p0 + m0);
#pragma unroll
            for (int ni = 0; ni < 4; ++ni) {
                int n = nt * 128 + wn * 64 + ni * 16 + cl;
                float4 v;
                v.x = acc[mi][ni][0] + bias.x; v.y = acc[mi][ni][1] + bias.y;
                v.z = acc[mi][ni][2] + bias.z; v.w = acc[mi][ni][3] + bias.w;
                *(float4*)(q0 + (size_t)n * 3072 + m0) = v;
            }
        }
    }
    if constexpr (EPI == 1) {           // maxout -> BL bf16 [n][512]
#pragma unroll
        for (int mi = 0; mi < 4; ++mi) {
            int m0 = mt * 128 + wm * 64 + mi * 16 + rg;
            float4 eb4 = *(const float4*)(p1 + m0);
#pragma unroll
            for (int ni = 0; ni < 4; ++ni) {
                int n = nt * 128 + wn * 64 + ni * 16 + cl;
                int b = n >> 6;
                float v0 = acc[mi][ni][0] + p0[b * 1024 + m0 + 0] + eb4.x;
                float v1 = acc[mi][ni][1] + p0[b * 1024 + m0 + 1] + eb4.y;
                float v2 = acc[mi][ni][2] + p0[b * 1024 + m0 + 2] + eb4.z;
                float v3 = acc[mi][ni][3] + p0[b * 1024 + m0 + 3] + eb4.w;
                unsigned pk = f2bf(fmaxf(v0, v1)) | ((unsigned)f2bf(fmaxf(v2, v3)) << 16);
                *(unsigned*)(q1 + (size_t)n * 512 + (m0 >> 1)) = pk;
            }
        }
    }
    if constexpr (EPI == 2) {           // gate -> g8 u8 [n][VOCP]
#pragma unroll
        for (int mi = 0; mi < 4; ++mi) {
            int v0 = mt * 128 + wm * 64 + mi * 16 + rg;
#pragma unroll
            for (int ni = 0; ni < 4; ++ni) {
                int n = nt * 128 + wn * 64 + ni * 16 + cl;
                int b = n >> 6;
                float4 gcv = *(const float4*)(p0 + (size_t)b * VOCP + v0);
                unsigned pk = 0;
#pragma unroll
                for (int r = 0; r < 4; ++r) {
                    float garg = acc[mi][ni][r] + ((const float*)&gcv)[r];
                    float gate = 1.0f / (1.0f + expf(-garg));
                    pk |= ((unsigned)(int)(gate * 255.0f + 0.5f)) << (8 * r);
                }
                *(unsigned*)(q2 + (size_t)n * VOCP + v0) = pk;
            }
        }
    }
    if constexpr (EPI == 3) {           // logits -> Lb bf16 [n][VOCP] + partial max/sumexp
        __shared__ float redm[2][128];
        __shared__ float reds[2][128];
#pragma unroll
        for (int mi = 0; mi < 4; ++mi) {
            int v0 = mt * 128 + wm * 64 + mi * 16 + rg;
#pragma unroll
            for (int ni = 0; ni < 4; ++ni) {
                int n = nt * 128 + wn * 64 + ni * 16 + cl;
                unsigned lo = f2bf(acc[mi][ni][0]) | ((unsigned)f2bf(acc[mi][ni][1]) << 16);
                unsigned hi = f2bf(acc[mi][ni][2]) | ((unsigned)f2bf(acc[mi][ni][3]) << 16);
                *(uint2*)(q1 + (size_t)n * VOCP + v0) = make_uint2(lo, hi);
            }
        }
#pragma unroll
        for (int ni = 0; ni < 4; ++ni) {
            float lm = -1e30f;
#pragma unroll
            for (int mi = 0; mi < 4; ++mi) {
                int v0 = mt * 128 + wm * 64 + mi * 16 + rg;
#pragma unroll
                for (int r = 0; r < 4; ++r)
                    if (v0 + r < VOC) lm = fmaxf(lm, acc[mi][ni][r]);
            }
            lm = fmaxf(lm, __shfl_xor(lm, 16));
            lm = fmaxf(lm, __shfl_xor(lm, 32));
            float s = 0.0f;
#pragma unroll
            for (int mi = 0; mi < 4; ++mi) {
                int v0 = mt * 128 + wm * 64 + mi * 16 + rg;
#pragma unroll
                for (int r = 0; r < 4; ++r)
                    if (v0 + r < VOC) s += expf(acc[mi][ni][r] - lm);
            }
            s += __shfl_xor(s, 16);
            s += __shfl_xor(s, 32);
            if (lane < 16) {
                redm[wm][wn * 64 + ni * 16 + lane] = lm;
                reds[wm][wn * 64 + ni * 16 + lane] = s;
            }
        }
        __syncthreads();
        if (tid < 128) {
            float m0_ = redm[0][tid], m1_ = redm[1][tid];
            float m = fmaxf(m0_, m1_);
            float s = reds[0][tid] * expf(m0_ - m) + reds[1][tid] * expf(m1_ - m);
            int n = nt * 128 + tid;
            q0[(size_t)n * NTMP + mt] = m;
            q3[(size_t)n * NTMP + mt] = s;
        }
    }
    if constexpr (EPI == 4) {           // gc fp32 [b][VOCP], only n<32 valid
#pragma unroll
        for (int mi = 0; mi < 4; ++mi) {
            int m0 = mt * 128 + wm * 64 + mi * 16 + rg;
#pragma unroll
            for (int ni = 0; ni < 4; ++ni) {
                int n = nt * 128 + wn * 64 + ni * 16 + cl;
                if (n < 32) {
                    float4 v;
                    v.x = acc[mi][ni][0]; v.y = acc[mi][ni][1];
                    v.z = acc[mi][ni][2]; v.w = acc[mi][ni][3];
                    *(float4*)(q0 + (size_t)n * VOCP + m0) = v;
                }
            }
        }
    }
    if constexpr (EPI == 5) {           // ks fp32 [b][KSN], n<32, m<KSN
#pragma unroll
        for (int mi = 0; mi < 4; ++mi) {
            int m0 = mt * 128 + wm * 64 + mi * 16 + rg;
#pragma unroll
            for (int ni = 0; ni < 4; ++ni) {
                int n = nt * 128 + wn * 64 + ni * 16 + cl;
                if (n < 32 && m0 < KSN) {
                    float4 v;
                    v.x = acc[mi][ni][0]; v.y = acc[mi][ni][1];
                    v.z = acc[mi][ni][2]; v.w = acc[mi][ni][3];
                    *(float4*)(q0 + (size_t)n * KSN + m0) = v;
                }
            }
        }
    }
}

// ------------------------------------------------- persistent GRU: all 64 steps, one dispatch
// 128 blocks x 256 threads, guaranteed co-resident (<= 256 CUs). Manual grid barrier
// between steps (agent-scope atomic + threadfence, standard grid.sync pattern).
// Block: 32 j-lanes x 8 batches; bid swizzled so the 4 batch-groups sharing a
// WhhT j-slice land on the same XCD (consecutive-ID round-robin assumption; perf-only).
__global__ __launch_bounds__(256, 2) void k_gru_p(const float* __restrict__ WhhT,
                                                  const float* __restrict__ GI,
                                                  const float* __restrict__ bhh,
                                                  const float* __restrict__ h0,
                                                  float* __restrict__ Hall,
                                                  unsigned* __restrict__ cnt) {
    __shared__ float hl[8][1032];
    const int bid = blockIdx.x;
    const int jb = (bid & 7) * 4 + ((bid >> 3) & 3);  // 0..31
    const int bg = bid >> 5;                           // 0..3
    const int tid = threadIdx.x;
    const int jl = tid & 31, bq = tid >> 5;
    const int j = jb * 32 + jl;
    const int b = bg * 8 + bq;
    const float bh0 = bhh[j], bh1 = bhh[1024 + j], bh2 = bhh[2048 + j];
    const float* wj = WhhT + j;

    for (int t = 0; t < 64; ++t) {
        // stage h_prev rows [bg*8, bg*8+8) into LDS
#pragma unroll
        for (int p = 0; p < 8; ++p) {
            int id = tid + p * 256;          // 0..2047 float4-slots
            int row = id >> 8, c4 = (id & 255) * 4;
            const float* hp = (t == 0) ? h0 + (size_t)(bg * 8 + row) * 1024
                                       : Hall + ((size_t)(bg * 8 + row) * 64 + t - 1) * 1024;
            *(float4*)&hl[row][c4] = *(const float4*)(hp + c4);
        }
        __syncthreads();
        const float* hrow = hl[bq];
        float ar = 0.f, az = 0.f, an = 0.f;
#pragma unroll 8
        for (int k = 0; k < 1024; ++k) {
            float h = hrow[k];
            const float* wk = wj + (size_t)k * 3072;
            ar += wk[0] * h;
            az += wk[1024] * h;
            an += wk[2048] * h;
        }
        int n = b * 64 + t;
        const float* gi = GI + (size_t)n * 3072 + j;
        float r = sigmoidf_(gi[0] + ar + bh0);
        float z = sigmoidf_(gi[1024] + az + bh1);
        float nn = tanhf(gi[2048] + r * (an + bh2));
        float hnew = (1.0f - z) * nn + z * hrow[j];
        Hall[(size_t)n * 1024 + j] = hnew;

        if (t < 63) {
            __threadfence();                 // release: make h stores agent-visible
            __syncthreads();
            if (tid == 0) {
                __hip_atomic_fetch_add(cnt, 1u, __ATOMIC_ACQ_REL, __HIP_MEMORY_SCOPE_AGENT);
                unsigned target = 128u * (unsigned)(t + 1);
                while (__hip_atomic_load(cnt, __ATOMIC_ACQUIRE, __HIP_MEMORY_SCOPE_AGENT) < target)
                    __builtin_amdgcn_s_sleep(2);
            }
            __syncthreads();
            __threadfence();                 // acquire: invalidate before reading others' h
        } else {
            __syncthreads();
        }
    }
}

// ------------------------------------------------- per-row lse from partials
__global__ __launch_bounds__(256) void k_lse(const float* __restrict__ pmax,
                                             const float* __restrict__ psum,
                                             float* __restrict__ lse) {
    int n = blockIdx.x;
    int t = threadIdx.x;
    __shared__ float sm[256];
    const float* pm = pmax + (size_t)n * NTMP;
    const float* ps = psum + (size_t)n * NTMP;
    float m = -1e30f;
    for (int p = t; p < NTM; p += 256) m = fmaxf(m, pm[p]);
    sm[t] = m;
    __syncthreads();
    for (int s = 128; s > 0; s >>= 1) { if (t < s) sm[t] = fmaxf(sm[t], sm[t + s]); __syncthreads(); }
    m = sm[0];
    __syncthreads();
    float s = 0.0f;
    for (int p = t; p < NTM; p += 256) s += ps[p] * expf(pm[p] - m);
    sm[t] = s;
    __syncthreads();
    for (int r = 128; r > 0; r >>= 1) { if (t < r) sm[t] += sm[t + r]; __syncthreads(); }
    if (t == 0) lse[n] = m + logf(sm[0]);
}

// ------------------------------------------------- final combine (fully coalesced)
__global__ __launch_bounds__(256) void k_final(const u16* __restrict__ Lb,
                                               const unsigned char* __restrict__ g8,
                                               const float* __restrict__ lse,
                                               const float* __restrict__ ks,
                                               const float* __restrict__ lsek,
                                               float* __restrict__ out) {
    int n = blockIdx.y;
    int b = n >> 6;
    float lsen = lse[n], lkb = lsek[b];
    int base = blockIdx.x * 2048;
#pragma unroll
    for (int i = 0; i < 8; ++i) {
        int v = base + i * 256 + threadIdx.x;
        if (v < VOC) {
            float L = bf2f(Lb[(size_t)n * VOCP + v]);
            float g = g8[(size_t)n * VOCP + v] * (1.0f / 255.0f);
            float kp = ((v >= 10 && v < 10 + KSN) ? ks[(size_t)b * KSN + (v - 10)] : 0.0f) - lkb;
            out[(size_t)n * VOC + v] = g * (L - lsen) + (1.0f - g) * kp;
        }
    }
}

// ---------------------------------------------------------------- launch
extern "C" void kernel_launch(void* const* d_in, const int* in_sizes, int n_in,
                              void* d_out, int out_size, void* d_ws, size_t ws_size,
                              hipStream_t stream) {
    const float* ses    = (const float*)d_in[0];
    const float* know   = (const float*)d_in[1];
    const int*   target = (const int*)d_in[2];
    const float* embed  = (const float*)d_in[3];
    const float* Wih    = (const float*)d_in[4];
    const float* Whh    = (const float*)d_in[5];
    const float* bih    = (const float*)d_in[6];
    const float* bhh    = (const float*)d_in[7];
    const float* sdw    = (const float*)d_in[8];
    const float* sdb    = (const float*)d_in[9];
    const float* dw     = (const float*)d_in[10];
    const float* siw    = (const float*)d_in[11];
    const float* ew     = (const float*)d_in[12];
    const float* eb     = (const float*)d_in[13];
    const float* W1     = (const float*)d_in[14];
    const float* W2     = (const float*)d_in[15];
    const float* W3     = (const float*)d_in[16];
    const float* W4     = (const float*)d_in[17];
    const float* kvw    = (const float*)d_in[18];

    char* ws = (char*)d_ws;
    size_t o = 0;
    auto alloc = [&](size_t bytes) { char* r = ws + o; o += (bytes + 255) & ~(size_t)255; return r; };
    u16*   Aemb  = (u16*)  alloc((size_t)VOCP * 512 * 2);
    u16*   A34   = (u16*)  alloc((size_t)VOCP * 1536 * 2);
    u16*   Adwew = (u16*)  alloc((size_t)1024 * 1536 * 2);
    u16*   Wihb  = (u16*)  alloc((size_t)3072 * 512 * 2);
    u16*   BG    = (u16*)  alloc((size_t)2048 * 1536 * 2);
    u16*   BL    = (u16*)  alloc((size_t)2048 * 512 * 2);
    float* GI    = (float*)alloc((size_t)2048 * 3072 * 4);
    float* Hall  = (float*)alloc((size_t)2048 * 1024 * 4);
    float* WhhT  = (float*)alloc((size_t)1024 * 3072 * 4);
    float* h0    = (float*)alloc((size_t)32 * 1024 * 4);
    float* sesinf= (float*)alloc((size_t)32 * 1024 * 4);
    float* gc    = (float*)alloc((size_t)32 * VOCP * 4);
    float* ksb   = (float*)alloc((size_t)32 * KSN * 4);
    float* lsek  = (float*)alloc(256);
    float* lse   = (float*)alloc((size_t)2048 * 4);
    unsigned* cnt= (unsigned*)alloc(256);
    float* pmax  = (float*)alloc((size_t)2048 * NTMP * 4);
    float* psum  = (float*)alloc((size_t)2048 * NTMP * 4);
    unsigned char* g8 = (unsigned char*)alloc((size_t)2048 * VOCP);   // aliased: kvwb
    u16*   Lb    = (u16*)  alloc((size_t)2048 * VOCP * 2);            // aliased: Awk
    u16*   Bsk   = (u16*)  alloc((size_t)128 * 2048 * 2);
    float* out = (float*)d_out;

    u16*   kvwb  = (u16*)g8;       // 8832*1024*2 = 18.1 MB <= g8 (102 MB)
    u16*   Awk   = Lb;             // 50048*2048*2 == Lb size

    hipMemsetAsync(cnt, 0, 4, stream);

    // weight conversions (early users of aliased buffers come first)
    k_cvt<<<dim3(VOC, 1), 256, 0, stream>>>(embed, Aemb, 512, 512, 512);
    k_cvt<<<dim3(VOC, 1), 256, 0, stream>>>(W3, A34, 1024, 1024, 1536);
    k_cvt<<<dim3(VOC, 1), 256, 0, stream>>>(W4, A34 + 1024, 512, 512, 1536);
    k_cvt<<<dim3(VOC, 1), 256, 0, stream>>>(W1, Awk, 1024, 1024, 2048);
    k_cvt<<<dim3(VOC, 1), 256, 0, stream>>>(W2, Awk + 1024, 1024, 1024, 2048);
    k_cvt<<<dim3(KSN, 1), 256, 0, stream>>>(kvw, kvwb, 1024, 1024, 1024);
    k_pad0<<<dim3(VOCP - VOC), 256, 0, stream>>>(Aemb, A34, Awk);
    k_padK<<<dim3(KSNP - KSN), 256, 0, stream>>>(kvwb);
    k_cvt<<<dim3(1024, 1), 256, 0, stream>>>(dw, Adwew, 1024, 1024, 1536);
    k_cvt<<<dim3(1024, 1), 256, 0, stream>>>(ew, Adwew + 1024, 512, 512, 1536);
    k_cvt<<<dim3(3072, 1), 256, 0, stream>>>(Wih, Wihb, 512, 512, 512);
    k_bsk<<<dim3(128), 256, 0, stream>>>(ses, know, Bsk);
    k_tr<<<dim3(96, 32), 256, 0, stream>>>(Whh, WhhT);

    k_gather<<<dim3(2048), 128, 0, stream>>>(embed, target, BG);
    k_h0_sesinf<<<dim3(32), 256, 0, stream>>>(ses, sdw, sdb, siw, h0, sesinf);

    // gc = [W1|W2] @ [ses|know]   (MFMA, n<32 valid)
    gemm_bt<4><<<dim3(1, NTM), 256, 0, stream>>>(Awk, 2048, Bsk, 2048, 2048,
                                                 nullptr, nullptr, gc, nullptr, nullptr, nullptr);
    // ks = kvw @ know   (MFMA, B = know half of Bsk)
    gemm_bt<5><<<dim3(1, 69), 256, 0, stream>>>(kvwb, 1024, Bsk + 1024, 2048, 1024,
                                                nullptr, nullptr, ksb, nullptr, nullptr, nullptr);
    k_lseknow<<<dim3(32), 256, 0, stream>>>(ksb, lsek);

    // GI = TE @ Wih.T + bih
    gemm_bt<0><<<dim3(16, 24), 256, 0, stream>>>(Wihb, 512, BG + 1024, 1536, 512,
                                                 bih, nullptr, GI, nullptr, nullptr, nullptr);
    // GRU recurrence: one persistent kernel, 64 steps with internal grid barriers
    k_gru_p<<<dim3(128), 256, 0, stream>>>(WhhT, GI, bhh, h0, Hall, cnt);
    // Hall -> BG[:,0:1024] bf16
    k_cvt<<<dim3(2048, 1), 256, 0, stream>>>(Hall, BG, 1024, 1024, 1536);
    // MX (maxout) -> BL
    gemm_bt<1><<<dim3(16, 8), 256, 0, stream>>>(Adwew, 1536, BG, 1536, 1536,
                                                sesinf, eb, nullptr, BL, nullptr, nullptr);
    // gate GEMM -> g8
    gemm_bt<2><<<dim3(16, NTM), 256, 0, stream>>>(A34, 1536, BG, 1536, 1536,
                                                  gc, nullptr, nullptr, nullptr, g8, nullptr);
    // logit GEMM -> Lb + partials
    gemm_bt<3><<<dim3(16, NTM), 256, 0, stream>>>(Aemb, 512, BL, 512, 512,
                                                  nullptr, nullptr, pmax, Lb, nullptr, psum);
    k_lse<<<dim3(2048), 256, 0, stream>>>(pmax, psum, lse);
    k_final<<<dim3(25, 2048), 256, 0, stream>>>(Lb, g8, lse, ksb, lsek, out);
}

// Round 5
// 2474.848 us; speedup vs baseline: 2.3450x; 2.3450x over previous
//
#include <hip/hip_runtime.h>

// Problem dims
constexpr int VOC  = 50005;
constexpr int VOCP = 50048;   // 391*128, padded vocab
constexpr int NTM  = 391;     // vocab tiles (128) for big GEMMs
constexpr int NTMP = 400;     // padded partial stride
constexpr int KSN  = 8784;    // KNOW-1
constexpr int KSNP = 8832;    // 69*128
constexpr float NPAD = 41221.0f;

typedef unsigned short u16;
typedef __attribute__((ext_vector_type(4))) float f32x4;
typedef __attribute__((ext_vector_type(8))) short bf16x8;

__device__ __forceinline__ float dot4(float4 a, float4 b) {
    return a.x*b.x + a.y*b.y + a.z*b.z + a.w*b.w;
}
__device__ __forceinline__ float sigmoidf_(float x) { return 1.0f / (1.0f + expf(-x)); }
__device__ __forceinline__ u16 f2bf(float f) {
    unsigned x = __float_as_uint(f);
    return (u16)((x + 0x7FFFu + ((x >> 16) & 1u)) >> 16);
}
__device__ __forceinline__ float bf2f(u16 u) { return __uint_as_float(((unsigned)u) << 16); }
__device__ __forceinline__ void gload_lds16(const void* g, void* l) {
    __builtin_amdgcn_global_load_lds((const __attribute__((address_space(1))) unsigned int*)g,
                                     (__attribute__((address_space(3))) unsigned int*)l, 16, 0, 0);
}

// ---------------------------------------------------------------- cvt fp32 -> bf16 (strided)
__global__ __launch_bounds__(256) void k_cvt(const float* __restrict__ src, u16* __restrict__ dst,
                                             int ncols, int sld, int dld) {
    int row = blockIdx.x;
    int c = (blockIdx.y * 256 + threadIdx.x) * 4;
    if (c >= ncols) return;
    float4 v = *(const float4*)(src + (size_t)row * sld + c);
    unsigned lo = f2bf(v.x) | ((unsigned)f2bf(v.y) << 16);
    unsigned hi = f2bf(v.z) | ((unsigned)f2bf(v.w) << 16);
    *(uint2*)(dst + (size_t)row * dld + c) = make_uint2(lo, hi);
}

// zero pad rows 50005..50047 of Aemb / A34 / Awk
__global__ __launch_bounds__(256) void k_pad0(u16* __restrict__ Aemb, u16* __restrict__ A34,
                                              u16* __restrict__ Awk) {
    int r = VOC + blockIdx.x;
    unsigned* pe = (unsigned*)(Aemb + (size_t)r * 512);
    if (threadIdx.x < 256) pe[threadIdx.x] = 0;
    unsigned* p3 = (unsigned*)(A34 + (size_t)r * 1536);
    for (int i = threadIdx.x; i < 768; i += 256) p3[i] = 0;
    unsigned* pw = (unsigned*)(Awk + (size_t)r * 2048);
    for (int i = threadIdx.x; i < 1024; i += 256) pw[i] = 0;
}
// zero pad rows 8784..8831 of kvwb
__global__ __launch_bounds__(256) void k_padK(u16* __restrict__ kvwb) {
    int r = KSN + blockIdx.x;
    unsigned* p = (unsigned*)(kvwb + (size_t)r * 1024);
    for (int i = threadIdx.x; i < 512; i += 256) p[i] = 0;
}

// build Bsk [128][2048] bf16: rows 0..31 = [ses|know], rows 32..127 = 0
__global__ __launch_bounds__(256) void k_bsk(const float* __restrict__ ses,
                                             const float* __restrict__ know,
                                             u16* __restrict__ Bsk) {
    int row = blockIdx.x;
    for (int c0 = threadIdx.x * 4; c0 < 2048; c0 += 1024) {
        uint2 val = make_uint2(0, 0);
        if (row < 32) {
            const float* srcp = (c0 < 1024) ? ses + (size_t)row * 1024 + c0
                                            : know + (size_t)row * 1024 + (c0 - 1024);
            float4 v = *(const float4*)srcp;
            val = make_uint2(f2bf(v.x) | ((unsigned)f2bf(v.y) << 16),
                             f2bf(v.z) | ((unsigned)f2bf(v.w) << 16));
        }
        *(uint2*)(Bsk + (size_t)row * 2048 + c0) = val;
    }
}

// ---------------------------------------------------------------- gather target embeddings -> BG[:,1024:1536] bf16
__global__ __launch_bounds__(128) void k_gather(const float* __restrict__ embed,
                                                const int* __restrict__ target,
                                                u16* __restrict__ BG) {
    int n = blockIdx.x;
    int row = target[n];
    int c = threadIdx.x * 4;
    float4 v = *(const float4*)(embed + (size_t)row * 512 + c);
    unsigned lo = f2bf(v.x) | ((unsigned)f2bf(v.y) << 16);
    unsigned hi = f2bf(v.z) | ((unsigned)f2bf(v.w) << 16);
    *(uint2*)(BG + (size_t)n * 1536 + 1024 + c) = make_uint2(lo, hi);
}

// ------------------------------------------------- h0 + ses_inf_vec (fp32, small)
__global__ __launch_bounds__(256) void k_h0_sesinf(const float* __restrict__ ses,
                                                   const float* __restrict__ sdw,
                                                   const float* __restrict__ sdb,
                                                   const float* __restrict__ siw,
                                                   float* __restrict__ h0,
                                                   float* __restrict__ sesinf) {
    int g = blockIdx.x * 256 + threadIdx.x;
    int b = g & 31;
    int jg = g >> 5;
    int j0 = jg * 4;
    const float4* s4 = (const float4*)(ses + (size_t)b * 1024);
    const float4* wa[4];
    const float4* wc[4];
#pragma unroll
    for (int r = 0; r < 4; ++r) {
        wa[r] = (const float4*)(sdw + (size_t)(j0 + r) * 1024);
        wc[r] = (const float4*)(siw + (size_t)(j0 + r) * 1024);
    }
    float a[4] = {0, 0, 0, 0}, c[4] = {0, 0, 0, 0};
    for (int kq = 0; kq < 256; ++kq) {
        float4 sv = s4[kq];
#pragma unroll
        for (int r = 0; r < 4; ++r) { a[r] += dot4(sv, wa[r][kq]); c[r] += dot4(sv, wc[r][kq]); }
    }
#pragma unroll
    for (int r = 0; r < 4; ++r) {
        h0[b * 1024 + j0 + r] = tanhf(a[r] + sdb[j0 + r]);
        sesinf[b * 1024 + j0 + r] = c[r];
    }
}

// ------------------------------------------------- lse of padded know scores
__global__ __launch_bounds__(256) void k_lseknow(const float* __restrict__ ks,
                                                 float* __restrict__ lsek) {
    int b = blockIdx.x;
    int t = threadIdx.x;
    __shared__ float sm[256];
    float m = -1e30f;
    for (int j = t; j < KSN; j += 256) m = fmaxf(m, ks[(size_t)b * KSN + j]);
    sm[t] = m;
    __syncthreads();
    for (int s = 128; s > 0; s >>= 1) { if (t < s) sm[t] = fmaxf(sm[t], sm[t + s]); __syncthreads(); }
    m = fmaxf(sm[0], 0.0f);
    __syncthreads();
    float s = 0.0f;
    for (int j = t; j < KSN; j += 256) s += expf(ks[(size_t)b * KSN + j] - m);
    sm[t] = s;
    __syncthreads();
    for (int r = 128; r > 0; r >>= 1) { if (t < r) sm[t] += sm[t + r]; __syncthreads(); }
    if (t == 0) lsek[b] = m + logf(sm[0] + NPAD * expf(0.0f - m));
}

// ================================================= templated bf16 MFMA GEMM (C[m][n] = A[m]·B[n])
// EPI 0: GI (+bias, fp32)  EPI 1: MX maxout  EPI 2: gate (u8)  EPI 3: logits+partials
// EPI 4: gc fp32 [b][VOCP] (n<32)  EPI 5: ks fp32 [b][KSN] (n<32, m<KSN)
template<int EPI>
__global__ __launch_bounds__(256) void gemm_bt(
    const u16* __restrict__ A, int lda,
    const u16* __restrict__ B, int ldb, int K,
    const float* __restrict__ p0, const float* __restrict__ p1,
    float* __restrict__ q0, u16* __restrict__ q1,
    unsigned char* __restrict__ q2, float* __restrict__ q3)
{
    __shared__ u16 Asm[128 * 64];
    __shared__ u16 Bsm[128 * 64];
    const int tid = threadIdx.x;
    const int lane = tid & 63;
    const int w = tid >> 6;
    const int wm = w >> 1, wn = w & 1;
    const int nt = blockIdx.x, mt = blockIdx.y;

    f32x4 acc[4][4];
#pragma unroll
    for (int i = 0; i < 4; ++i)
#pragma unroll
        for (int j = 0; j < 4; ++j) acc[i][j] = (f32x4){0.f, 0.f, 0.f, 0.f};

    for (int kt = 0; kt < K; kt += 64) {
#pragma unroll
        for (int p = 0; p < 4; ++p) {
            int flat = (w * 4 + p) * 64 + lane;       // 0..1023 16B-slots
            int row = flat >> 3, slot = flat & 7;
            int ss = slot ^ (row & 7);                // inverse-swizzled source slot
            gload_lds16(A + (size_t)(mt * 128 + row) * lda + kt + ss * 8, Asm + flat * 8);
            gload_lds16(B + (size_t)(nt * 128 + row) * ldb + kt + ss * 8, Bsm + flat * 8);
        }
        __syncthreads();
#pragma unroll
        for (int kc = 0; kc < 2; ++kc) {
            bf16x8 af[4], bfr[4];
#pragma unroll
            for (int mi = 0; mi < 4; ++mi) {
                int row = wm * 64 + mi * 16 + (lane & 15);
                int bcol = kc * 64 + ((lane >> 4) << 4);
                af[mi] = *(const bf16x8*)((const char*)Asm + row * 128 + (bcol ^ ((row & 7) << 4)));
            }
#pragma unroll
            for (int ni = 0; ni < 4; ++ni) {
                int row = wn * 64 + ni * 16 + (lane & 15);
                int bcol = kc * 64 + ((lane >> 4) << 4);
                bfr[ni] = *(const bf16x8*)((const char*)Bsm + row * 128 + (bcol ^ ((row & 7) << 4)));
            }
#pragma unroll
            for (int mi = 0; mi < 4; ++mi)
#pragma unroll
                for (int ni = 0; ni < 4; ++ni)
                    acc[mi][ni] = __builtin_amdgcn_mfma_f32_16x16x32_bf16(af[mi], bfr[ni], acc[mi][ni], 0, 0, 0);
        }
        __syncthreads();
    }

    const int cl = lane & 15;           // n offset within fragment
    const int rg = (lane >> 4) << 2;    // m base within fragment

    if constexpr (EPI == 0) {           // GI = TE@Wih.T + bih  (fp32 [n][3072])
#pragma unroll
        for (int mi = 0; mi < 4; ++mi) {
            int m0 = mt * 128 + wm * 64 + mi * 16 + rg;
            float4 bias = *(const float4*)(p0 + m0);
#pragma unroll
            for (int ni = 0; ni < 4; ++ni) {
                int n = nt * 128 + wn * 64 + ni * 16 + cl;
                float4 v;
                v.x = acc[mi][ni][0] + bias.x; v.y = acc[mi][ni][1] + bias.y;
                v.z = acc[mi][ni][2] + bias.z; v.w = acc[mi][ni][3] + bias.w;
                *(float4*)(q0 + (size_t)n * 3072 + m0) = v;
            }
        }
    }
    if constexpr (EPI == 1) {           // maxout -> BL bf16 [n][512]
#pragma unroll
        for (int mi = 0; mi < 4; ++mi) {
            int m0 = mt * 128 + wm * 64 + mi * 16 + rg;
            float4 eb4 = *(const float4*)(p1 + m0);
#pragma unroll
            for (int ni = 0; ni < 4; ++ni) {
                int n = nt * 128 + wn * 64 + ni * 16 + cl;
                int b = n >> 6;
                float v0 = acc[mi][ni][0] + p0[b * 1024 + m0 + 0] + eb4.x;
                float v1 = acc[mi][ni][1] + p0[b * 1024 + m0 + 1] + eb4.y;
                float v2 = acc[mi][ni][2] + p0[b * 1024 + m0 + 2] + eb4.z;
                float v3 = acc[mi][ni][3] + p0[b * 1024 + m0 + 3] + eb4.w;
                unsigned pk = f2bf(fmaxf(v0, v1)) | ((unsigned)f2bf(fmaxf(v2, v3)) << 16);
                *(unsigned*)(q1 + (size_t)n * 512 + (m0 >> 1)) = pk;
            }
        }
    }
    if constexpr (EPI == 2) {           // gate -> g8 u8 [n][VOCP]
#pragma unroll
        for (int mi = 0; mi < 4; ++mi) {
            int v0 = mt * 128 + wm * 64 + mi * 16 + rg;
#pragma unroll
            for (int ni = 0; ni < 4; ++ni) {
                int n = nt * 128 + wn * 64 + ni * 16 + cl;
                int b = n >> 6;
                float4 gcv = *(const float4*)(p0 + (size_t)b * VOCP + v0);
                unsigned pk = 0;
#pragma unroll
                for (int r = 0; r < 4; ++r) {
                    float garg = acc[mi][ni][r] + ((const float*)&gcv)[r];
                    float gate = 1.0f / (1.0f + expf(-garg));
                    pk |= ((unsigned)(int)(gate * 255.0f + 0.5f)) << (8 * r);
                }
                *(unsigned*)(q2 + (size_t)n * VOCP + v0) = pk;
            }
        }
    }
    if constexpr (EPI == 3) {           // logits -> Lb bf16 [n][VOCP] + partial max/sumexp
        __shared__ float redm[2][128];
        __shared__ float reds[2][128];
#pragma unroll
        for (int mi = 0; mi < 4; ++mi) {
            int v0 = mt * 128 + wm * 64 + mi * 16 + rg;
#pragma unroll
            for (int ni = 0; ni < 4; ++ni) {
                int n = nt * 128 + wn * 64 + ni * 16 + cl;
                unsigned lo = f2bf(acc[mi][ni][0]) | ((unsigned)f2bf(acc[mi][ni][1]) << 16);
                unsigned hi = f2bf(acc[mi][ni][2]) | ((unsigned)f2bf(acc[mi][ni][3]) << 16);
                *(uint2*)(q1 + (size_t)n * VOCP + v0) = make_uint2(lo, hi);
            }
        }
#pragma unroll
        for (int ni = 0; ni < 4; ++ni) {
            float lm = -1e30f;
#pragma unroll
            for (int mi = 0; mi < 4; ++mi) {
                int v0 = mt * 128 + wm * 64 + mi * 16 + rg;
#pragma unroll
                for (int r = 0; r < 4; ++r)
                    if (v0 + r < VOC) lm = fmaxf(lm, acc[mi][ni][r]);
            }
            lm = fmaxf(lm, __shfl_xor(lm, 16));
            lm = fmaxf(lm, __shfl_xor(lm, 32));
            float s = 0.0f;
#pragma unroll
            for (int mi = 0; mi < 4; ++mi) {
                int v0 = mt * 128 + wm * 64 + mi * 16 + rg;
#pragma unroll
                for (int r = 0; r < 4; ++r)
                    if (v0 + r < VOC) s += expf(acc[mi][ni][r] - lm);
            }
            s += __shfl_xor(s, 16);
            s += __shfl_xor(s, 32);
            if (lane < 16) {
                redm[wm][wn * 64 + ni * 16 + lane] = lm;
                reds[wm][wn * 64 + ni * 16 + lane] = s;
            }
        }
        __syncthreads();
        if (tid < 128) {
            float m0_ = redm[0][tid], m1_ = redm[1][tid];
            float m = fmaxf(m0_, m1_);
            float s = reds[0][tid] * expf(m0_ - m) + reds[1][tid] * expf(m1_ - m);
            int n = nt * 128 + tid;
            q0[(size_t)n * NTMP + mt] = m;
            q3[(size_t)n * NTMP + mt] = s;
        }
    }
    if constexpr (EPI == 4) {           // gc fp32 [b][VOCP], only n<32 valid
#pragma unroll
        for (int mi = 0; mi < 4; ++mi) {
            int m0 = mt * 128 + wm * 64 + mi * 16 + rg;
#pragma unroll
            for (int ni = 0; ni < 4; ++ni) {
                int n = nt * 128 + wn * 64 + ni * 16 + cl;
                if (n < 32) {
                    float4 v;
                    v.x = acc[mi][ni][0]; v.y = acc[mi][ni][1];
                    v.z = acc[mi][ni][2]; v.w = acc[mi][ni][3];
                    *(float4*)(q0 + (size_t)n * VOCP + m0) = v;
                }
            }
        }
    }
    if constexpr (EPI == 5) {           // ks fp32 [b][KSN], n<32, m<KSN
#pragma unroll
        for (int mi = 0; mi < 4; ++mi) {
            int m0 = mt * 128 + wm * 64 + mi * 16 + rg;
#pragma unroll
            for (int ni = 0; ni < 4; ++ni) {
                int n = nt * 128 + wn * 64 + ni * 16 + cl;
                if (n < 32 && m0 < KSN) {
                    float4 v;
                    v.x = acc[mi][ni][0]; v.y = acc[mi][ni][1];
                    v.z = acc[mi][ni][2]; v.w = acc[mi][ni][3];
                    *(float4*)(q0 + (size_t)n * KSN + m0) = v;
                }
            }
        }
    }
}

// ------------------------------------------------- persistent MFMA GRU: all 64 steps, one dispatch
// 32 blocks x 256 threads (4 waves). Block jb owns j-slice [jb*32, jb*32+32):
// A-panel = Whh rows {j, 1024+j, 2048+j} = 96 rows x 1024 K bf16 (196 KB, per-XCD-L2 resident).
// Per step: MFMA GEMM [96 x 32 x 1024] staged in LDS, epilogue fuses gate math,
// writes h bf16 directly into BG[:, 0:1024] (stride 1536). Grid barrier between steps.
__global__ __launch_bounds__(256, 2) void k_gru_m(const u16* __restrict__ WhhB,
                                                  const float* __restrict__ GI,
                                                  const float* __restrict__ bhh,
                                                  const u16* __restrict__ h0b,
                                                  u16* __restrict__ BG,
                                                  unsigned* __restrict__ cnt) {
    __shared__ u16 Asm[96 * 64];      // 12 KB
    __shared__ u16 Bsm[32 * 64];      // 4 KB
    __shared__ float epi[96][36];     // 13.8 KB fp32 exchange
    const int tid = threadIdx.x;
    const int lane = tid & 63;
    const int w = tid >> 6;
    const int wm = w >> 1, wn = w & 1;         // M-half (48 rows), N-half (16 cols)
    const int jb = blockIdx.x;
    const int j0 = jb * 32;
    // epilogue coords
    const int jl = tid & 31, grp = tid >> 5;   // j' 0..31, batch group 0..7
    const int je = j0 + jl;
    const float bh0 = bhh[je], bh1 = bhh[1024 + je], bh2 = bhh[2048 + je];

    for (int t = 0; t < 64; ++t) {
        f32x4 acc[3];
#pragma unroll
        for (int i = 0; i < 3; ++i) acc[i] = (f32x4){0.f, 0.f, 0.f, 0.f};

        for (int kt = 0; kt < 1024; kt += 64) {
            // stage A: 96 rows x 64 K (768 slots, 3/thread), linear LDS + inverse-swz source
#pragma unroll
            for (int p = 0; p < 3; ++p) {
                int flat = tid + p * 256;
                int row = flat >> 3, slot = flat & 7;
                int ss = slot ^ (row & 7);
                int gr = j0 + row + ((row >> 5) * 992);   // 0->j0+row, 32->1024+.., 64->2048+..
                gload_lds16(WhhB + (size_t)gr * 1024 + kt + ss * 8, Asm + flat * 8);
            }
            // stage B: 32 batch rows x 64 K (256 slots, 1/thread)
            {
                int row = tid >> 3, slot = tid & 7;
                int ss = slot ^ (row & 7);
                const u16* src = (t == 0) ? h0b + (size_t)row * 1024 + kt + ss * 8
                                          : BG + ((size_t)(row * 64 + t - 1)) * 1536 + kt + ss * 8;
                gload_lds16(src, Bsm + tid * 8);
            }
            __syncthreads();
#pragma unroll
            for (int kc = 0; kc < 2; ++kc) {
                int bcol = kc * 64 + ((lane >> 4) << 4);
                bf16x8 bfr;
                {
                    int row = wn * 16 + (lane & 15);
                    bfr = *(const bf16x8*)((const char*)Bsm + row * 128 + (bcol ^ ((row & 7) << 4)));
                }
#pragma unroll
                for (int mi = 0; mi < 3; ++mi) {
                    int row = wm * 48 + mi * 16 + (lane & 15);
                    bf16x8 af = *(const bf16x8*)((const char*)Asm + row * 128 + (bcol ^ ((row & 7) << 4)));
                    acc[mi] = __builtin_amdgcn_mfma_f32_16x16x32_bf16(af, bfr, acc[mi], 0, 0, 0);
                }
            }
            __syncthreads();
        }

        // write acc -> epi LDS: m = wm*48 + mi*16 + (lane>>4)*4 + r, n = wn*16 + (lane&15)
        {
            const int cl = wn * 16 + (lane & 15);
            const int rg = (lane >> 4) << 2;
#pragma unroll
            for (int mi = 0; mi < 3; ++mi) {
                int m0 = wm * 48 + mi * 16 + rg;
#pragma unroll
                for (int r = 0; r < 4; ++r) epi[m0 + r][cl] = acc[mi][r];
            }
        }
        __syncthreads();

        // epilogue: thread (jl, grp) handles j'=jl, batches grp*4..grp*4+3
        {
            float4 ar4 = *(const float4*)&epi[jl][grp * 4];
            float4 az4 = *(const float4*)&epi[32 + jl][grp * 4];
            float4 an4 = *(const float4*)&epi[64 + jl][grp * 4];
            float ar[4] = {ar4.x, ar4.y, ar4.z, ar4.w};
            float az[4] = {az4.x, az4.y, az4.z, az4.w};
            float an[4] = {an4.x, an4.y, an4.z, an4.w};
#pragma unroll
            for (int r = 0; r < 4; ++r) {
                int b = grp * 4 + r;
                int n = b * 64 + t;
                const float* gi = GI + (size_t)n * 3072 + je;
                float rr = sigmoidf_(gi[0] + ar[r] + bh0);
                float zz = sigmoidf_(gi[1024] + az[r] + bh1);
                float nn = tanhf(gi[2048] + rr * (an[r] + bh2));
                float hp = bf2f((t == 0) ? h0b[(size_t)b * 1024 + je]
                                         : BG[((size_t)(b * 64 + t - 1)) * 1536 + je]);
                float hnew = (1.0f - zz) * nn + zz * hp;
                BG[(size_t)n * 1536 + je] = f2bf(hnew);
            }
        }

        if (t < 63) {
            __threadfence();
            __syncthreads();
            if (tid == 0) {
                __hip_atomic_fetch_add(cnt, 1u, __ATOMIC_ACQ_REL, __HIP_MEMORY_SCOPE_AGENT);
                unsigned target = 32u * (unsigned)(t + 1);
                while (__hip_atomic_load(cnt, __ATOMIC_ACQUIRE, __HIP_MEMORY_SCOPE_AGENT) < target)
                    __builtin_amdgcn_s_sleep(2);
            }
            __syncthreads();
            __threadfence();
        }
    }
}

// ------------------------------------------------- per-row lse from partials
__global__ __launch_bounds__(256) void k_lse(const float* __restrict__ pmax,
                                             const float* __restrict__ psum,
                                             float* __restrict__ lse) {
    int n = blockIdx.x;
    int t = threadIdx.x;
    __shared__ float sm[256];
    const float* pm = pmax + (size_t)n * NTMP;
    const float* ps = psum + (size_t)n * NTMP;
    float m = -1e30f;
    for (int p = t; p < NTM; p += 256) m = fmaxf(m, pm[p]);
    sm[t] = m;
    __syncthreads();
    for (int s = 128; s > 0; s >>= 1) { if (t < s) sm[t] = fmaxf(sm[t], sm[t + s]); __syncthreads(); }
    m = sm[0];
    __syncthreads();
    float s = 0.0f;
    for (int p = t; p < NTM; p += 256) s += ps[p] * expf(pm[p] - m);
    sm[t] = s;
    __syncthreads();
    for (int r = 128; r > 0; r >>= 1) { if (t < r) sm[t] += sm[t + r]; __syncthreads(); }
    if (t == 0) lse[n] = m + logf(sm[0]);
}

// ------------------------------------------------- final combine (fully coalesced)
__global__ __launch_bounds__(256) void k_final(const u16* __restrict__ Lb,
                                               const unsigned char* __restrict__ g8,
                                               const float* __restrict__ lse,
                                               const float* __restrict__ ks,
                                               const float* __restrict__ lsek,
                                               float* __restrict__ out) {
    int n = blockIdx.y;
    int b = n >> 6;
    float lsen = lse[n], lkb = lsek[b];
    int base = blockIdx.x * 2048;
#pragma unroll
    for (int i = 0; i < 8; ++i) {
        int v = base + i * 256 + threadIdx.x;
        if (v < VOC) {
            float L = bf2f(Lb[(size_t)n * VOCP + v]);
            float g = g8[(size_t)n * VOCP + v] * (1.0f / 255.0f);
            float kp = ((v >= 10 && v < 10 + KSN) ? ks[(size_t)b * KSN + (v - 10)] : 0.0f) - lkb;
            out[(size_t)n * VOC + v] = g * (L - lsen) + (1.0f - g) * kp;
        }
    }
}

// ---------------------------------------------------------------- launch
extern "C" void kernel_launch(void* const* d_in, const int* in_sizes, int n_in,
                              void* d_out, int out_size, void* d_ws, size_t ws_size,
                              hipStream_t stream) {
    const float* ses    = (const float*)d_in[0];
    const float* know   = (const float*)d_in[1];
    const int*   target = (const int*)d_in[2];
    const float* embed  = (const float*)d_in[3];
    const float* Wih    = (const float*)d_in[4];
    const float* Whh    = (const float*)d_in[5];
    const float* bih    = (const float*)d_in[6];
    const float* bhh    = (const float*)d_in[7];
    const float* sdw    = (const float*)d_in[8];
    const float* sdb    = (const float*)d_in[9];
    const float* dw     = (const float*)d_in[10];
    const float* siw    = (const float*)d_in[11];
    const float* ew     = (const float*)d_in[12];
    const float* eb     = (const float*)d_in[13];
    const float* W1     = (const float*)d_in[14];
    const float* W2     = (const float*)d_in[15];
    const float* W3     = (const float*)d_in[16];
    const float* W4     = (const float*)d_in[17];
    const float* kvw    = (const float*)d_in[18];

    char* ws = (char*)d_ws;
    size_t o = 0;
    auto alloc = [&](size_t bytes) { char* r = ws + o; o += (bytes + 255) & ~(size_t)255; return r; };
    u16*   Aemb  = (u16*)  alloc((size_t)VOCP * 512 * 2);
    u16*   A34   = (u16*)  alloc((size_t)VOCP * 1536 * 2);
    u16*   Adwew = (u16*)  alloc((size_t)1024 * 1536 * 2);
    u16*   Wihb  = (u16*)  alloc((size_t)3072 * 512 * 2);
    u16*   WhhB  = (u16*)  alloc((size_t)3072 * 1024 * 2);
    u16*   h0b   = (u16*)  alloc((size_t)32 * 1024 * 2);
    u16*   BG    = (u16*)  alloc((size_t)2048 * 1536 * 2);
    u16*   BL    = (u16*)  alloc((size_t)2048 * 512 * 2);
    float* GI    = (float*)alloc((size_t)2048 * 3072 * 4);
    float* h0    = (float*)alloc((size_t)32 * 1024 * 4);
    float* sesinf= (float*)alloc((size_t)32 * 1024 * 4);
    float* gc    = (float*)alloc((size_t)32 * VOCP * 4);
    float* ksb   = (float*)alloc((size_t)32 * KSN * 4);
    float* lsek  = (float*)alloc(256);
    float* lse   = (float*)alloc((size_t)2048 * 4);
    unsigned* cnt= (unsigned*)alloc(256);
    float* pmax  = (float*)alloc((size_t)2048 * NTMP * 4);
    float* psum  = (float*)alloc((size_t)2048 * NTMP * 4);
    unsigned char* g8 = (unsigned char*)alloc((size_t)2048 * VOCP);   // aliased: kvwb
    u16*   Lb    = (u16*)  alloc((size_t)2048 * VOCP * 2);            // aliased: Awk
    u16*   Bsk   = (u16*)  alloc((size_t)128 * 2048 * 2);
    float* out = (float*)d_out;

    u16*   kvwb  = (u16*)g8;       // 8832*1024*2 = 18.1 MB <= g8 (102 MB)
    u16*   Awk   = Lb;             // 50048*2048*2 == Lb size

    hipMemsetAsync(cnt, 0, 4, stream);

    // weight conversions (early users of aliased buffers come first)
    k_cvt<<<dim3(VOC, 1), 256, 0, stream>>>(embed, Aemb, 512, 512, 512);
    k_cvt<<<dim3(VOC, 1), 256, 0, stream>>>(W3, A34, 1024, 1024, 1536);
    k_cvt<<<dim3(VOC, 1), 256, 0, stream>>>(W4, A34 + 1024, 512, 512, 1536);
    k_cvt<<<dim3(VOC, 1), 256, 0, stream>>>(W1, Awk, 1024, 1024, 2048);
    k_cvt<<<dim3(VOC, 1), 256, 0, stream>>>(W2, Awk + 1024, 1024, 1024, 2048);
    k_cvt<<<dim3(KSN, 1), 256, 0, stream>>>(kvw, kvwb, 1024, 1024, 1024);
    k_pad0<<<dim3(VOCP - VOC), 256, 0, stream>>>(Aemb, A34, Awk);
    k_padK<<<dim3(KSNP - KSN), 256, 0, stream>>>(kvwb);
    k_cvt<<<dim3(1024, 1), 256, 0, stream>>>(dw, Adwew, 1024, 1024, 1536);
    k_cvt<<<dim3(1024, 1), 256, 0, stream>>>(ew, Adwew + 1024, 512, 512, 1536);
    k_cvt<<<dim3(3072, 1), 256, 0, stream>>>(Wih, Wihb, 512, 512, 512);
    k_cvt<<<dim3(3072, 1), 256, 0, stream>>>(Whh, WhhB, 1024, 1024, 1024);
    k_bsk<<<dim3(128), 256, 0, stream>>>(ses, know, Bsk);

    k_gather<<<dim3(2048), 128, 0, stream>>>(embed, target, BG);
    k_h0_sesinf<<<dim3(32), 256, 0, stream>>>(ses, sdw, sdb, siw, h0, sesinf);
    k_cvt<<<dim3(32, 1), 256, 0, stream>>>(h0, h0b, 1024, 1024, 1024);

    // gc = [W1|W2] @ [ses|know]   (MFMA, n<32 valid)
    gemm_bt<4><<<dim3(1, NTM), 256, 0, stream>>>(Awk, 2048, Bsk, 2048, 2048,
                                                 nullptr, nullptr, gc, nullptr, nullptr, nullptr);
    // ks = kvw @ know   (MFMA, B = know half of Bsk)
    gemm_bt<5><<<dim3(1, 69), 256, 0, stream>>>(kvwb, 1024, Bsk + 1024, 2048, 1024,
                                                nullptr, nullptr, ksb, nullptr, nullptr, nullptr);
    k_lseknow<<<dim3(32), 256, 0, stream>>>(ksb, lsek);

    // GI = TE @ Wih.T + bih
    gemm_bt<0><<<dim3(16, 24), 256, 0, stream>>>(Wihb, 512, BG + 1024, 1536, 512,
                                                 bih, nullptr, GI, nullptr, nullptr, nullptr);
    // GRU recurrence: persistent MFMA kernel, h written bf16 directly into BG[:,0:1024]
    k_gru_m<<<dim3(32), 256, 0, stream>>>(WhhB, GI, bhh, h0b, BG, cnt);
    // MX (maxout) -> BL
    gemm_bt<1><<<dim3(16, 8), 256, 0, stream>>>(Adwew, 1536, BG, 1536, 1536,
                                                sesinf, eb, nullptr, BL, nullptr, nullptr);
    // gate GEMM -> g8
    gemm_bt<2><<<dim3(16, NTM), 256, 0, stream>>>(A34, 1536, BG, 1536, 1536,
                                                  gc, nullptr, nullptr, nullptr, g8, nullptr);
    // logit GEMM -> Lb + partials
    gemm_bt<3><<<dim3(16, NTM), 256, 0, stream>>>(Aemb, 512, BL, 512, 512,
                                                  nullptr, nullptr, pmax, Lb, nullptr, psum);
    k_lse<<<dim3(2048), 256, 0, stream>>>(pmax, psum, lse);
    k_final<<<dim3(25, 2048), 256, 0, stream>>>(Lb, g8, lse, ksb, lsek, out);
}

// Round 6
// 2127.409 us; speedup vs baseline: 2.7280x; 1.1633x over previous
//
#include <hip/hip_runtime.h>

// Problem dims
constexpr int VOC  = 50005;
constexpr int VOCP = 50048;   // 391*128, padded vocab
constexpr int NTM  = 391;     // vocab tiles (128) for big GEMMs
constexpr int NTMP = 400;     // padded partial stride
constexpr int KSN  = 8784;    // KNOW-1
constexpr int KSNP = 8832;    // 69*128
constexpr float NPAD = 41221.0f;

typedef unsigned short u16;
typedef __attribute__((ext_vector_type(4))) float f32x4;
typedef __attribute__((ext_vector_type(8))) short bf16x8;

__device__ __forceinline__ float dot4(float4 a, float4 b) {
    return a.x*b.x + a.y*b.y + a.z*b.z + a.w*b.w;
}
__device__ __forceinline__ float sigmoidf_(float x) { return 1.0f / (1.0f + expf(-x)); }
__device__ __forceinline__ u16 f2bf(float f) {
    unsigned x = __float_as_uint(f);
    return (u16)((x + 0x7FFFu + ((x >> 16) & 1u)) >> 16);
}
__device__ __forceinline__ float bf2f(u16 u) { return __uint_as_float(((unsigned)u) << 16); }
__device__ __forceinline__ void gload_lds16(const void* g, void* l) {
    __builtin_amdgcn_global_load_lds((const __attribute__((address_space(1))) unsigned int*)g,
                                     (__attribute__((address_space(3))) unsigned int*)l, 16, 0, 0);
}

// ---------------------------------------------------------------- cvt fp32 -> bf16 (strided)
__global__ __launch_bounds__(256) void k_cvt(const float* __restrict__ src, u16* __restrict__ dst,
                                             int ncols, int sld, int dld) {
    int row = blockIdx.x;
    int c = (blockIdx.y * 256 + threadIdx.x) * 4;
    if (c >= ncols) return;
    float4 v = *(const float4*)(src + (size_t)row * sld + c);
    unsigned lo = f2bf(v.x) | ((unsigned)f2bf(v.y) << 16);
    unsigned hi = f2bf(v.z) | ((unsigned)f2bf(v.w) << 16);
    *(uint2*)(dst + (size_t)row * dld + c) = make_uint2(lo, hi);
}

// zero pad rows 50005..50047 of Aemb / A34 / Awk
__global__ __launch_bounds__(256) void k_pad0(u16* __restrict__ Aemb, u16* __restrict__ A34,
                                              u16* __restrict__ Awk) {
    int r = VOC + blockIdx.x;
    unsigned* pe = (unsigned*)(Aemb + (size_t)r * 512);
    if (threadIdx.x < 256) pe[threadIdx.x] = 0;
    unsigned* p3 = (unsigned*)(A34 + (size_t)r * 1536);
    for (int i = threadIdx.x; i < 768; i += 256) p3[i] = 0;
    unsigned* pw = (unsigned*)(Awk + (size_t)r * 2048);
    for (int i = threadIdx.x; i < 1024; i += 256) pw[i] = 0;
}
// zero pad rows 8784..8831 of kvwb
__global__ __launch_bounds__(256) void k_padK(u16* __restrict__ kvwb) {
    int r = KSN + blockIdx.x;
    unsigned* p = (unsigned*)(kvwb + (size_t)r * 1024);
    for (int i = threadIdx.x; i < 512; i += 256) p[i] = 0;
}

// build Bsk [128][2048] bf16: rows 0..31 = [ses|know], rows 32..127 = 0
__global__ __launch_bounds__(256) void k_bsk(const float* __restrict__ ses,
                                             const float* __restrict__ know,
                                             u16* __restrict__ Bsk) {
    int row = blockIdx.x;
    for (int c0 = threadIdx.x * 4; c0 < 2048; c0 += 1024) {
        uint2 val = make_uint2(0, 0);
        if (row < 32) {
            const float* srcp = (c0 < 1024) ? ses + (size_t)row * 1024 + c0
                                            : know + (size_t)row * 1024 + (c0 - 1024);
            float4 v = *(const float4*)srcp;
            val = make_uint2(f2bf(v.x) | ((unsigned)f2bf(v.y) << 16),
                             f2bf(v.z) | ((unsigned)f2bf(v.w) << 16));
        }
        *(uint2*)(Bsk + (size_t)row * 2048 + c0) = val;
    }
}

// ---------------------------------------------------------------- gather target embeddings -> BG[:,1024:1536] bf16
__global__ __launch_bounds__(128) void k_gather(const float* __restrict__ embed,
                                                const int* __restrict__ target,
                                                u16* __restrict__ BG) {
    int n = blockIdx.x;
    int row = target[n];
    int c = threadIdx.x * 4;
    float4 v = *(const float4*)(embed + (size_t)row * 512 + c);
    unsigned lo = f2bf(v.x) | ((unsigned)f2bf(v.y) << 16);
    unsigned hi = f2bf(v.z) | ((unsigned)f2bf(v.w) << 16);
    *(uint2*)(BG + (size_t)n * 1536 + 1024 + c) = make_uint2(lo, hi);
}

// ------------------------------------------------- h0 + ses_inf_vec (fp32, small)
__global__ __launch_bounds__(256) void k_h0_sesinf(const float* __restrict__ ses,
                                                   const float* __restrict__ sdw,
                                                   const float* __restrict__ sdb,
                                                   const float* __restrict__ siw,
                                                   float* __restrict__ h0,
                                                   float* __restrict__ sesinf) {
    int g = blockIdx.x * 256 + threadIdx.x;
    int b = g & 31;
    int jg = g >> 5;
    int j0 = jg * 4;
    const float4* s4 = (const float4*)(ses + (size_t)b * 1024);
    const float4* wa[4];
    const float4* wc[4];
#pragma unroll
    for (int r = 0; r < 4; ++r) {
        wa[r] = (const float4*)(sdw + (size_t)(j0 + r) * 1024);
        wc[r] = (const float4*)(siw + (size_t)(j0 + r) * 1024);
    }
    float a[4] = {0, 0, 0, 0}, c[4] = {0, 0, 0, 0};
    for (int kq = 0; kq < 256; ++kq) {
        float4 sv = s4[kq];
#pragma unroll
        for (int r = 0; r < 4; ++r) { a[r] += dot4(sv, wa[r][kq]); c[r] += dot4(sv, wc[r][kq]); }
    }
#pragma unroll
    for (int r = 0; r < 4; ++r) {
        h0[b * 1024 + j0 + r] = tanhf(a[r] + sdb[j0 + r]);
        sesinf[b * 1024 + j0 + r] = c[r];
    }
}

// ------------------------------------------------- lse of padded know scores
__global__ __launch_bounds__(256) void k_lseknow(const float* __restrict__ ks,
                                                 float* __restrict__ lsek) {
    int b = blockIdx.x;
    int t = threadIdx.x;
    __shared__ float sm[256];
    float m = -1e30f;
    for (int j = t; j < KSN; j += 256) m = fmaxf(m, ks[(size_t)b * KSN + j]);
    sm[t] = m;
    __syncthreads();
    for (int s = 128; s > 0; s >>= 1) { if (t < s) sm[t] = fmaxf(sm[t], sm[t + s]); __syncthreads(); }
    m = fmaxf(sm[0], 0.0f);
    __syncthreads();
    float s = 0.0f;
    for (int j = t; j < KSN; j += 256) s += expf(ks[(size_t)b * KSN + j] - m);
    sm[t] = s;
    __syncthreads();
    for (int r = 128; r > 0; r >>= 1) { if (t < r) sm[t] += sm[t + r]; __syncthreads(); }
    if (t == 0) lsek[b] = m + logf(sm[0] + NPAD * expf(0.0f - m));
}

// ================================================= templated bf16 MFMA GEMM (C[m][n] = A[m]·B[n])
// EPI 0: GI (+bias, fp32)  EPI 1: MX maxout  EPI 2: gate (u8)  EPI 3: logits+partials
// EPI 4: gc fp32 [b][VOCP] (n<32)  EPI 5: ks fp32 [b][KSN] (n<32, m<KSN)
template<int EPI>
__global__ __launch_bounds__(256) void gemm_bt(
    const u16* __restrict__ A, int lda,
    const u16* __restrict__ B, int ldb, int K,
    const float* __restrict__ p0, const float* __restrict__ p1,
    float* __restrict__ q0, u16* __restrict__ q1,
    unsigned char* __restrict__ q2, float* __restrict__ q3)
{
    __shared__ u16 Asm[128 * 64];
    __shared__ u16 Bsm[128 * 64];
    const int tid = threadIdx.x;
    const int lane = tid & 63;
    const int w = tid >> 6;
    const int wm = w >> 1, wn = w & 1;
    const int nt = blockIdx.x, mt = blockIdx.y;

    f32x4 acc[4][4];
#pragma unroll
    for (int i = 0; i < 4; ++i)
#pragma unroll
        for (int j = 0; j < 4; ++j) acc[i][j] = (f32x4){0.f, 0.f, 0.f, 0.f};

    for (int kt = 0; kt < K; kt += 64) {
#pragma unroll
        for (int p = 0; p < 4; ++p) {
            int flat = (w * 4 + p) * 64 + lane;       // 0..1023 16B-slots
            int row = flat >> 3, slot = flat & 7;
            int ss = slot ^ (row & 7);                // inverse-swizzled source slot
            gload_lds16(A + (size_t)(mt * 128 + row) * lda + kt + ss * 8, Asm + flat * 8);
            gload_lds16(B + (size_t)(nt * 128 + row) * ldb + kt + ss * 8, Bsm + flat * 8);
        }
        __syncthreads();
#pragma unroll
        for (int kc = 0; kc < 2; ++kc) {
            bf16x8 af[4], bfr[4];
#pragma unroll
            for (int mi = 0; mi < 4; ++mi) {
                int row = wm * 64 + mi * 16 + (lane & 15);
                int bcol = kc * 64 + ((lane >> 4) << 4);
                af[mi] = *(const bf16x8*)((const char*)Asm + row * 128 + (bcol ^ ((row & 7) << 4)));
            }
#pragma unroll
            for (int ni = 0; ni < 4; ++ni) {
                int row = wn * 64 + ni * 16 + (lane & 15);
                int bcol = kc * 64 + ((lane >> 4) << 4);
                bfr[ni] = *(const bf16x8*)((const char*)Bsm + row * 128 + (bcol ^ ((row & 7) << 4)));
            }
#pragma unroll
            for (int mi = 0; mi < 4; ++mi)
#pragma unroll
                for (int ni = 0; ni < 4; ++ni)
                    acc[mi][ni] = __builtin_amdgcn_mfma_f32_16x16x32_bf16(af[mi], bfr[ni], acc[mi][ni], 0, 0, 0);
        }
        __syncthreads();
    }

    const int cl = lane & 15;           // n offset within fragment
    const int rg = (lane >> 4) << 2;    // m base within fragment

    if constexpr (EPI == 0) {           // GI = TE@Wih.T + bih  (fp32 [n][3072])
#pragma unroll
        for (int mi = 0; mi < 4; ++mi) {
            int m0 = mt * 128 + wm * 64 + mi * 16 + rg;
            float4 bias = *(const float4*)(p0 + m0);
#pragma unroll
            for (int ni = 0; ni < 4; ++ni) {
                int n = nt * 128 + wn * 64 + ni * 16 + cl;
                float4 v;
                v.x = acc[mi][ni][0] + bias.x; v.y = acc[mi][ni][1] + bias.y;
                v.z = acc[mi][ni][2] + bias.z; v.w = acc[mi][ni][3] + bias.w;
                *(float4*)(q0 + (size_t)n * 3072 + m0) = v;
            }
        }
    }
    if constexpr (EPI == 1) {           // maxout -> BL bf16 [n][512]
#pragma unroll
        for (int mi = 0; mi < 4; ++mi) {
            int m0 = mt * 128 + wm * 64 + mi * 16 + rg;
            float4 eb4 = *(const float4*)(p1 + m0);
#pragma unroll
            for (int ni = 0; ni < 4; ++ni) {
                int n = nt * 128 + wn * 64 + ni * 16 + cl;
                int b = n >> 6;
                float v0 = acc[mi][ni][0] + p0[b * 1024 + m0 + 0] + eb4.x;
                float v1 = acc[mi][ni][1] + p0[b * 1024 + m0 + 1] + eb4.y;
                float v2 = acc[mi][ni][2] + p0[b * 1024 + m0 + 2] + eb4.z;
                float v3 = acc[mi][ni][3] + p0[b * 1024 + m0 + 3] + eb4.w;
                unsigned pk = f2bf(fmaxf(v0, v1)) | ((unsigned)f2bf(fmaxf(v2, v3)) << 16);
                *(unsigned*)(q1 + (size_t)n * 512 + (m0 >> 1)) = pk;
            }
        }
    }
    if constexpr (EPI == 2) {           // gate -> g8 u8 [n][VOCP]
#pragma unroll
        for (int mi = 0; mi < 4; ++mi) {
            int v0 = mt * 128 + wm * 64 + mi * 16 + rg;
#pragma unroll
            for (int ni = 0; ni < 4; ++ni) {
                int n = nt * 128 + wn * 64 + ni * 16 + cl;
                int b = n >> 6;
                float4 gcv = *(const float4*)(p0 + (size_t)b * VOCP + v0);
                unsigned pk = 0;
#pragma unroll
                for (int r = 0; r < 4; ++r) {
                    float garg = acc[mi][ni][r] + ((const float*)&gcv)[r];
                    float gate = 1.0f / (1.0f + expf(-garg));
                    pk |= ((unsigned)(int)(gate * 255.0f + 0.5f)) << (8 * r);
                }
                *(unsigned*)(q2 + (size_t)n * VOCP + v0) = pk;
            }
        }
    }
    if constexpr (EPI == 3) {           // logits -> Lb bf16 [n][VOCP] + partial max/sumexp
        __shared__ float redm[2][128];
        __shared__ float reds[2][128];
#pragma unroll
        for (int mi = 0; mi < 4; ++mi) {
            int v0 = mt * 128 + wm * 64 + mi * 16 + rg;
#pragma unroll
            for (int ni = 0; ni < 4; ++ni) {
                int n = nt * 128 + wn * 64 + ni * 16 + cl;
                unsigned lo = f2bf(acc[mi][ni][0]) | ((unsigned)f2bf(acc[mi][ni][1]) << 16);
                unsigned hi = f2bf(acc[mi][ni][2]) | ((unsigned)f2bf(acc[mi][ni][3]) << 16);
                *(uint2*)(q1 + (size_t)n * VOCP + v0) = make_uint2(lo, hi);
            }
        }
#pragma unroll
        for (int ni = 0; ni < 4; ++ni) {
            float lm = -1e30f;
#pragma unroll
            for (int mi = 0; mi < 4; ++mi) {
                int v0 = mt * 128 + wm * 64 + mi * 16 + rg;
#pragma unroll
                for (int r = 0; r < 4; ++r)
                    if (v0 + r < VOC) lm = fmaxf(lm, acc[mi][ni][r]);
            }
            lm = fmaxf(lm, __shfl_xor(lm, 16));
            lm = fmaxf(lm, __shfl_xor(lm, 32));
            float s = 0.0f;
#pragma unroll
            for (int mi = 0; mi < 4; ++mi) {
                int v0 = mt * 128 + wm * 64 + mi * 16 + rg;
#pragma unroll
                for (int r = 0; r < 4; ++r)
                    if (v0 + r < VOC) s += expf(acc[mi][ni][r] - lm);
            }
            s += __shfl_xor(s, 16);
            s += __shfl_xor(s, 32);
            if (lane < 16) {
                redm[wm][wn * 64 + ni * 16 + lane] = lm;
                reds[wm][wn * 64 + ni * 16 + lane] = s;
            }
        }
        __syncthreads();
        if (tid < 128) {
            float m0_ = redm[0][tid], m1_ = redm[1][tid];
            float m = fmaxf(m0_, m1_);
            float s = reds[0][tid] * expf(m0_ - m) + reds[1][tid] * expf(m1_ - m);
            int n = nt * 128 + tid;
            q0[(size_t)n * NTMP + mt] = m;
            q3[(size_t)n * NTMP + mt] = s;
        }
    }
    if constexpr (EPI == 4) {           // gc fp32 [b][VOCP], only n<32 valid
#pragma unroll
        for (int mi = 0; mi < 4; ++mi) {
            int m0 = mt * 128 + wm * 64 + mi * 16 + rg;
#pragma unroll
            for (int ni = 0; ni < 4; ++ni) {
                int n = nt * 128 + wn * 64 + ni * 16 + cl;
                if (n < 32) {
                    float4 v;
                    v.x = acc[mi][ni][0]; v.y = acc[mi][ni][1];
                    v.z = acc[mi][ni][2]; v.w = acc[mi][ni][3];
                    *(float4*)(q0 + (size_t)n * VOCP + m0) = v;
                }
            }
        }
    }
    if constexpr (EPI == 5) {           // ks fp32 [b][KSN], n<32, m<KSN
#pragma unroll
        for (int mi = 0; mi < 4; ++mi) {
            int m0 = mt * 128 + wm * 64 + mi * 16 + rg;
#pragma unroll
            for (int ni = 0; ni < 4; ++ni) {
                int n = nt * 128 + wn * 64 + ni * 16 + cl;
                if (n < 32 && m0 < KSN) {
                    float4 v;
                    v.x = acc[mi][ni][0]; v.y = acc[mi][ni][1];
                    v.z = acc[mi][ni][2]; v.w = acc[mi][ni][3];
                    *(float4*)(q0 + (size_t)n * KSN + m0) = v;
                }
            }
        }
    }
}

// ------------------------------------------------- persistent MFMA GRU, barrier-free chunk pipeline
// 32 blocks x 256 threads. Block jb owns j-slice [jb*32, jb*32+32).
// Per wave: private A dbuf (48x64 bf16 x2) + B dbuf (16x64 x2) in LDS; 16 K-chunks
// pipelined with counted vmcnt (8 gload_lds/chunk), NO __syncthreads in the chunk loop.
// GI + h_prev prefetched to registers in the prologue. Gate exchange via LDS (aliased
// onto A bufs) with raw s_barrier + lgkmcnt only. One grid barrier per step.
__global__ __launch_bounds__(256, 1) void k_gru_m2(const u16* __restrict__ WhhB,
                                                   const float* __restrict__ GI,
                                                   const float* __restrict__ bhh,
                                                   const u16* __restrict__ h0b,
                                                   u16* __restrict__ BG,
                                                   unsigned* __restrict__ cnt) {
    __shared__ __align__(16) char smem[65536];
    const int tid = threadIdx.x;
    const int lane = tid & 63;
    const int w = tid >> 6;
    const int wm = w >> 1, wn = w & 1;
    const int jb = blockIdx.x;
    const int j0 = jb * 32;
    const int jl = tid & 31, grp = tid >> 5;
    const int je = j0 + jl;
    const float bh0 = bhh[je], bh1 = bhh[1024 + je], bh2 = bhh[2048 + je];

    char* Abase = smem + w * 12288;            // 2 bufs x 6144 B (48x64 bf16)
    char* Bbase = smem + 49152 + w * 4096;     // 2 bufs x 2048 B (16x64 bf16)
    float (*epi)[33] = (float(*)[33])smem;     // aliased on A region after chunks

    for (int t = 0; t < 64; ++t) {
        const u16* hsrc = (t == 0) ? h0b : BG + (size_t)(t - 1) * 1536;
        const size_t hstr = (t == 0) ? 1024 : (size_t)64 * 1536;

        // ---- prologue: GI + h_prev prefetch into registers
        float gi_r[4], gi_z[4], gi_n[4], hpv[4];
#pragma unroll
        for (int r = 0; r < 4; ++r) {
            int b = grp * 4 + r;
            const float* gp = GI + ((size_t)(b * 64 + t)) * 3072 + je;
            gi_r[r] = gp[0]; gi_z[r] = gp[1024]; gi_n[r] = gp[2048];
            hpv[r] = bf2f(hsrc[(size_t)b * hstr + je]);
        }

        auto stageA = [&](int c) {
            char* dst = Abase + (c & 1) * 6144;
            int kt = c * 64;
#pragma unroll
            for (int q = 0; q < 6; ++q) {
                int s = q * 64 + lane;
                int rl = s >> 3;                      // 0..47 local row
                int cs = (s & 7) ^ (rl & 7);          // inverse-swizzled src slot
                int pr = wm * 48 + rl;                // panel row 0..95
                int gr = (pr >> 5) * 1024 + j0 + (pr & 31);
                gload_lds16(WhhB + (size_t)gr * 1024 + kt + cs * 8, dst + q * 1024);
            }
        };
        auto stageB = [&](int c) {
            char* dst = Bbase + (c & 1) * 2048;
            int kt = c * 64;
#pragma unroll
            for (int q = 0; q < 2; ++q) {
                int s = q * 64 + lane;
                int rl = s >> 3;                      // 0..15
                int cs = (s & 7) ^ (rl & 7);
                int b = wn * 16 + rl;
                gload_lds16(hsrc + (size_t)b * hstr + kt + cs * 8, dst + q * 1024);
            }
        };
        stageA(0); stageB(0); stageA(1); stageB(1);
        asm volatile("s_waitcnt vmcnt(0)" ::: "memory");
        __builtin_amdgcn_sched_barrier(0);

        f32x4 acc[3] = {{0.f,0.f,0.f,0.f},{0.f,0.f,0.f,0.f},{0.f,0.f,0.f,0.f}};
        const int colsel = (lane >> 4) << 4;
        const int lrow = lane & 15;
        const int bx = (lrow & 7) << 4;

#pragma unroll 2
        for (int c = 0; c < 16; ++c) {
            char* Ab = Abase + (c & 1) * 6144;
            char* Bb = Bbase + (c & 1) * 2048;
            bf16x8 bf0 = *(const bf16x8*)(Bb + lrow * 128 + ((0 + colsel) ^ bx));
            bf16x8 bf1 = *(const bf16x8*)(Bb + lrow * 128 + ((64 + colsel) ^ bx));
            bf16x8 af0[3], af1[3];
#pragma unroll
            for (int mi = 0; mi < 3; ++mi) {
                int ar = mi * 16 + lrow;
                int ax = (ar & 7) << 4;
                af0[mi] = *(const bf16x8*)(Ab + ar * 128 + ((0 + colsel) ^ ax));
                af1[mi] = *(const bf16x8*)(Ab + ar * 128 + ((64 + colsel) ^ ax));
            }
#pragma unroll
            for (int mi = 0; mi < 3; ++mi) {
                acc[mi] = __builtin_amdgcn_mfma_f32_16x16x32_bf16(af0[mi], bf0, acc[mi], 0, 0, 0);
                acc[mi] = __builtin_amdgcn_mfma_f32_16x16x32_bf16(af1[mi], bf1, acc[mi], 0, 0, 0);
            }
            // wave-local: ds_reads complete before overwriting this buffer
            asm volatile("s_waitcnt lgkmcnt(0)" ::: "memory");
            __builtin_amdgcn_sched_barrier(0);
            if (c < 14) {
                stageA(c + 2); stageB(c + 2);
                asm volatile("s_waitcnt vmcnt(8)" ::: "memory");   // chunk c+1 landed
            } else if (c == 14) {
                asm volatile("s_waitcnt vmcnt(0)" ::: "memory");   // chunk 15 landed
            }
            __builtin_amdgcn_sched_barrier(0);
        }

        // ---- gate exchange (epi aliases A bufs; raw barriers, no vmcnt drain)
        asm volatile("s_waitcnt lgkmcnt(0)" ::: "memory");
        __builtin_amdgcn_s_barrier();
        {
            const int cl = wn * 16 + lrow;
            const int rg = (lane >> 4) << 2;
#pragma unroll
            for (int mi = 0; mi < 3; ++mi) {
                int m0 = wm * 48 + mi * 16 + rg;
#pragma unroll
                for (int r = 0; r < 4; ++r) epi[m0 + r][cl] = acc[mi][r];
            }
        }
        asm volatile("s_waitcnt lgkmcnt(0)" ::: "memory");
        __builtin_amdgcn_s_barrier();
#pragma unroll
        for (int r = 0; r < 4; ++r) {
            int b = grp * 4 + r;
            float ar = epi[jl][b];
            float az = epi[32 + jl][b];
            float an = epi[64 + jl][b];
            float rr = sigmoidf_(gi_r[r] + ar + bh0);
            float zz = sigmoidf_(gi_z[r] + az + bh1);
            float nn = tanhf(gi_n[r] + rr * (an + bh2));
            float hnew = (1.0f - zz) * nn + zz * hpv[r];
            BG[((size_t)(b * 64 + t)) * 1536 + je] = f2bf(hnew);
        }

        if (t < 63) {
            __threadfence();
            __syncthreads();
            if (tid == 0) {
                __hip_atomic_fetch_add(cnt, 1u, __ATOMIC_ACQ_REL, __HIP_MEMORY_SCOPE_AGENT);
                unsigned tgt = 32u * (unsigned)(t + 1);
                while (__hip_atomic_load(cnt, __ATOMIC_ACQUIRE, __HIP_MEMORY_SCOPE_AGENT) < tgt)
                    __builtin_amdgcn_s_sleep(1);
            }
            __syncthreads();
            __threadfence();
        } else {
            __syncthreads();
        }
    }
}

// ------------------------------------------------- per-row lse from partials
__global__ __launch_bounds__(256) void k_lse(const float* __restrict__ pmax,
                                             const float* __restrict__ psum,
                                             float* __restrict__ lse) {
    int n = blockIdx.x;
    int t = threadIdx.x;
    __shared__ float sm[256];
    const float* pm = pmax + (size_t)n * NTMP;
    const float* ps = psum + (size_t)n * NTMP;
    float m = -1e30f;
    for (int p = t; p < NTM; p += 256) m = fmaxf(m, pm[p]);
    sm[t] = m;
    __syncthreads();
    for (int s = 128; s > 0; s >>= 1) { if (t < s) sm[t] = fmaxf(sm[t], sm[t + s]); __syncthreads(); }
    m = sm[0];
    __syncthreads();
    float s = 0.0f;
    for (int p = t; p < NTM; p += 256) s += ps[p] * expf(pm[p] - m);
    sm[t] = s;
    __syncthreads();
    for (int r = 128; r > 0; r >>= 1) { if (t < r) sm[t] += sm[t + r]; __syncthreads(); }
    if (t == 0) lse[n] = m + logf(sm[0]);
}

// ------------------------------------------------- final combine (fully coalesced)
__global__ __launch_bounds__(256) void k_final(const u16* __restrict__ Lb,
                                               const unsigned char* __restrict__ g8,
                                               const float* __restrict__ lse,
                                               const float* __restrict__ ks,
                                               const float* __restrict__ lsek,
                                               float* __restrict__ out) {
    int n = blockIdx.y;
    int b = n >> 6;
    float lsen = lse[n], lkb = lsek[b];
    int base = blockIdx.x * 2048;
#pragma unroll
    for (int i = 0; i < 8; ++i) {
        int v = base + i * 256 + threadIdx.x;
        if (v < VOC) {
            float L = bf2f(Lb[(size_t)n * VOCP + v]);
            float g = g8[(size_t)n * VOCP + v] * (1.0f / 255.0f);
            float kp = ((v >= 10 && v < 10 + KSN) ? ks[(size_t)b * KSN + (v - 10)] : 0.0f) - lkb;
            out[(size_t)n * VOC + v] = g * (L - lsen) + (1.0f - g) * kp;
        }
    }
}

// ---------------------------------------------------------------- launch
extern "C" void kernel_launch(void* const* d_in, const int* in_sizes, int n_in,
                              void* d_out, int out_size, void* d_ws, size_t ws_size,
                              hipStream_t stream) {
    const float* ses    = (const float*)d_in[0];
    const float* know   = (const float*)d_in[1];
    const int*   target = (const int*)d_in[2];
    const float* embed  = (const float*)d_in[3];
    const float* Wih    = (const float*)d_in[4];
    const float* Whh    = (const float*)d_in[5];
    const float* bih    = (const float*)d_in[6];
    const float* bhh    = (const float*)d_in[7];
    const float* sdw    = (const float*)d_in[8];
    const float* sdb    = (const float*)d_in[9];
    const float* dw     = (const float*)d_in[10];
    const float* siw    = (const float*)d_in[11];
    const float* ew     = (const float*)d_in[12];
    const float* eb     = (const float*)d_in[13];
    const float* W1     = (const float*)d_in[14];
    const float* W2     = (const float*)d_in[15];
    const float* W3     = (const float*)d_in[16];
    const float* W4     = (const float*)d_in[17];
    const float* kvw    = (const float*)d_in[18];

    char* ws = (char*)d_ws;
    size_t o = 0;
    auto alloc = [&](size_t bytes) { char* r = ws + o; o += (bytes + 255) & ~(size_t)255; return r; };
    u16*   Aemb  = (u16*)  alloc((size_t)VOCP * 512 * 2);
    u16*   A34   = (u16*)  alloc((size_t)VOCP * 1536 * 2);
    u16*   Adwew = (u16*)  alloc((size_t)1024 * 1536 * 2);
    u16*   Wihb  = (u16*)  alloc((size_t)3072 * 512 * 2);
    u16*   WhhB  = (u16*)  alloc((size_t)3072 * 1024 * 2);
    u16*   h0b   = (u16*)  alloc((size_t)32 * 1024 * 2);
    u16*   BG    = (u16*)  alloc((size_t)2048 * 1536 * 2);
    u16*   BL    = (u16*)  alloc((size_t)2048 * 512 * 2);
    float* GI    = (float*)alloc((size_t)2048 * 3072 * 4);
    float* h0    = (float*)alloc((size_t)32 * 1024 * 4);
    float* sesinf= (float*)alloc((size_t)32 * 1024 * 4);
    float* gc    = (float*)alloc((size_t)32 * VOCP * 4);
    float* ksb   = (float*)alloc((size_t)32 * KSN * 4);
    float* lsek  = (float*)alloc(256);
    float* lse   = (float*)alloc((size_t)2048 * 4);
    unsigned* cnt= (unsigned*)alloc(256);
    float* pmax  = (float*)alloc((size_t)2048 * NTMP * 4);
    float* psum  = (float*)alloc((size_t)2048 * NTMP * 4);
    unsigned char* g8 = (unsigned char*)alloc((size_t)2048 * VOCP);   // aliased: kvwb
    u16*   Lb    = (u16*)  alloc((size_t)2048 * VOCP * 2);            // aliased: Awk
    u16*   Bsk   = (u16*)  alloc((size_t)128 * 2048 * 2);
    float* out = (float*)d_out;

    u16*   kvwb  = (u16*)g8;       // 8832*1024*2 = 18.1 MB <= g8 (102 MB)
    u16*   Awk   = Lb;             // 50048*2048*2 == Lb size

    hipMemsetAsync(cnt, 0, 4, stream);

    // weight conversions (early users of aliased buffers come first)
    k_cvt<<<dim3(VOC, 1), 256, 0, stream>>>(embed, Aemb, 512, 512, 512);
    k_cvt<<<dim3(VOC, 1), 256, 0, stream>>>(W3, A34, 1024, 1024, 1536);
    k_cvt<<<dim3(VOC, 1), 256, 0, stream>>>(W4, A34 + 1024, 512, 512, 1536);
    k_cvt<<<dim3(VOC, 1), 256, 0, stream>>>(W1, Awk, 1024, 1024, 2048);
    k_cvt<<<dim3(VOC, 1), 256, 0, stream>>>(W2, Awk + 1024, 1024, 1024, 2048);
    k_cvt<<<dim3(KSN, 1), 256, 0, stream>>>(kvw, kvwb, 1024, 1024, 1024);
    k_pad0<<<dim3(VOCP - VOC), 256, 0, stream>>>(Aemb, A34, Awk);
    k_padK<<<dim3(KSNP - KSN), 256, 0, stream>>>(kvwb);
    k_cvt<<<dim3(1024, 1), 256, 0, stream>>>(dw, Adwew, 1024, 1024, 1536);
    k_cvt<<<dim3(1024, 1), 256, 0, stream>>>(ew, Adwew + 1024, 512, 512, 1536);
    k_cvt<<<dim3(3072, 1), 256, 0, stream>>>(Wih, Wihb, 512, 512, 512);
    k_cvt<<<dim3(3072, 1), 256, 0, stream>>>(Whh, WhhB, 1024, 1024, 1024);
    k_bsk<<<dim3(128), 256, 0, stream>>>(ses, know, Bsk);

    k_gather<<<dim3(2048), 128, 0, stream>>>(embed, target, BG);
    k_h0_sesinf<<<dim3(32), 256, 0, stream>>>(ses, sdw, sdb, siw, h0, sesinf);
    k_cvt<<<dim3(32, 1), 256, 0, stream>>>(h0, h0b, 1024, 1024, 1024);

    // gc = [W1|W2] @ [ses|know]   (MFMA, n<32 valid)
    gemm_bt<4><<<dim3(1, NTM), 256, 0, stream>>>(Awk, 2048, Bsk, 2048, 2048,
                                                 nullptr, nullptr, gc, nullptr, nullptr, nullptr);
    // ks = kvw @ know   (MFMA, B = know half of Bsk)
    gemm_bt<5><<<dim3(1, 69), 256, 0, stream>>>(kvwb, 1024, Bsk + 1024, 2048, 1024,
                                                nullptr, nullptr, ksb, nullptr, nullptr, nullptr);
    k_lseknow<<<dim3(32), 256, 0, stream>>>(ksb, lsek);

    // GI = TE @ Wih.T + bih
    gemm_bt<0><<<dim3(16, 24), 256, 0, stream>>>(Wihb, 512, BG + 1024, 1536, 512,
                                                 bih, nullptr, GI, nullptr, nullptr, nullptr);
    // GRU recurrence: persistent barrier-free-pipeline MFMA kernel
    k_gru_m2<<<dim3(32), 256, 0, stream>>>(WhhB, GI, bhh, h0b, BG, cnt);
    // MX (maxout) -> BL
    gemm_bt<1><<<dim3(16, 8), 256, 0, stream>>>(Adwew, 1536, BG, 1536, 1536,
                                                sesinf, eb, nullptr, BL, nullptr, nullptr);
    // gate GEMM -> g8
    gemm_bt<2><<<dim3(16, NTM), 256, 0, stream>>>(A34, 1536, BG, 1536, 1536,
                                                  gc, nullptr, nullptr, nullptr, g8, nullptr);
    // logit GEMM -> Lb + partials
    gemm_bt<3><<<dim3(16, NTM), 256, 0, stream>>>(Aemb, 512, BL, 512, 512,
                                                  nullptr, nullptr, pmax, Lb, nullptr, psum);
    k_lse<<<dim3(2048), 256, 0, stream>>>(pmax, psum, lse);
    k_final<<<dim3(25, 2048), 256, 0, stream>>>(Lb, g8, lse, ksb, lsek, out);
}

// Round 7
// 2080.892 us; speedup vs baseline: 2.7889x; 1.0224x over previous
//
#include <hip/hip_runtime.h>

// Problem dims
constexpr int VOC  = 50005;
constexpr int VOCP = 50048;   // 391*128, padded vocab
constexpr int NTM  = 391;     // vocab tiles (128) for big GEMMs
constexpr int NTMP = 400;     // padded partial stride
constexpr int KSN  = 8784;    // KNOW-1
constexpr int KSNP = 8832;    // 69*128
constexpr float NPAD = 41221.0f;

typedef unsigned short u16;
typedef __attribute__((ext_vector_type(4))) float f32x4;
typedef __attribute__((ext_vector_type(8))) short bf16x8;

__device__ __forceinline__ float dot4(float4 a, float4 b) {
    return a.x*b.x + a.y*b.y + a.z*b.z + a.w*b.w;
}
__device__ __forceinline__ float sigmoidf_(float x) { return 1.0f / (1.0f + expf(-x)); }
__device__ __forceinline__ u16 f2bf(float f) {
    unsigned x = __float_as_uint(f);
    return (u16)((x + 0x7FFFu + ((x >> 16) & 1u)) >> 16);
}
__device__ __forceinline__ float bf2f(u16 u) { return __uint_as_float(((unsigned)u) << 16); }
__device__ __forceinline__ void gload_lds16(const void* g, void* l) {
    __builtin_amdgcn_global_load_lds((const __attribute__((address_space(1))) unsigned int*)g,
                                     (__attribute__((address_space(3))) unsigned int*)l, 16, 0, 0);
}

// ---------------------------------------------------------------- cvt fp32 -> bf16 (strided)
__global__ __launch_bounds__(256) void k_cvt(const float* __restrict__ src, u16* __restrict__ dst,
                                             int ncols, int sld, int dld) {
    int row = blockIdx.x;
    int c = (blockIdx.y * 256 + threadIdx.x) * 4;
    if (c >= ncols) return;
    float4 v = *(const float4*)(src + (size_t)row * sld + c);
    unsigned lo = f2bf(v.x) | ((unsigned)f2bf(v.y) << 16);
    unsigned hi = f2bf(v.z) | ((unsigned)f2bf(v.w) << 16);
    *(uint2*)(dst + (size_t)row * dld + c) = make_uint2(lo, hi);
}

// zero pad rows 50005..50047 of Aemb / A34 / Awk
__global__ __launch_bounds__(256) void k_pad0(u16* __restrict__ Aemb, u16* __restrict__ A34,
                                              u16* __restrict__ Awk) {
    int r = VOC + blockIdx.x;
    unsigned* pe = (unsigned*)(Aemb + (size_t)r * 512);
    if (threadIdx.x < 256) pe[threadIdx.x] = 0;
    unsigned* p3 = (unsigned*)(A34 + (size_t)r * 1536);
    for (int i = threadIdx.x; i < 768; i += 256) p3[i] = 0;
    unsigned* pw = (unsigned*)(Awk + (size_t)r * 2048);
    for (int i = threadIdx.x; i < 1024; i += 256) pw[i] = 0;
}
// zero pad rows 8784..8831 of kvwb
__global__ __launch_bounds__(256) void k_padK(u16* __restrict__ kvwb) {
    int r = KSN + blockIdx.x;
    unsigned* p = (unsigned*)(kvwb + (size_t)r * 1024);
    for (int i = threadIdx.x; i < 512; i += 256) p[i] = 0;
}

// build Bsk [128][2048] bf16: rows 0..31 = [ses|know], rows 32..127 = 0
__global__ __launch_bounds__(256) void k_bsk(const float* __restrict__ ses,
                                             const float* __restrict__ know,
                                             u16* __restrict__ Bsk) {
    int row = blockIdx.x;
    for (int c0 = threadIdx.x * 4; c0 < 2048; c0 += 1024) {
        uint2 val = make_uint2(0, 0);
        if (row < 32) {
            const float* srcp = (c0 < 1024) ? ses + (size_t)row * 1024 + c0
                                            : know + (size_t)row * 1024 + (c0 - 1024);
            float4 v = *(const float4*)srcp;
            val = make_uint2(f2bf(v.x) | ((unsigned)f2bf(v.y) << 16),
                             f2bf(v.z) | ((unsigned)f2bf(v.w) << 16));
        }
        *(uint2*)(Bsk + (size_t)row * 2048 + c0) = val;
    }
}

// ---------------------------------------------------------------- gather target embeddings -> BG[:,1024:1536] bf16
__global__ __launch_bounds__(128) void k_gather(const float* __restrict__ embed,
                                                const int* __restrict__ target,
                                                u16* __restrict__ BG) {
    int n = blockIdx.x;
    int row = target[n];
    int c = threadIdx.x * 4;
    float4 v = *(const float4*)(embed + (size_t)row * 512 + c);
    unsigned lo = f2bf(v.x) | ((unsigned)f2bf(v.y) << 16);
    unsigned hi = f2bf(v.z) | ((unsigned)f2bf(v.w) << 16);
    *(uint2*)(BG + (size_t)n * 1536 + 1024 + c) = make_uint2(lo, hi);
}

// ------------------------------------------------- h0 + ses_inf_vec (fp32, small)
__global__ __launch_bounds__(256) void k_h0_sesinf(const float* __restrict__ ses,
                                                   const float* __restrict__ sdw,
                                                   const float* __restrict__ sdb,
                                                   const float* __restrict__ siw,
                                                   float* __restrict__ h0,
                                                   float* __restrict__ sesinf) {
    int g = blockIdx.x * 256 + threadIdx.x;
    int b = g & 31;
    int jg = g >> 5;
    int j0 = jg * 4;
    const float4* s4 = (const float4*)(ses + (size_t)b * 1024);
    const float4* wa[4];
    const float4* wc[4];
#pragma unroll
    for (int r = 0; r < 4; ++r) {
        wa[r] = (const float4*)(sdw + (size_t)(j0 + r) * 1024);
        wc[r] = (const float4*)(siw + (size_t)(j0 + r) * 1024);
    }
    float a[4] = {0, 0, 0, 0}, c[4] = {0, 0, 0, 0};
    for (int kq = 0; kq < 256; ++kq) {
        float4 sv = s4[kq];
#pragma unroll
        for (int r = 0; r < 4; ++r) { a[r] += dot4(sv, wa[r][kq]); c[r] += dot4(sv, wc[r][kq]); }
    }
#pragma unroll
    for (int r = 0; r < 4; ++r) {
        h0[b * 1024 + j0 + r] = tanhf(a[r] + sdb[j0 + r]);
        sesinf[b * 1024 + j0 + r] = c[r];
    }
}

// ------------------------------------------------- lse of padded know scores
__global__ __launch_bounds__(256) void k_lseknow(const float* __restrict__ ks,
                                                 float* __restrict__ lsek) {
    int b = blockIdx.x;
    int t = threadIdx.x;
    __shared__ float sm[256];
    float m = -1e30f;
    for (int j = t; j < KSN; j += 256) m = fmaxf(m, ks[(size_t)b * KSN + j]);
    sm[t] = m;
    __syncthreads();
    for (int s = 128; s > 0; s >>= 1) { if (t < s) sm[t] = fmaxf(sm[t], sm[t + s]); __syncthreads(); }
    m = fmaxf(sm[0], 0.0f);
    __syncthreads();
    float s = 0.0f;
    for (int j = t; j < KSN; j += 256) s += expf(ks[(size_t)b * KSN + j] - m);
    sm[t] = s;
    __syncthreads();
    for (int r = 128; r > 0; r >>= 1) { if (t < r) sm[t] += sm[t + r]; __syncthreads(); }
    if (t == 0) lsek[b] = m + logf(sm[0] + NPAD * expf(0.0f - m));
}

// ================================================= templated bf16 MFMA GEMM (C[m][n] = A[m]·B[n])
// EPI 0: GI (+bias, fp32)  EPI 1: MX maxout  EPI 2: gate (u8)  EPI 3: logits+partials
// EPI 4: gc fp32 [b][VOCP] (n<32)  EPI 5: ks fp32 [b][KSN] (n<32, m<KSN)
template<int EPI>
__global__ __launch_bounds__(256) void gemm_bt(
    const u16* __restrict__ A, int lda,
    const u16* __restrict__ B, int ldb, int K,
    const float* __restrict__ p0, const float* __restrict__ p1,
    float* __restrict__ q0, u16* __restrict__ q1,
    unsigned char* __restrict__ q2, float* __restrict__ q3)
{
    __shared__ u16 Asm[128 * 64];
    __shared__ u16 Bsm[128 * 64];
    const int tid = threadIdx.x;
    const int lane = tid & 63;
    const int w = tid >> 6;
    const int wm = w >> 1, wn = w & 1;
    const int nt = blockIdx.x, mt = blockIdx.y;

    f32x4 acc[4][4];
#pragma unroll
    for (int i = 0; i < 4; ++i)
#pragma unroll
        for (int j = 0; j < 4; ++j) acc[i][j] = (f32x4){0.f, 0.f, 0.f, 0.f};

    for (int kt = 0; kt < K; kt += 64) {
#pragma unroll
        for (int p = 0; p < 4; ++p) {
            int flat = (w * 4 + p) * 64 + lane;       // 0..1023 16B-slots
            int row = flat >> 3, slot = flat & 7;
            int ss = slot ^ (row & 7);                // inverse-swizzled source slot
            gload_lds16(A + (size_t)(mt * 128 + row) * lda + kt + ss * 8, Asm + flat * 8);
            gload_lds16(B + (size_t)(nt * 128 + row) * ldb + kt + ss * 8, Bsm + flat * 8);
        }
        __syncthreads();
#pragma unroll
        for (int kc = 0; kc < 2; ++kc) {
            bf16x8 af[4], bfr[4];
#pragma unroll
            for (int mi = 0; mi < 4; ++mi) {
                int row = wm * 64 + mi * 16 + (lane & 15);
                int bcol = kc * 64 + ((lane >> 4) << 4);
                af[mi] = *(const bf16x8*)((const char*)Asm + row * 128 + (bcol ^ ((row & 7) << 4)));
            }
#pragma unroll
            for (int ni = 0; ni < 4; ++ni) {
                int row = wn * 64 + ni * 16 + (lane & 15);
                int bcol = kc * 64 + ((lane >> 4) << 4);
                bfr[ni] = *(const bf16x8*)((const char*)Bsm + row * 128 + (bcol ^ ((row & 7) << 4)));
            }
#pragma unroll
            for (int mi = 0; mi < 4; ++mi)
#pragma unroll
                for (int ni = 0; ni < 4; ++ni)
                    acc[mi][ni] = __builtin_amdgcn_mfma_f32_16x16x32_bf16(af[mi], bfr[ni], acc[mi][ni], 0, 0, 0);
        }
        __syncthreads();
    }

    const int cl = lane & 15;           // n offset within fragment
    const int rg = (lane >> 4) << 2;    // m base within fragment

    if constexpr (EPI == 0) {           // GI = TE@Wih.T + bih  (fp32 [n][3072])
#pragma unroll
        for (int mi = 0; mi < 4; ++mi) {
            int m0 = mt * 128 + wm * 64 + mi * 16 + rg;
            float4 bias = *(const float4*)(p0 + m0);
#pragma unroll
            for (int ni = 0; ni < 4; ++ni) {
                int n = nt * 128 + wn * 64 + ni * 16 + cl;
                float4 v;
                v.x = acc[mi][ni][0] + bias.x; v.y = acc[mi][ni][1] + bias.y;
                v.z = acc[mi][ni][2] + bias.z; v.w = acc[mi][ni][3] + bias.w;
                *(float4*)(q0 + (size_t)n * 3072 + m0) = v;
            }
        }
    }
    if constexpr (EPI == 1) {           // maxout -> BL bf16 [n][512]
#pragma unroll
        for (int mi = 0; mi < 4; ++mi) {
            int m0 = mt * 128 + wm * 64 + mi * 16 + rg;
            float4 eb4 = *(const float4*)(p1 + m0);
#pragma unroll
            for (int ni = 0; ni < 4; ++ni) {
                int n = nt * 128 + wn * 64 + ni * 16 + cl;
                int b = n >> 6;
                float v0 = acc[mi][ni][0] + p0[b * 1024 + m0 + 0] + eb4.x;
                float v1 = acc[mi][ni][1] + p0[b * 1024 + m0 + 1] + eb4.y;
                float v2 = acc[mi][ni][2] + p0[b * 1024 + m0 + 2] + eb4.z;
                float v3 = acc[mi][ni][3] + p0[b * 1024 + m0 + 3] + eb4.w;
                unsigned pk = f2bf(fmaxf(v0, v1)) | ((unsigned)f2bf(fmaxf(v2, v3)) << 16);
                *(unsigned*)(q1 + (size_t)n * 512 + (m0 >> 1)) = pk;
            }
        }
    }
    if constexpr (EPI == 2) {           // gate -> g8 u8 [n][VOCP]
#pragma unroll
        for (int mi = 0; mi < 4; ++mi) {
            int v0 = mt * 128 + wm * 64 + mi * 16 + rg;
#pragma unroll
            for (int ni = 0; ni < 4; ++ni) {
                int n = nt * 128 + wn * 64 + ni * 16 + cl;
                int b = n >> 6;
                float4 gcv = *(const float4*)(p0 + (size_t)b * VOCP + v0);
                unsigned pk = 0;
#pragma unroll
                for (int r = 0; r < 4; ++r) {
                    float garg = acc[mi][ni][r] + ((const float*)&gcv)[r];
                    float gate = 1.0f / (1.0f + expf(-garg));
                    pk |= ((unsigned)(int)(gate * 255.0f + 0.5f)) << (8 * r);
                }
                *(unsigned*)(q2 + (size_t)n * VOCP + v0) = pk;
            }
        }
    }
    if constexpr (EPI == 3) {           // logits -> Lb bf16 [n][VOCP] + partial max/sumexp
        __shared__ float redm[2][128];
        __shared__ float reds[2][128];
#pragma unroll
        for (int mi = 0; mi < 4; ++mi) {
            int v0 = mt * 128 + wm * 64 + mi * 16 + rg;
#pragma unroll
            for (int ni = 0; ni < 4; ++ni) {
                int n = nt * 128 + wn * 64 + ni * 16 + cl;
                unsigned lo = f2bf(acc[mi][ni][0]) | ((unsigned)f2bf(acc[mi][ni][1]) << 16);
                unsigned hi = f2bf(acc[mi][ni][2]) | ((unsigned)f2bf(acc[mi][ni][3]) << 16);
                *(uint2*)(q1 + (size_t)n * VOCP + v0) = make_uint2(lo, hi);
            }
        }
#pragma unroll
        for (int ni = 0; ni < 4; ++ni) {
            float lm = -1e30f;
#pragma unroll
            for (int mi = 0; mi < 4; ++mi) {
                int v0 = mt * 128 + wm * 64 + mi * 16 + rg;
#pragma unroll
                for (int r = 0; r < 4; ++r)
                    if (v0 + r < VOC) lm = fmaxf(lm, acc[mi][ni][r]);
            }
            lm = fmaxf(lm, __shfl_xor(lm, 16));
            lm = fmaxf(lm, __shfl_xor(lm, 32));
            float s = 0.0f;
#pragma unroll
            for (int mi = 0; mi < 4; ++mi) {
                int v0 = mt * 128 + wm * 64 + mi * 16 + rg;
#pragma unroll
                for (int r = 0; r < 4; ++r)
                    if (v0 + r < VOC) s += expf(acc[mi][ni][r] - lm);
            }
            s += __shfl_xor(s, 16);
            s += __shfl_xor(s, 32);
            if (lane < 16) {
                redm[wm][wn * 64 + ni * 16 + lane] = lm;
                reds[wm][wn * 64 + ni * 16 + lane] = s;
            }
        }
        __syncthreads();
        if (tid < 128) {
            float m0_ = redm[0][tid], m1_ = redm[1][tid];
            float m = fmaxf(m0_, m1_);
            float s = reds[0][tid] * expf(m0_ - m) + reds[1][tid] * expf(m1_ - m);
            int n = nt * 128 + tid;
            q0[(size_t)n * NTMP + mt] = m;
            q3[(size_t)n * NTMP + mt] = s;
        }
    }
    if constexpr (EPI == 4) {           // gc fp32 [b][VOCP], only n<32 valid
#pragma unroll
        for (int mi = 0; mi < 4; ++mi) {
            int m0 = mt * 128 + wm * 64 + mi * 16 + rg;
#pragma unroll
            for (int ni = 0; ni < 4; ++ni) {
                int n = nt * 128 + wn * 64 + ni * 16 + cl;
                if (n < 32) {
                    float4 v;
                    v.x = acc[mi][ni][0]; v.y = acc[mi][ni][1];
                    v.z = acc[mi][ni][2]; v.w = acc[mi][ni][3];
                    *(float4*)(q0 + (size_t)n * VOCP + m0) = v;
                }
            }
        }
    }
    if constexpr (EPI == 5) {           // ks fp32 [b][KSN], n<32, m<KSN
#pragma unroll
        for (int mi = 0; mi < 4; ++mi) {
            int m0 = mt * 128 + wm * 64 + mi * 16 + rg;
#pragma unroll
            for (int ni = 0; ni < 4; ++ni) {
                int n = nt * 128 + wn * 64 + ni * 16 + cl;
                if (n < 32 && m0 < KSN) {
                    float4 v;
                    v.x = acc[mi][ni][0]; v.y = acc[mi][ni][1];
                    v.z = acc[mi][ni][2]; v.w = acc[mi][ni][3];
                    *(float4*)(q0 + (size_t)n * KSN + m0) = v;
                }
            }
        }
    }
}

// ------------------------------------------------- persistent MFMA GRU v3
// 32 blocks x 256 threads. BK=128 (8 chunks/step, halves sync count). Per-wave
// private A dbuf (48x128 bf16 x2 = 24 KB) + B dbuf (16x128 x2 = 8 KB); 128 KB LDS.
// Counted vmcnt pipeline, no intra-chunk syncthreads. Grid barrier = flag-array
// (parallel stores, all-thread polling) instead of serialized atomic RMW.
__global__ __launch_bounds__(256, 1) void k_gru_m3(const u16* __restrict__ WhhB,
                                                   const float* __restrict__ GI,
                                                   const float* __restrict__ bhh,
                                                   const u16* __restrict__ h0b,
                                                   u16* __restrict__ BG,
                                                   unsigned* __restrict__ flags) {
    __shared__ __align__(16) char smem[131072];
    const int tid = threadIdx.x;
    const int lane = tid & 63;
    const int w = tid >> 6;
    const int wm = w >> 1, wn = w & 1;
    const int jb = blockIdx.x;
    const int j0 = jb * 32;
    const int jl = tid & 31, grp = tid >> 5;
    const int je = j0 + jl;
    const float bh0 = bhh[je], bh1 = bhh[1024 + je], bh2 = bhh[2048 + je];

    char* Abase = smem + w * 24576;             // 2 bufs x 12288 B (48x128 bf16)
    char* Bbase = smem + 98304 + w * 8192;      // 2 bufs x 4096 B (16x128 bf16)
    float (*epi)[33] = (float(*)[33])smem;      // aliased on A region after chunks

    for (int t = 0; t < 64; ++t) {
        const u16* hsrc = (t == 0) ? h0b : BG + (size_t)(t - 1) * 1536;
        const size_t hstr = (t == 0) ? 1024 : (size_t)64 * 1536;

        // ---- prologue: GI + h_prev prefetch into registers (consumed in epilogue)
        float gi_r[4], gi_z[4], gi_n[4], hpv[4];
#pragma unroll
        for (int r = 0; r < 4; ++r) {
            int b = grp * 4 + r;
            const float* gp = GI + ((size_t)(b * 64 + t)) * 3072 + je;
            gi_r[r] = gp[0]; gi_z[r] = gp[1024]; gi_n[r] = gp[2048];
            hpv[r] = bf2f(hsrc[(size_t)b * hstr + je]);
        }

        auto stageA = [&](int c) {        // 12 gload_lds (48 rows x 256 B)
            char* dst = Abase + (c & 1) * 12288;
            int kt = c * 128;
#pragma unroll
            for (int q = 0; q < 12; ++q) {
                int s = q * 64 + lane;
                int rl = s >> 4;                      // 0..47 local row
                int cs = (s & 15) ^ (rl & 7);         // inverse-swizzled 16B src slot
                int pr = wm * 48 + rl;                // panel row 0..95
                int gr = (pr >> 5) * 1024 + j0 + (pr & 31);
                gload_lds16(WhhB + (size_t)gr * 1024 + kt + cs * 8, dst + q * 1024);
            }
        };
        auto stageB = [&](int c) {        // 4 gload_lds (16 rows x 256 B)
            char* dst = Bbase + (c & 1) * 4096;
            int kt = c * 128;
#pragma unroll
            for (int q = 0; q < 4; ++q) {
                int s = q * 64 + lane;
                int rl = s >> 4;                      // 0..15
                int cs = (s & 15) ^ (rl & 7);
                int b = wn * 16 + rl;
                gload_lds16(hsrc + (size_t)b * hstr + kt + cs * 8, dst + q * 1024);
            }
        };
        stageA(0); stageB(0); stageA(1); stageB(1);
        asm volatile("s_waitcnt vmcnt(16)" ::: "memory");   // chunk 0 landed
        __builtin_amdgcn_sched_barrier(0);

        f32x4 acc[3] = {{0.f,0.f,0.f,0.f},{0.f,0.f,0.f,0.f},{0.f,0.f,0.f,0.f}};
        const int colsel = (lane >> 4) << 4;   // byte col within 64B sub-chunk
        const int lrow = lane & 15;

#pragma unroll 2
        for (int c = 0; c < 8; ++c) {
            char* Ab = Abase + (c & 1) * 12288;
            char* Bb = Bbase + (c & 1) * 4096;
#pragma unroll
            for (int kc = 0; kc < 4; ++kc) {
                int cb = kc * 64 + colsel;
                bf16x8 bfr = *(const bf16x8*)(Bb + lrow * 256 + (cb ^ ((lrow & 7) << 4)));
                bf16x8 af[3];
#pragma unroll
                for (int mi = 0; mi < 3; ++mi) {
                    int ar = mi * 16 + lrow;
                    af[mi] = *(const bf16x8*)(Ab + ar * 256 + (cb ^ ((ar & 7) << 4)));
                }
#pragma unroll
                for (int mi = 0; mi < 3; ++mi)
                    acc[mi] = __builtin_amdgcn_mfma_f32_16x16x32_bf16(af[mi], bfr, acc[mi], 0, 0, 0);
            }
            // wave-local: ds_reads of this buffer complete before overwriting it
            asm volatile("s_waitcnt lgkmcnt(0)" ::: "memory");
            __builtin_amdgcn_sched_barrier(0);
            if (c < 6) {
                stageA(c + 2); stageB(c + 2);
                asm volatile("s_waitcnt vmcnt(16)" ::: "memory");   // chunk c+1 landed
            } else if (c == 6) {
                asm volatile("s_waitcnt vmcnt(0)" ::: "memory");    // chunk 7 landed
            }
            __builtin_amdgcn_sched_barrier(0);
        }

        // ---- gate exchange (epi aliases A bufs; raw barriers, no vmcnt drain)
        asm volatile("s_waitcnt lgkmcnt(0)" ::: "memory");
        __builtin_amdgcn_s_barrier();
        {
            const int cl = wn * 16 + lrow;
            const int rg = (lane >> 4) << 2;
#pragma unroll
            for (int mi = 0; mi < 3; ++mi) {
                int m0 = wm * 48 + mi * 16 + rg;
#pragma unroll
                for (int r = 0; r < 4; ++r) epi[m0 + r][cl] = acc[mi][r];
            }
        }
        asm volatile("s_waitcnt lgkmcnt(0)" ::: "memory");
        __builtin_amdgcn_s_barrier();
#pragma unroll
        for (int r = 0; r < 4; ++r) {
            int b = grp * 4 + r;
            float ar = epi[jl][b];
            float az = epi[32 + jl][b];
            float an = epi[64 + jl][b];
            float rr = sigmoidf_(gi_r[r] + ar + bh0);
            float zz = sigmoidf_(gi_z[r] + az + bh1);
            float nn = tanhf(gi_n[r] + rr * (an + bh2));
            float hnew = (1.0f - zz) * nn + zz * hpv[r];
            BG[((size_t)(b * 64 + t)) * 1536 + je] = f2bf(hnew);
        }

        if (t < 63) {
            __threadfence();                 // release: h visible device-wide
            __syncthreads();                 // all block threads arrived
            if (tid == 0)
                __hip_atomic_store(&flags[jb], (unsigned)(t + 1),
                                   __ATOMIC_RELAXED, __HIP_MEMORY_SCOPE_AGENT);
            unsigned tgt = (unsigned)(t + 1);
            while (true) {
                unsigned v = __hip_atomic_load(&flags[lane & 31],
                                               __ATOMIC_RELAXED, __HIP_MEMORY_SCOPE_AGENT);
                if (__all(v >= tgt)) break;
                __builtin_amdgcn_s_sleep(1);
            }
            __threadfence();                 // acquire: invalidate stale L2 lines
        } else {
            __syncthreads();
        }
    }
}

// ------------------------------------------------- per-row lse from partials
__global__ __launch_bounds__(256) void k_lse(const float* __restrict__ pmax,
                                             const float* __restrict__ psum,
                                             float* __restrict__ lse) {
    int n = blockIdx.x;
    int t = threadIdx.x;
    __shared__ float sm[256];
    const float* pm = pmax + (size_t)n * NTMP;
    const float* ps = psum + (size_t)n * NTMP;
    float m = -1e30f;
    for (int p = t; p < NTM; p += 256) m = fmaxf(m, pm[p]);
    sm[t] = m;
    __syncthreads();
    for (int s = 128; s > 0; s >>= 1) { if (t < s) sm[t] = fmaxf(sm[t], sm[t + s]); __syncthreads(); }
    m = sm[0];
    __syncthreads();
    float s = 0.0f;
    for (int p = t; p < NTM; p += 256) s += ps[p] * expf(pm[p] - m);
    sm[t] = s;
    __syncthreads();
    for (int r = 128; r > 0; r >>= 1) { if (t < r) sm[t] += sm[t + r]; __syncthreads(); }
    if (t == 0) lse[n] = m + logf(sm[0]);
}

// ------------------------------------------------- final combine (fully coalesced)
__global__ __launch_bounds__(256) void k_final(const u16* __restrict__ Lb,
                                               const unsigned char* __restrict__ g8,
                                               const float* __restrict__ lse,
                                               const float* __restrict__ ks,
                                               const float* __restrict__ lsek,
                                               float* __restrict__ out) {
    int n = blockIdx.y;
    int b = n >> 6;
    float lsen = lse[n], lkb = lsek[b];
    int base = blockIdx.x * 2048;
#pragma unroll
    for (int i = 0; i < 8; ++i) {
        int v = base + i * 256 + threadIdx.x;
        if (v < VOC) {
            float L = bf2f(Lb[(size_t)n * VOCP + v]);
            float g = g8[(size_t)n * VOCP + v] * (1.0f / 255.0f);
            float kp = ((v >= 10 && v < 10 + KSN) ? ks[(size_t)b * KSN + (v - 10)] : 0.0f) - lkb;
            out[(size_t)n * VOC + v] = g * (L - lsen) + (1.0f - g) * kp;
        }
    }
}

// ---------------------------------------------------------------- launch
extern "C" void kernel_launch(void* const* d_in, const int* in_sizes, int n_in,
                              void* d_out, int out_size, void* d_ws, size_t ws_size,
                              hipStream_t stream) {
    const float* ses    = (const float*)d_in[0];
    const float* know   = (const float*)d_in[1];
    const int*   target = (const int*)d_in[2];
    const float* embed  = (const float*)d_in[3];
    const float* Wih    = (const float*)d_in[4];
    const float* Whh    = (const float*)d_in[5];
    const float* bih    = (const float*)d_in[6];
    const float* bhh    = (const float*)d_in[7];
    const float* sdw    = (const float*)d_in[8];
    const float* sdb    = (const float*)d_in[9];
    const float* dw     = (const float*)d_in[10];
    const float* siw    = (const float*)d_in[11];
    const float* ew     = (const float*)d_in[12];
    const float* eb     = (const float*)d_in[13];
    const float* W1     = (const float*)d_in[14];
    const float* W2     = (const float*)d_in[15];
    const float* W3     = (const float*)d_in[16];
    const float* W4     = (const float*)d_in[17];
    const float* kvw    = (const float*)d_in[18];

    char* ws = (char*)d_ws;
    size_t o = 0;
    auto alloc = [&](size_t bytes) { char* r = ws + o; o += (bytes + 255) & ~(size_t)255; return r; };
    u16*   Aemb  = (u16*)  alloc((size_t)VOCP * 512 * 2);
    u16*   A34   = (u16*)  alloc((size_t)VOCP * 1536 * 2);
    u16*   Adwew = (u16*)  alloc((size_t)1024 * 1536 * 2);
    u16*   Wihb  = (u16*)  alloc((size_t)3072 * 512 * 2);
    u16*   WhhB  = (u16*)  alloc((size_t)3072 * 1024 * 2);
    u16*   h0b   = (u16*)  alloc((size_t)32 * 1024 * 2);
    u16*   BG    = (u16*)  alloc((size_t)2048 * 1536 * 2);
    u16*   BL    = (u16*)  alloc((size_t)2048 * 512 * 2);
    float* GI    = (float*)alloc((size_t)2048 * 3072 * 4);
    float* h0    = (float*)alloc((size_t)32 * 1024 * 4);
    float* sesinf= (float*)alloc((size_t)32 * 1024 * 4);
    float* gc    = (float*)alloc((size_t)32 * VOCP * 4);
    float* ksb   = (float*)alloc((size_t)32 * KSN * 4);
    float* lsek  = (float*)alloc(256);
    float* lse   = (float*)alloc((size_t)2048 * 4);
    unsigned* flags = (unsigned*)alloc(256);
    float* pmax  = (float*)alloc((size_t)2048 * NTMP * 4);
    float* psum  = (float*)alloc((size_t)2048 * NTMP * 4);
    unsigned char* g8 = (unsigned char*)alloc((size_t)2048 * VOCP);   // aliased: kvwb
    u16*   Lb    = (u16*)  alloc((size_t)2048 * VOCP * 2);            // aliased: Awk
    u16*   Bsk   = (u16*)  alloc((size_t)128 * 2048 * 2);
    float* out = (float*)d_out;

    u16*   kvwb  = (u16*)g8;       // 8832*1024*2 = 18.1 MB <= g8 (102 MB)
    u16*   Awk   = Lb;             // 50048*2048*2 == Lb size

    hipMemsetAsync(flags, 0, 128, stream);

    // weight conversions (early users of aliased buffers come first)
    k_cvt<<<dim3(VOC, 1), 256, 0, stream>>>(embed, Aemb, 512, 512, 512);
    k_cvt<<<dim3(VOC, 1), 256, 0, stream>>>(W3, A34, 1024, 1024, 1536);
    k_cvt<<<dim3(VOC, 1), 256, 0, stream>>>(W4, A34 + 1024, 512, 512, 1536);
    k_cvt<<<dim3(VOC, 1), 256, 0, stream>>>(W1, Awk, 1024, 1024, 2048);
    k_cvt<<<dim3(VOC, 1), 256, 0, stream>>>(W2, Awk + 1024, 1024, 1024, 2048);
    k_cvt<<<dim3(KSN, 1), 256, 0, stream>>>(kvw, kvwb, 1024, 1024, 1024);
    k_pad0<<<dim3(VOCP - VOC), 256, 0, stream>>>(Aemb, A34, Awk);
    k_padK<<<dim3(KSNP - KSN), 256, 0, stream>>>(kvwb);
    k_cvt<<<dim3(1024, 1), 256, 0, stream>>>(dw, Adwew, 1024, 1024, 1536);
    k_cvt<<<dim3(1024, 1), 256, 0, stream>>>(ew, Adwew + 1024, 512, 512, 1536);
    k_cvt<<<dim3(3072, 1), 256, 0, stream>>>(Wih, Wihb, 512, 512, 512);
    k_cvt<<<dim3(3072, 1), 256, 0, stream>>>(Whh, WhhB, 1024, 1024, 1024);
    k_bsk<<<dim3(128), 256, 0, stream>>>(ses, know, Bsk);

    k_gather<<<dim3(2048), 128, 0, stream>>>(embed, target, BG);
    k_h0_sesinf<<<dim3(32), 256, 0, stream>>>(ses, sdw, sdb, siw, h0, sesinf);
    k_cvt<<<dim3(32, 1), 256, 0, stream>>>(h0, h0b, 1024, 1024, 1024);

    // gc = [W1|W2] @ [ses|know]   (MFMA, n<32 valid)
    gemm_bt<4><<<dim3(1, NTM), 256, 0, stream>>>(Awk, 2048, Bsk, 2048, 2048,
                                                 nullptr, nullptr, gc, nullptr, nullptr, nullptr);
    // ks = kvw @ know   (MFMA, B = know half of Bsk)
    gemm_bt<5><<<dim3(1, 69), 256, 0, stream>>>(kvwb, 1024, Bsk + 1024, 2048, 1024,
                                                nullptr, nullptr, ksb, nullptr, nullptr, nullptr);
    k_lseknow<<<dim3(32), 256, 0, stream>>>(ksb, lsek);

    // GI = TE @ Wih.T + bih
    gemm_bt<0><<<dim3(16, 24), 256, 0, stream>>>(Wihb, 512, BG + 1024, 1536, 512,
                                                 bih, nullptr, GI, nullptr, nullptr, nullptr);
    // GRU recurrence: persistent MFMA kernel, flag-array grid barrier
    k_gru_m3<<<dim3(32), 256, 0, stream>>>(WhhB, GI, bhh, h0b, BG, flags);
    // MX (maxout) -> BL
    gemm_bt<1><<<dim3(16, 8), 256, 0, stream>>>(Adwew, 1536, BG, 1536, 1536,
                                                sesinf, eb, nullptr, BL, nullptr, nullptr);
    // gate GEMM -> g8
    gemm_bt<2><<<dim3(16, NTM), 256, 0, stream>>>(A34, 1536, BG, 1536, 1536,
                                                  gc, nullptr, nullptr, nullptr, g8, nullptr);
    // logit GEMM -> Lb + partials
    gemm_bt<3><<<dim3(16, NTM), 256, 0, stream>>>(Aemb, 512, BL, 512, 512,
                                                  nullptr, nullptr, pmax, Lb, nullptr, psum);
    k_lse<<<dim3(2048), 256, 0, stream>>>(pmax, psum, lse);
    k_final<<<dim3(25, 2048), 256, 0, stream>>>(Lb, g8, lse, ksb, lsek, out);
}

// Round 8
// 1680.497 us; speedup vs baseline: 3.4534x; 1.2383x over previous
//
#include <hip/hip_runtime.h>

// Problem dims
constexpr int VOC  = 50005;
constexpr int VOCP = 50048;   // 391*128, padded vocab
constexpr int NTM  = 391;     // vocab tiles (128) for big GEMMs
constexpr int NTMP = 400;     // padded partial stride
constexpr int KSN  = 8784;    // KNOW-1
constexpr int KSNP = 8832;    // 69*128
constexpr float NPAD = 41221.0f;

typedef unsigned short u16;
typedef __attribute__((ext_vector_type(4))) float f32x4;
typedef __attribute__((ext_vector_type(8))) short bf16x8;

__device__ __forceinline__ float dot4(float4 a, float4 b) {
    return a.x*b.x + a.y*b.y + a.z*b.z + a.w*b.w;
}
__device__ __forceinline__ float sigmoidf_(float x) { return 1.0f / (1.0f + expf(-x)); }
__device__ __forceinline__ u16 f2bf(float f) {
    unsigned x = __float_as_uint(f);
    return (u16)((x + 0x7FFFu + ((x >> 16) & 1u)) >> 16);
}
__device__ __forceinline__ float bf2f(u16 u) { return __uint_as_float(((unsigned)u) << 16); }
template<int AUX>
__device__ __forceinline__ void gload_lds16x(const void* g, void* l) {
    __builtin_amdgcn_global_load_lds((const __attribute__((address_space(1))) unsigned int*)g,
                                     (__attribute__((address_space(3))) unsigned int*)l, 16, 0, AUX);
}
__device__ __forceinline__ void gload_lds16(const void* g, void* l) { gload_lds16x<0>(g, l); }
// device-coherent u16 store (write-through to coherence point, cross-XCD visible)
__device__ __forceinline__ void store_u16_sc(u16* p, u16 v) {
    asm volatile("global_store_short %0, %1, off sc0 sc1" :: "v"(p), "v"((unsigned)v) : "memory");
}

// ---------------------------------------------------------------- cvt fp32 -> bf16 (strided)
__global__ __launch_bounds__(256) void k_cvt(const float* __restrict__ src, u16* __restrict__ dst,
                                             int ncols, int sld, int dld) {
    int row = blockIdx.x;
    int c = (blockIdx.y * 256 + threadIdx.x) * 4;
    if (c >= ncols) return;
    float4 v = *(const float4*)(src + (size_t)row * sld + c);
    unsigned lo = f2bf(v.x) | ((unsigned)f2bf(v.y) << 16);
    unsigned hi = f2bf(v.z) | ((unsigned)f2bf(v.w) << 16);
    *(uint2*)(dst + (size_t)row * dld + c) = make_uint2(lo, hi);
}

// zero pad rows 50005..50047 of Aemb / A34 / Awk
__global__ __launch_bounds__(256) void k_pad0(u16* __restrict__ Aemb, u16* __restrict__ A34,
                                              u16* __restrict__ Awk) {
    int r = VOC + blockIdx.x;
    unsigned* pe = (unsigned*)(Aemb + (size_t)r * 512);
    if (threadIdx.x < 256) pe[threadIdx.x] = 0;
    unsigned* p3 = (unsigned*)(A34 + (size_t)r * 1536);
    for (int i = threadIdx.x; i < 768; i += 256) p3[i] = 0;
    unsigned* pw = (unsigned*)(Awk + (size_t)r * 2048);
    for (int i = threadIdx.x; i < 1024; i += 256) pw[i] = 0;
}
// zero pad rows 8784..8831 of kvwb
__global__ __launch_bounds__(256) void k_padK(u16* __restrict__ kvwb) {
    int r = KSN + blockIdx.x;
    unsigned* p = (unsigned*)(kvwb + (size_t)r * 1024);
    for (int i = threadIdx.x; i < 512; i += 256) p[i] = 0;
}

// build Bsk [128][2048] bf16: rows 0..31 = [ses|know], rows 32..127 = 0
__global__ __launch_bounds__(256) void k_bsk(const float* __restrict__ ses,
                                             const float* __restrict__ know,
                                             u16* __restrict__ Bsk) {
    int row = blockIdx.x;
    for (int c0 = threadIdx.x * 4; c0 < 2048; c0 += 1024) {
        uint2 val = make_uint2(0, 0);
        if (row < 32) {
            const float* srcp = (c0 < 1024) ? ses + (size_t)row * 1024 + c0
                                            : know + (size_t)row * 1024 + (c0 - 1024);
            float4 v = *(const float4*)srcp;
            val = make_uint2(f2bf(v.x) | ((unsigned)f2bf(v.y) << 16),
                             f2bf(v.z) | ((unsigned)f2bf(v.w) << 16));
        }
        *(uint2*)(Bsk + (size_t)row * 2048 + c0) = val;
    }
}

// ---------------------------------------------------------------- gather target embeddings -> BG[:,1024:1536] bf16
__global__ __launch_bounds__(128) void k_gather(const float* __restrict__ embed,
                                                const int* __restrict__ target,
                                                u16* __restrict__ BG) {
    int n = blockIdx.x;
    int row = target[n];
    int c = threadIdx.x * 4;
    float4 v = *(const float4*)(embed + (size_t)row * 512 + c);
    unsigned lo = f2bf(v.x) | ((unsigned)f2bf(v.y) << 16);
    unsigned hi = f2bf(v.z) | ((unsigned)f2bf(v.w) << 16);
    *(uint2*)(BG + (size_t)n * 1536 + 1024 + c) = make_uint2(lo, hi);
}

// ------------------------------------------------- h0 + ses_inf_vec (fp32, small)
__global__ __launch_bounds__(256) void k_h0_sesinf(const float* __restrict__ ses,
                                                   const float* __restrict__ sdw,
                                                   const float* __restrict__ sdb,
                                                   const float* __restrict__ siw,
                                                   float* __restrict__ h0,
                                                   float* __restrict__ sesinf) {
    int g = blockIdx.x * 256 + threadIdx.x;
    int b = g & 31;
    int jg = g >> 5;
    int j0 = jg * 4;
    const float4* s4 = (const float4*)(ses + (size_t)b * 1024);
    const float4* wa[4];
    const float4* wc[4];
#pragma unroll
    for (int r = 0; r < 4; ++r) {
        wa[r] = (const float4*)(sdw + (size_t)(j0 + r) * 1024);
        wc[r] = (const float4*)(siw + (size_t)(j0 + r) * 1024);
    }
    float a[4] = {0, 0, 0, 0}, c[4] = {0, 0, 0, 0};
    for (int kq = 0; kq < 256; ++kq) {
        float4 sv = s4[kq];
#pragma unroll
        for (int r = 0; r < 4; ++r) { a[r] += dot4(sv, wa[r][kq]); c[r] += dot4(sv, wc[r][kq]); }
    }
#pragma unroll
    for (int r = 0; r < 4; ++r) {
        h0[b * 1024 + j0 + r] = tanhf(a[r] + sdb[j0 + r]);
        sesinf[b * 1024 + j0 + r] = c[r];
    }
}

// ------------------------------------------------- lse of padded know scores
__global__ __launch_bounds__(256) void k_lseknow(const float* __restrict__ ks,
                                                 float* __restrict__ lsek) {
    int b = blockIdx.x;
    int t = threadIdx.x;
    __shared__ float sm[256];
    float m = -1e30f;
    for (int j = t; j < KSN; j += 256) m = fmaxf(m, ks[(size_t)b * KSN + j]);
    sm[t] = m;
    __syncthreads();
    for (int s = 128; s > 0; s >>= 1) { if (t < s) sm[t] = fmaxf(sm[t], sm[t + s]); __syncthreads(); }
    m = fmaxf(sm[0], 0.0f);
    __syncthreads();
    float s = 0.0f;
    for (int j = t; j < KSN; j += 256) s += expf(ks[(size_t)b * KSN + j] - m);
    sm[t] = s;
    __syncthreads();
    for (int r = 128; r > 0; r >>= 1) { if (t < r) sm[t] += sm[t + r]; __syncthreads(); }
    if (t == 0) lsek[b] = m + logf(sm[0] + NPAD * expf(0.0f - m));
}

// ================================================= templated bf16 MFMA GEMM (C[m][n] = A[m]·B[n])
// EPI 0: GI (+bias, fp32)  EPI 1: MX maxout  EPI 2: gate (u8)  EPI 3: logits+partials
// EPI 4: gc fp32 [b][VOCP] (n<32)  EPI 5: ks fp32 [b][KSN] (n<32, m<KSN)
template<int EPI>
__global__ __launch_bounds__(256) void gemm_bt(
    const u16* __restrict__ A, int lda,
    const u16* __restrict__ B, int ldb, int K,
    const float* __restrict__ p0, const float* __restrict__ p1,
    float* __restrict__ q0, u16* __restrict__ q1,
    unsigned char* __restrict__ q2, float* __restrict__ q3)
{
    __shared__ u16 Asm[128 * 64];
    __shared__ u16 Bsm[128 * 64];
    const int tid = threadIdx.x;
    const int lane = tid & 63;
    const int w = tid >> 6;
    const int wm = w >> 1, wn = w & 1;
    const int nt = blockIdx.x, mt = blockIdx.y;

    f32x4 acc[4][4];
#pragma unroll
    for (int i = 0; i < 4; ++i)
#pragma unroll
        for (int j = 0; j < 4; ++j) acc[i][j] = (f32x4){0.f, 0.f, 0.f, 0.f};

    for (int kt = 0; kt < K; kt += 64) {
#pragma unroll
        for (int p = 0; p < 4; ++p) {
            int flat = (w * 4 + p) * 64 + lane;       // 0..1023 16B-slots
            int row = flat >> 3, slot = flat & 7;
            int ss = slot ^ (row & 7);                // inverse-swizzled source slot
            gload_lds16(A + (size_t)(mt * 128 + row) * lda + kt + ss * 8, Asm + flat * 8);
            gload_lds16(B + (size_t)(nt * 128 + row) * ldb + kt + ss * 8, Bsm + flat * 8);
        }
        __syncthreads();
#pragma unroll
        for (int kc = 0; kc < 2; ++kc) {
            bf16x8 af[4], bfr[4];
#pragma unroll
            for (int mi = 0; mi < 4; ++mi) {
                int row = wm * 64 + mi * 16 + (lane & 15);
                int bcol = kc * 64 + ((lane >> 4) << 4);
                af[mi] = *(const bf16x8*)((const char*)Asm + row * 128 + (bcol ^ ((row & 7) << 4)));
            }
#pragma unroll
            for (int ni = 0; ni < 4; ++ni) {
                int row = wn * 64 + ni * 16 + (lane & 15);
                int bcol = kc * 64 + ((lane >> 4) << 4);
                bfr[ni] = *(const bf16x8*)((const char*)Bsm + row * 128 + (bcol ^ ((row & 7) << 4)));
            }
#pragma unroll
            for (int mi = 0; mi < 4; ++mi)
#pragma unroll
                for (int ni = 0; ni < 4; ++ni)
                    acc[mi][ni] = __builtin_amdgcn_mfma_f32_16x16x32_bf16(af[mi], bfr[ni], acc[mi][ni], 0, 0, 0);
        }
        __syncthreads();
    }

    const int cl = lane & 15;           // n offset within fragment
    const int rg = (lane >> 4) << 2;    // m base within fragment

    if constexpr (EPI == 0) {           // GI = TE@Wih.T + bih  (fp32 [n][3072])
#pragma unroll
        for (int mi = 0; mi < 4; ++mi) {
            int m0 = mt * 128 + wm * 64 + mi * 16 + rg;
            float4 bias = *(const float4*)(p0 + m0);
#pragma unroll
            for (int ni = 0; ni < 4; ++ni) {
                int n = nt * 128 + wn * 64 + ni * 16 + cl;
                float4 v;
                v.x = acc[mi][ni][0] + bias.x; v.y = acc[mi][ni][1] + bias.y;
                v.z = acc[mi][ni][2] + bias.z; v.w = acc[mi][ni][3] + bias.w;
                *(float4*)(q0 + (size_t)n * 3072 + m0) = v;
            }
        }
    }
    if constexpr (EPI == 1) {           // maxout -> BL bf16 [n][512]
#pragma unroll
        for (int mi = 0; mi < 4; ++mi) {
            int m0 = mt * 128 + wm * 64 + mi * 16 + rg;
            float4 eb4 = *(const float4*)(p1 + m0);
#pragma unroll
            for (int ni = 0; ni < 4; ++ni) {
                int n = nt * 128 + wn * 64 + ni * 16 + cl;
                int b = n >> 6;
                float v0 = acc[mi][ni][0] + p0[b * 1024 + m0 + 0] + eb4.x;
                float v1 = acc[mi][ni][1] + p0[b * 1024 + m0 + 1] + eb4.y;
                float v2 = acc[mi][ni][2] + p0[b * 1024 + m0 + 2] + eb4.z;
                float v3 = acc[mi][ni][3] + p0[b * 1024 + m0 + 3] + eb4.w;
                unsigned pk = f2bf(fmaxf(v0, v1)) | ((unsigned)f2bf(fmaxf(v2, v3)) << 16);
                *(unsigned*)(q1 + (size_t)n * 512 + (m0 >> 1)) = pk;
            }
        }
    }
    if constexpr (EPI == 2) {           // gate -> g8 u8 [n][VOCP]
#pragma unroll
        for (int mi = 0; mi < 4; ++mi) {
            int v0 = mt * 128 + wm * 64 + mi * 16 + rg;
#pragma unroll
            for (int ni = 0; ni < 4; ++ni) {
                int n = nt * 128 + wn * 64 + ni * 16 + cl;
                int b = n >> 6;
                float4 gcv = *(const float4*)(p0 + (size_t)b * VOCP + v0);
                unsigned pk = 0;
#pragma unroll
                for (int r = 0; r < 4; ++r) {
                    float garg = acc[mi][ni][r] + ((const float*)&gcv)[r];
                    float gate = 1.0f / (1.0f + expf(-garg));
                    pk |= ((unsigned)(int)(gate * 255.0f + 0.5f)) << (8 * r);
                }
                *(unsigned*)(q2 + (size_t)n * VOCP + v0) = pk;
            }
        }
    }
    if constexpr (EPI == 3) {           // logits -> Lb bf16 [n][VOCP] + partial max/sumexp
        __shared__ float redm[2][128];
        __shared__ float reds[2][128];
#pragma unroll
        for (int mi = 0; mi < 4; ++mi) {
            int v0 = mt * 128 + wm * 64 + mi * 16 + rg;
#pragma unroll
            for (int ni = 0; ni < 4; ++ni) {
                int n = nt * 128 + wn * 64 + ni * 16 + cl;
                unsigned lo = f2bf(acc[mi][ni][0]) | ((unsigned)f2bf(acc[mi][ni][1]) << 16);
                unsigned hi = f2bf(acc[mi][ni][2]) | ((unsigned)f2bf(acc[mi][ni][3]) << 16);
                *(uint2*)(q1 + (size_t)n * VOCP + v0) = make_uint2(lo, hi);
            }
        }
#pragma unroll
        for (int ni = 0; ni < 4; ++ni) {
            float lm = -1e30f;
#pragma unroll
            for (int mi = 0; mi < 4; ++mi) {
                int v0 = mt * 128 + wm * 64 + mi * 16 + rg;
#pragma unroll
                for (int r = 0; r < 4; ++r)
                    if (v0 + r < VOC) lm = fmaxf(lm, acc[mi][ni][r]);
            }
            lm = fmaxf(lm, __shfl_xor(lm, 16));
            lm = fmaxf(lm, __shfl_xor(lm, 32));
            float s = 0.0f;
#pragma unroll
            for (int mi = 0; mi < 4; ++mi) {
                int v0 = mt * 128 + wm * 64 + mi * 16 + rg;
#pragma unroll
                for (int r = 0; r < 4; ++r)
                    if (v0 + r < VOC) s += expf(acc[mi][ni][r] - lm);
            }
            s += __shfl_xor(s, 16);
            s += __shfl_xor(s, 32);
            if (lane < 16) {
                redm[wm][wn * 64 + ni * 16 + lane] = lm;
                reds[wm][wn * 64 + ni * 16 + lane] = s;
            }
        }
        __syncthreads();
        if (tid < 128) {
            float m0_ = redm[0][tid], m1_ = redm[1][tid];
            float m = fmaxf(m0_, m1_);
            float s = reds[0][tid] * expf(m0_ - m) + reds[1][tid] * expf(m1_ - m);
            int n = nt * 128 + tid;
            q0[(size_t)n * NTMP + mt] = m;
            q3[(size_t)n * NTMP + mt] = s;
        }
    }
    if constexpr (EPI == 4) {           // gc fp32 [b][VOCP], only n<32 valid
#pragma unroll
        for (int mi = 0; mi < 4; ++mi) {
            int m0 = mt * 128 + wm * 64 + mi * 16 + rg;
#pragma unroll
            for (int ni = 0; ni < 4; ++ni) {
                int n = nt * 128 + wn * 64 + ni * 16 + cl;
                if (n < 32) {
                    float4 v;
                    v.x = acc[mi][ni][0]; v.y = acc[mi][ni][1];
                    v.z = acc[mi][ni][2]; v.w = acc[mi][ni][3];
                    *(float4*)(q0 + (size_t)n * VOCP + m0) = v;
                }
            }
        }
    }
    if constexpr (EPI == 5) {           // ks fp32 [b][KSN], n<32, m<KSN
#pragma unroll
        for (int mi = 0; mi < 4; ++mi) {
            int m0 = mt * 128 + wm * 64 + mi * 16 + rg;
#pragma unroll
            for (int ni = 0; ni < 4; ++ni) {
                int n = nt * 128 + wn * 64 + ni * 16 + cl;
                if (n < 32 && m0 < KSN) {
                    float4 v;
                    v.x = acc[mi][ni][0]; v.y = acc[mi][ni][1];
                    v.z = acc[mi][ni][2]; v.w = acc[mi][ni][3];
                    *(float4*)(q0 + (size_t)n * KSN + m0) = v;
                }
            }
        }
    }
}

// ------------------------------------------------- persistent MFMA GRU v4
// 64 blocks x 256 threads, 1 block/CU. Block owns 16 j's; A panel (48x1024 bf16 =
// 96 KB) staged in LDS ONCE. Waves split K (256 cols each); per step only h is
// staged (4 wave-private 32x64 chunks, counted vmcnt, no barriers). Cross-wave
// K-reduction via per-wave epi regions (aliased on own B bufs). h exchanged via
// sc0/sc1 device-coherent stores/loads -> NO threadfence, L2 stays warm.
// h_prev carried in registers. Flag-array grid barrier (64 flags, lane==block).
__global__ __launch_bounds__(256, 1) void k_gru_m4(const u16* __restrict__ WhhB,
                                                   const float* __restrict__ GI,
                                                   const float* __restrict__ bhh,
                                                   const u16* __restrict__ h0b,
                                                   u16* __restrict__ BG,
                                                   unsigned* __restrict__ flags) {
    __shared__ __align__(16) char smem[131072];
    // A: [48 rows][128 slots16] at 0..98303 (row stride 2048 B), swizzled slot s^(r&7)
    // B: per wave at 98304 + w*8192: 2 bufs x 4096 B (32 rows x 8 slots16)
    // epi: per wave float[48][33] aliased at its own B region (6336 B <= 8192)
    const int tid = threadIdx.x;
    const int lane = tid & 63;
    const int w = tid >> 6;
    const int jb = blockIdx.x;            // 0..63
    const int j0 = jb * 16;
    const int jl = tid & 15, bp = tid >> 4;   // epilogue coords: j' 0..15, batch pair 0..15
    const int je = j0 + jl;
    const float bh0 = bhh[je], bh1 = bhh[1024 + je], bh2 = bhh[2048 + je];
    char* Bbase = smem + 98304 + w * 8192;

    // ---- stage A panel once: rows {g*1024 + j0 + jj}, 6144 slots, 24/lane
#pragma unroll
    for (int it = 0; it < 24; ++it) {
        int flat = (it * 4 + w) * 64 + lane;
        int r = flat >> 7, s = flat & 127;
        int ss = s ^ (r & 7);
        int gr = (r >> 4) * 1024 + j0 + (r & 15);
        gload_lds16(WhhB + (size_t)gr * 1024 + ss * 8, smem + (size_t)flat * 16);
    }

    float hpv[2];
#pragma unroll
    for (int rb = 0; rb < 2; ++rb)
        hpv[rb] = bf2f(h0b[(size_t)(bp * 2 + rb) * 1024 + je]);

    const int lrow = lane & 15;
    const int ksel = lane >> 4;           // 0..3

    for (int t = 0; t < 64; ++t) {
        const u16* hsrc = (t == 0) ? h0b : BG + (size_t)(t - 1) * 1536;
        const size_t hstr = (t == 0) ? 1024 : (size_t)64 * 1536;

        // GI prefetch (consumed in epilogue; retires before B chunks in vmcnt order)
        float gi0[2], gi1[2], gi2[2];
#pragma unroll
        for (int rb = 0; rb < 2; ++rb) {
            const float* gp = GI + ((size_t)((bp * 2 + rb) * 64 + t)) * 3072 + je;
            gi0[rb] = gp[0]; gi1[rb] = gp[1024]; gi2[rb] = gp[2048];
        }
        __builtin_amdgcn_sched_barrier(0);

        auto stageB = [&](int c) {        // 4 gload_lds: 32 rows x 64 cols of wave's K-range
            char* dst = Bbase + (c & 1) * 4096;
            int kq0 = w * 256 + c * 64;
#pragma unroll
            for (int q = 0; q < 4; ++q) {
                int flat = q * 64 + lane;
                int r = flat >> 3, s = flat & 7;
                int ss = s ^ (r & 7);
                gload_lds16x<0x11>(hsrc + (size_t)r * hstr + kq0 + ss * 8,
                                   dst + (size_t)flat * 16);
            }
        };
        stageB(0); stageB(1);
        if (t == 0) {
            __syncthreads();              // drains vmcnt(0): A + B0 + B1 landed, all waves
        } else {
            asm volatile("s_waitcnt vmcnt(4)" ::: "memory");   // GI + B0 landed
        }
        __builtin_amdgcn_sched_barrier(0);

        f32x4 acc[3][2];
#pragma unroll
        for (int mi = 0; mi < 3; ++mi)
#pragma unroll
            for (int ni = 0; ni < 2; ++ni) acc[mi][ni] = (f32x4){0.f, 0.f, 0.f, 0.f};

#pragma unroll
        for (int c = 0; c < 4; ++c) {
            char* Bb = Bbase + (c & 1) * 4096;
#pragma unroll
            for (int ks = 0; ks < 2; ++ks) {
                int kb = ks * 64 + ksel * 16;              // byte col within 128B row
                bf16x8 bfr[2];
#pragma unroll
                for (int ni = 0; ni < 2; ++ni) {
                    int br = ni * 16 + lrow;
                    bfr[ni] = *(const bf16x8*)(Bb + br * 128 + (kb ^ ((br & 7) << 4)));
                }
                int kA = w * 512 + c * 128 + kb;           // byte col within 2048B row
#pragma unroll
                for (int mi = 0; mi < 3; ++mi) {
                    int ar = mi * 16 + lrow;
                    bf16x8 af = *(const bf16x8*)(smem + ar * 2048 + (kA ^ ((ar & 7) << 4)));
#pragma unroll
                    for (int ni = 0; ni < 2; ++ni)
                        acc[mi][ni] = __builtin_amdgcn_mfma_f32_16x16x32_bf16(af, bfr[ni], acc[mi][ni], 0, 0, 0);
                }
            }
            asm volatile("s_waitcnt lgkmcnt(0)" ::: "memory");   // reads done before reuse
            __builtin_amdgcn_sched_barrier(0);
            if (c < 2) {
                stageB(c + 2);
                asm volatile("s_waitcnt vmcnt(4)" ::: "memory"); // next chunk landed
            } else if (c == 2) {
                asm volatile("s_waitcnt vmcnt(0)" ::: "memory"); // last chunk landed
            }
            __builtin_amdgcn_sched_barrier(0);
        }

        // ---- cross-wave K-reduction via per-wave epi (aliases own B bufs)
        float (*epiw)[33] = (float(*)[33])Bbase;
        {
            const int rg = (lane >> 4) << 2;
#pragma unroll
            for (int mi = 0; mi < 3; ++mi)
#pragma unroll
                for (int ni = 0; ni < 2; ++ni) {
                    int m0 = mi * 16 + rg;
                    int cb = ni * 16 + lrow;
#pragma unroll
                    for (int r = 0; r < 4; ++r) epiw[m0 + r][cb] = acc[mi][ni][r];
                }
        }
        asm volatile("s_waitcnt lgkmcnt(0)" ::: "memory");
        __builtin_amdgcn_s_barrier();

        // epilogue: thread (jl, bp) -> j'=jl, batches bp*2, bp*2+1
#pragma unroll
        for (int rb = 0; rb < 2; ++rb) {
            int b = bp * 2 + rb;
            float s0 = 0.f, s1 = 0.f, s2 = 0.f;
#pragma unroll
            for (int ww = 0; ww < 4; ++ww) {
                float (*ep)[33] = (float(*)[33])(smem + 98304 + ww * 8192);
                s0 += ep[jl][b]; s1 += ep[16 + jl][b]; s2 += ep[32 + jl][b];
            }
            float rr = sigmoidf_(gi0[rb] + s0 + bh0);
            float zz = sigmoidf_(gi1[rb] + s1 + bh1);
            float nn = tanhf(gi2[rb] + rr * (s2 + bh2));
            float hnew = (1.0f - zz) * nn + zz * hpv[rb];
            hpv[rb] = hnew;
            store_u16_sc(BG + ((size_t)(b * 64 + t)) * 1536 + je, f2bf(hnew));
        }

        if (t < 63) {
            asm volatile("s_waitcnt vmcnt(0)" ::: "memory");   // h stores at coherence point
            __syncthreads();                                   // all threads stored + read epi
            if (tid == 0)
                __hip_atomic_store(&flags[jb], (unsigned)(t + 1),
                                   __ATOMIC_RELAXED, __HIP_MEMORY_SCOPE_AGENT);
            unsigned tgt = (unsigned)(t + 1);
            while (true) {
                unsigned v = __hip_atomic_load(&flags[lane],
                                               __ATOMIC_RELAXED, __HIP_MEMORY_SCOPE_AGENT);
                if (__all(v >= tgt)) break;
                __builtin_amdgcn_s_sleep(1);
            }
            __builtin_amdgcn_sched_barrier(0);
        }
    }
}

// ------------------------------------------------- per-row lse from partials
__global__ __launch_bounds__(256) void k_lse(const float* __restrict__ pmax,
                                             const float* __restrict__ psum,
                                             float* __restrict__ lse) {
    int n = blockIdx.x;
    int t = threadIdx.x;
    __shared__ float sm[256];
    const float* pm = pmax + (size_t)n * NTMP;
    const float* ps = psum + (size_t)n * NTMP;
    float m = -1e30f;
    for (int p = t; p < NTM; p += 256) m = fmaxf(m, pm[p]);
    sm[t] = m;
    __syncthreads();
    for (int s = 128; s > 0; s >>= 1) { if (t < s) sm[t] = fmaxf(sm[t], sm[t + s]); __syncthreads(); }
    m = sm[0];
    __syncthreads();
    float s = 0.0f;
    for (int p = t; p < NTM; p += 256) s += ps[p] * expf(pm[p] - m);
    sm[t] = s;
    __syncthreads();
    for (int r = 128; r > 0; r >>= 1) { if (t < r) sm[t] += sm[t + r]; __syncthreads(); }
    if (t == 0) lse[n] = m + logf(sm[0]);
}

// ------------------------------------------------- final combine (fully coalesced)
__global__ __launch_bounds__(256) void k_final(const u16* __restrict__ Lb,
                                               const unsigned char* __restrict__ g8,
                                               const float* __restrict__ lse,
                                               const float* __restrict__ ks,
                                               const float* __restrict__ lsek,
                                               float* __restrict__ out) {
    int n = blockIdx.y;
    int b = n >> 6;
    float lsen = lse[n], lkb = lsek[b];
    int base = blockIdx.x * 2048;
#pragma unroll
    for (int i = 0; i < 8; ++i) {
        int v = base + i * 256 + threadIdx.x;
        if (v < VOC) {
            float L = bf2f(Lb[(size_t)n * VOCP + v]);
            float g = g8[(size_t)n * VOCP + v] * (1.0f / 255.0f);
            float kp = ((v >= 10 && v < 10 + KSN) ? ks[(size_t)b * KSN + (v - 10)] : 0.0f) - lkb;
            out[(size_t)n * VOC + v] = g * (L - lsen) + (1.0f - g) * kp;
        }
    }
}

// ---------------------------------------------------------------- launch
extern "C" void kernel_launch(void* const* d_in, const int* in_sizes, int n_in,
                              void* d_out, int out_size, void* d_ws, size_t ws_size,
                              hipStream_t stream) {
    const float* ses    = (const float*)d_in[0];
    const float* know   = (const float*)d_in[1];
    const int*   target = (const int*)d_in[2];
    const float* embed  = (const float*)d_in[3];
    const float* Wih    = (const float*)d_in[4];
    const float* Whh    = (const float*)d_in[5];
    const float* bih    = (const float*)d_in[6];
    const float* bhh    = (const float*)d_in[7];
    const float* sdw    = (const float*)d_in[8];
    const float* sdb    = (const float*)d_in[9];
    const float* dw     = (const float*)d_in[10];
    const float* siw    = (const float*)d_in[11];
    const float* ew     = (const float*)d_in[12];
    const float* eb     = (const float*)d_in[13];
    const float* W1     = (const float*)d_in[14];
    const float* W2     = (const float*)d_in[15];
    const float* W3     = (const float*)d_in[16];
    const float* W4     = (const float*)d_in[17];
    const float* kvw    = (const float*)d_in[18];

    char* ws = (char*)d_ws;
    size_t o = 0;
    auto alloc = [&](size_t bytes) { char* r = ws + o; o += (bytes + 255) & ~(size_t)255; return r; };
    u16*   Aemb  = (u16*)  alloc((size_t)VOCP * 512 * 2);
    u16*   A34   = (u16*)  alloc((size_t)VOCP * 1536 * 2);
    u16*   Adwew = (u16*)  alloc((size_t)1024 * 1536 * 2);
    u16*   Wihb  = (u16*)  alloc((size_t)3072 * 512 * 2);
    u16*   WhhB  = (u16*)  alloc((size_t)3072 * 1024 * 2);
    u16*   h0b   = (u16*)  alloc((size_t)32 * 1024 * 2);
    u16*   BG    = (u16*)  alloc((size_t)2048 * 1536 * 2);
    u16*   BL    = (u16*)  alloc((size_t)2048 * 512 * 2);
    float* GI    = (float*)alloc((size_t)2048 * 3072 * 4);
    float* h0    = (float*)alloc((size_t)32 * 1024 * 4);
    float* sesinf= (float*)alloc((size_t)32 * 1024 * 4);
    float* gc    = (float*)alloc((size_t)32 * VOCP * 4);
    float* ksb   = (float*)alloc((size_t)32 * KSN * 4);
    float* lsek  = (float*)alloc(256);
    float* lse   = (float*)alloc((size_t)2048 * 4);
    unsigned* flags = (unsigned*)alloc(256);
    float* pmax  = (float*)alloc((size_t)2048 * NTMP * 4);
    float* psum  = (float*)alloc((size_t)2048 * NTMP * 4);
    unsigned char* g8 = (unsigned char*)alloc((size_t)2048 * VOCP);   // aliased: kvwb
    u16*   Lb    = (u16*)  alloc((size_t)2048 * VOCP * 2);            // aliased: Awk
    u16*   Bsk   = (u16*)  alloc((size_t)128 * 2048 * 2);
    float* out = (float*)d_out;

    u16*   kvwb  = (u16*)g8;       // 8832*1024*2 = 18.1 MB <= g8 (102 MB)
    u16*   Awk   = Lb;             // 50048*2048*2 == Lb size

    hipMemsetAsync(flags, 0, 256, stream);

    // weight conversions (early users of aliased buffers come first)
    k_cvt<<<dim3(VOC, 1), 256, 0, stream>>>(embed, Aemb, 512, 512, 512);
    k_cvt<<<dim3(VOC, 1), 256, 0, stream>>>(W3, A34, 1024, 1024, 1536);
    k_cvt<<<dim3(VOC, 1), 256, 0, stream>>>(W4, A34 + 1024, 512, 512, 1536);
    k_cvt<<<dim3(VOC, 1), 256, 0, stream>>>(W1, Awk, 1024, 1024, 2048);
    k_cvt<<<dim3(VOC, 1), 256, 0, stream>>>(W2, Awk + 1024, 1024, 1024, 2048);
    k_cvt<<<dim3(KSN, 1), 256, 0, stream>>>(kvw, kvwb, 1024, 1024, 1024);
    k_pad0<<<dim3(VOCP - VOC), 256, 0, stream>>>(Aemb, A34, Awk);
    k_padK<<<dim3(KSNP - KSN), 256, 0, stream>>>(kvwb);
    k_cvt<<<dim3(1024, 1), 256, 0, stream>>>(dw, Adwew, 1024, 1024, 1536);
    k_cvt<<<dim3(1024, 1), 256, 0, stream>>>(ew, Adwew + 1024, 512, 512, 1536);
    k_cvt<<<dim3(3072, 1), 256, 0, stream>>>(Wih, Wihb, 512, 512, 512);
    k_cvt<<<dim3(3072, 1), 256, 0, stream>>>(Whh, WhhB, 1024, 1024, 1024);
    k_bsk<<<dim3(128), 256, 0, stream>>>(ses, know, Bsk);

    k_gather<<<dim3(2048), 128, 0, stream>>>(embed, target, BG);
    k_h0_sesinf<<<dim3(32), 256, 0, stream>>>(ses, sdw, sdb, siw, h0, sesinf);
    k_cvt<<<dim3(32, 1), 256, 0, stream>>>(h0, h0b, 1024, 1024, 1024);

    // gc = [W1|W2] @ [ses|know]   (MFMA, n<32 valid)
    gemm_bt<4><<<dim3(1, NTM), 256, 0, stream>>>(Awk, 2048, Bsk, 2048, 2048,
                                                 nullptr, nullptr, gc, nullptr, nullptr, nullptr);
    // ks = kvw @ know   (MFMA, B = know half of Bsk)
    gemm_bt<5><<<dim3(1, 69), 256, 0, stream>>>(kvwb, 1024, Bsk + 1024, 2048, 1024,
                                                nullptr, nullptr, ksb, nullptr, nullptr, nullptr);
    k_lseknow<<<dim3(32), 256, 0, stream>>>(ksb, lsek);

    // GI = TE @ Wih.T + bih
    gemm_bt<0><<<dim3(16, 24), 256, 0, stream>>>(Wihb, 512, BG + 1024, 1536, 512,
                                                 bih, nullptr, GI, nullptr, nullptr, nullptr);
    // GRU recurrence: persistent LDS-resident-weights MFMA kernel, fence-free barrier
    k_gru_m4<<<dim3(64), 256, 0, stream>>>(WhhB, GI, bhh, h0b, BG, flags);
    // MX (maxout) -> BL
    gemm_bt<1><<<dim3(16, 8), 256, 0, stream>>>(Adwew, 1536, BG, 1536, 1536,
                                                sesinf, eb, nullptr, BL, nullptr, nullptr);
    // gate GEMM -> g8
    gemm_bt<2><<<dim3(16, NTM), 256, 0, stream>>>(A34, 1536, BG, 1536, 1536,
                                                  gc, nullptr, nullptr, nullptr, g8, nullptr);
    // logit GEMM -> Lb + partials
    gemm_bt<3><<<dim3(16, NTM), 256, 0, stream>>>(Aemb, 512, BL, 512, 512,
                                                  nullptr, nullptr, pmax, Lb, nullptr, psum);
    k_lse<<<dim3(2048), 256, 0, stream>>>(pmax, psum, lse);
    k_final<<<dim3(25, 2048), 256, 0, stream>>>(Lb, g8, lse, ksb, lsek, out);
}

// Round 9
// 1665.089 us; speedup vs baseline: 3.4854x; 1.0093x over previous
//
#include <hip/hip_runtime.h>

// Problem dims
constexpr int VOC  = 50005;
constexpr int VOCP = 50048;   // 391*128, padded vocab (128-tile GEMMs)
constexpr int VOCP2= 50176;   // 196*256, padded vocab (256-tile GEMM)
constexpr int NTM  = 391;     // vocab tiles (128) for 128-tile GEMMs
constexpr int NTMP = 400;     // padded partial stride
constexpr int KSN  = 8784;    // KNOW-1
constexpr int KSNP = 8832;    // 69*128
constexpr float NPAD = 41221.0f;

typedef unsigned short u16;
typedef __attribute__((ext_vector_type(4))) float f32x4;
typedef __attribute__((ext_vector_type(8))) short bf16x8;

__device__ __forceinline__ float dot4(float4 a, float4 b) {
    return a.x*b.x + a.y*b.y + a.z*b.z + a.w*b.w;
}
__device__ __forceinline__ float sigmoidf_(float x) { return 1.0f / (1.0f + expf(-x)); }
__device__ __forceinline__ u16 f2bf(float f) {
    unsigned x = __float_as_uint(f);
    return (u16)((x + 0x7FFFu + ((x >> 16) & 1u)) >> 16);
}
__device__ __forceinline__ float bf2f(u16 u) { return __uint_as_float(((unsigned)u) << 16); }
template<int AUX>
__device__ __forceinline__ void gload_lds16x(const void* g, void* l) {
    __builtin_amdgcn_global_load_lds((const __attribute__((address_space(1))) unsigned int*)g,
                                     (__attribute__((address_space(3))) unsigned int*)l, 16, 0, AUX);
}
__device__ __forceinline__ void gload_lds16(const void* g, void* l) { gload_lds16x<0>(g, l); }
// device-coherent u16 store (write-through to coherence point, cross-XCD visible)
__device__ __forceinline__ void store_u16_sc(u16* p, u16 v) {
    asm volatile("global_store_short %0, %1, off sc0 sc1" :: "v"(p), "v"((unsigned)v) : "memory");
}

// ---------------------------------------------------------------- cvt fp32 -> bf16 (strided)
__global__ __launch_bounds__(256) void k_cvt(const float* __restrict__ src, u16* __restrict__ dst,
                                             int ncols, int sld, int dld) {
    int row = blockIdx.x;
    int c = (blockIdx.y * 256 + threadIdx.x) * 4;
    if (c >= ncols) return;
    float4 v = *(const float4*)(src + (size_t)row * sld + c);
    unsigned lo = f2bf(v.x) | ((unsigned)f2bf(v.y) << 16);
    unsigned hi = f2bf(v.z) | ((unsigned)f2bf(v.w) << 16);
    *(uint2*)(dst + (size_t)row * dld + c) = make_uint2(lo, hi);
}

// zero pad rows 50005..50175 of A34 (VOCP2), 50005..50047 of Aemb / Awk (VOCP)
__global__ __launch_bounds__(256) void k_pad0(u16* __restrict__ Aemb, u16* __restrict__ A34,
                                              u16* __restrict__ Awk) {
    int r = VOC + blockIdx.x;            // 50005..50175
    unsigned* p3 = (unsigned*)(A34 + (size_t)r * 1536);
    for (int i = threadIdx.x; i < 768; i += 256) p3[i] = 0;
    if (r < VOCP) {
        unsigned* pe = (unsigned*)(Aemb + (size_t)r * 512);
        if (threadIdx.x < 256) pe[threadIdx.x] = 0;
        unsigned* pw = (unsigned*)(Awk + (size_t)r * 2048);
        for (int i = threadIdx.x; i < 1024; i += 256) pw[i] = 0;
    }
}
// zero pad rows 8784..8831 of kvwb
__global__ __launch_bounds__(256) void k_padK(u16* __restrict__ kvwb) {
    int r = KSN + blockIdx.x;
    unsigned* p = (unsigned*)(kvwb + (size_t)r * 1024);
    for (int i = threadIdx.x; i < 512; i += 256) p[i] = 0;
}

// build Bsk [128][2048] bf16: rows 0..31 = [ses|know], rows 32..127 = 0
__global__ __launch_bounds__(256) void k_bsk(const float* __restrict__ ses,
                                             const float* __restrict__ know,
                                             u16* __restrict__ Bsk) {
    int row = blockIdx.x;
    for (int c0 = threadIdx.x * 4; c0 < 2048; c0 += 1024) {
        uint2 val = make_uint2(0, 0);
        if (row < 32) {
            const float* srcp = (c0 < 1024) ? ses + (size_t)row * 1024 + c0
                                            : know + (size_t)row * 1024 + (c0 - 1024);
            float4 v = *(const float4*)srcp;
            val = make_uint2(f2bf(v.x) | ((unsigned)f2bf(v.y) << 16),
                             f2bf(v.z) | ((unsigned)f2bf(v.w) << 16));
        }
        *(uint2*)(Bsk + (size_t)row * 2048 + c0) = val;
    }
}

// ---------------------------------------------------------------- gather target embeddings -> BG[:,1024:1536] bf16
__global__ __launch_bounds__(128) void k_gather(const float* __restrict__ embed,
                                                const int* __restrict__ target,
                                                u16* __restrict__ BG) {
    int n = blockIdx.x;
    int row = target[n];
    int c = threadIdx.x * 4;
    float4 v = *(const float4*)(embed + (size_t)row * 512 + c);
    unsigned lo = f2bf(v.x) | ((unsigned)f2bf(v.y) << 16);
    unsigned hi = f2bf(v.z) | ((unsigned)f2bf(v.w) << 16);
    *(uint2*)(BG + (size_t)n * 1536 + 1024 + c) = make_uint2(lo, hi);
}

// ------------------------------------------------- h0 + ses_inf_vec (fp32, small)
__global__ __launch_bounds__(256) void k_h0_sesinf(const float* __restrict__ ses,
                                                   const float* __restrict__ sdw,
                                                   const float* __restrict__ sdb,
                                                   const float* __restrict__ siw,
                                                   float* __restrict__ h0,
                                                   float* __restrict__ sesinf) {
    int g = blockIdx.x * 256 + threadIdx.x;
    int b = g & 31;
    int jg = g >> 5;
    int j0 = jg * 4;
    const float4* s4 = (const float4*)(ses + (size_t)b * 1024);
    const float4* wa[4];
    const float4* wc[4];
#pragma unroll
    for (int r = 0; r < 4; ++r) {
        wa[r] = (const float4*)(sdw + (size_t)(j0 + r) * 1024);
        wc[r] = (const float4*)(siw + (size_t)(j0 + r) * 1024);
    }
    float a[4] = {0, 0, 0, 0}, c[4] = {0, 0, 0, 0};
    for (int kq = 0; kq < 256; ++kq) {
        float4 sv = s4[kq];
#pragma unroll
        for (int r = 0; r < 4; ++r) { a[r] += dot4(sv, wa[r][kq]); c[r] += dot4(sv, wc[r][kq]); }
    }
#pragma unroll
    for (int r = 0; r < 4; ++r) {
        h0[b * 1024 + j0 + r] = tanhf(a[r] + sdb[j0 + r]);
        sesinf[b * 1024 + j0 + r] = c[r];
    }
}

// ------------------------------------------------- lse of padded know scores
__global__ __launch_bounds__(256) void k_lseknow(const float* __restrict__ ks,
                                                 float* __restrict__ lsek) {
    int b = blockIdx.x;
    int t = threadIdx.x;
    __shared__ float sm[256];
    float m = -1e30f;
    for (int j = t; j < KSN; j += 256) m = fmaxf(m, ks[(size_t)b * KSN + j]);
    sm[t] = m;
    __syncthreads();
    for (int s = 128; s > 0; s >>= 1) { if (t < s) sm[t] = fmaxf(sm[t], sm[t + s]); __syncthreads(); }
    m = fmaxf(sm[0], 0.0f);
    __syncthreads();
    float s = 0.0f;
    for (int j = t; j < KSN; j += 256) s += expf(ks[(size_t)b * KSN + j] - m);
    sm[t] = s;
    __syncthreads();
    for (int r = 128; r > 0; r >>= 1) { if (t < r) sm[t] += sm[t + r]; __syncthreads(); }
    if (t == 0) lsek[b] = m + logf(sm[0] + NPAD * expf(0.0f - m));
}

// ================================================= templated bf16 MFMA GEMM (C[m][n] = A[m]·B[n]) 128-tile
// EPI 0: GI (+bias, fp32)  EPI 1: MX maxout  EPI 3: logits+partials
// EPI 4: gc fp32 [b][VOCP2] (n<32)  EPI 5: ks fp32 [b][KSN] (n<32, m<KSN)
template<int EPI>
__global__ __launch_bounds__(256) void gemm_bt(
    const u16* __restrict__ A, int lda,
    const u16* __restrict__ B, int ldb, int K,
    const float* __restrict__ p0, const float* __restrict__ p1,
    float* __restrict__ q0, u16* __restrict__ q1,
    unsigned char* __restrict__ q2, float* __restrict__ q3)
{
    __shared__ u16 Asm[128 * 64];
    __shared__ u16 Bsm[128 * 64];
    const int tid = threadIdx.x;
    const int lane = tid & 63;
    const int w = tid >> 6;
    const int wm = w >> 1, wn = w & 1;
    const int nt = blockIdx.x, mt = blockIdx.y;

    f32x4 acc[4][4];
#pragma unroll
    for (int i = 0; i < 4; ++i)
#pragma unroll
        for (int j = 0; j < 4; ++j) acc[i][j] = (f32x4){0.f, 0.f, 0.f, 0.f};

    for (int kt = 0; kt < K; kt += 64) {
#pragma unroll
        for (int p = 0; p < 4; ++p) {
            int flat = (w * 4 + p) * 64 + lane;       // 0..1023 16B-slots
            int row = flat >> 3, slot = flat & 7;
            int ss = slot ^ (row & 7);                // inverse-swizzled source slot
            gload_lds16(A + (size_t)(mt * 128 + row) * lda + kt + ss * 8, Asm + flat * 8);
            gload_lds16(B + (size_t)(nt * 128 + row) * ldb + kt + ss * 8, Bsm + flat * 8);
        }
        __syncthreads();
#pragma unroll
        for (int kc = 0; kc < 2; ++kc) {
            bf16x8 af[4], bfr[4];
#pragma unroll
            for (int mi = 0; mi < 4; ++mi) {
                int row = wm * 64 + mi * 16 + (lane & 15);
                int bcol = kc * 64 + ((lane >> 4) << 4);
                af[mi] = *(const bf16x8*)((const char*)Asm + row * 128 + (bcol ^ ((row & 7) << 4)));
            }
#pragma unroll
            for (int ni = 0; ni < 4; ++ni) {
                int row = wn * 64 + ni * 16 + (lane & 15);
                int bcol = kc * 64 + ((lane >> 4) << 4);
                bfr[ni] = *(const bf16x8*)((const char*)Bsm + row * 128 + (bcol ^ ((row & 7) << 4)));
            }
#pragma unroll
            for (int mi = 0; mi < 4; ++mi)
#pragma unroll
                for (int ni = 0; ni < 4; ++ni)
                    acc[mi][ni] = __builtin_amdgcn_mfma_f32_16x16x32_bf16(af[mi], bfr[ni], acc[mi][ni], 0, 0, 0);
        }
        __syncthreads();
    }

    const int cl = lane & 15;           // n offset within fragment
    const int rg = (lane >> 4) << 2;    // m base within fragment

    if constexpr (EPI == 0) {           // GI = TE@Wih.T + bih  (fp32 [n][3072])
#pragma unroll
        for (int mi = 0; mi < 4; ++mi) {
            int m0 = mt * 128 + wm * 64 + mi * 16 + rg;
            float4 bias = *(const float4*)(p0 + m0);
#pragma unroll
            for (int ni = 0; ni < 4; ++ni) {
                int n = nt * 128 + wn * 64 + ni * 16 + cl;
                float4 v;
                v.x = acc[mi][ni][0] + bias.x; v.y = acc[mi][ni][1] + bias.y;
                v.z = acc[mi][ni][2] + bias.z; v.w = acc[mi][ni][3] + bias.w;
                *(float4*)(q0 + (size_t)n * 3072 + m0) = v;
            }
        }
    }
    if constexpr (EPI == 1) {           // maxout -> BL bf16 [n][512]
#pragma unroll
        for (int mi = 0; mi < 4; ++mi) {
            int m0 = mt * 128 + wm * 64 + mi * 16 + rg;
            float4 eb4 = *(const float4*)(p1 + m0);
#pragma unroll
            for (int ni = 0; ni < 4; ++ni) {
                int n = nt * 128 + wn * 64 + ni * 16 + cl;
                int b = n >> 6;
                float v0 = acc[mi][ni][0] + p0[b * 1024 + m0 + 0] + eb4.x;
                float v1 = acc[mi][ni][1] + p0[b * 1024 + m0 + 1] + eb4.y;
                float v2 = acc[mi][ni][2] + p0[b * 1024 + m0 + 2] + eb4.z;
                float v3 = acc[mi][ni][3] + p0[b * 1024 + m0 + 3] + eb4.w;
                unsigned pk = f2bf(fmaxf(v0, v1)) | ((unsigned)f2bf(fmaxf(v2, v3)) << 16);
                *(unsigned*)(q1 + (size_t)n * 512 + (m0 >> 1)) = pk;
            }
        }
    }
    if constexpr (EPI == 3) {           // logits -> Lb bf16 [n][VOCP] + partial max/sumexp
        __shared__ float redm[2][128];
        __shared__ float reds[2][128];
#pragma unroll
        for (int mi = 0; mi < 4; ++mi) {
            int v0 = mt * 128 + wm * 64 + mi * 16 + rg;
#pragma unroll
            for (int ni = 0; ni < 4; ++ni) {
                int n = nt * 128 + wn * 64 + ni * 16 + cl;
                unsigned lo = f2bf(acc[mi][ni][0]) | ((unsigned)f2bf(acc[mi][ni][1]) << 16);
                unsigned hi = f2bf(acc[mi][ni][2]) | ((unsigned)f2bf(acc[mi][ni][3]) << 16);
                *(uint2*)(q1 + (size_t)n * VOCP + v0) = make_uint2(lo, hi);
            }
        }
#pragma unroll
        for (int ni = 0; ni < 4; ++ni) {
            float lm = -1e30f;
#pragma unroll
            for (int mi = 0; mi < 4; ++mi) {
                int v0 = mt * 128 + wm * 64 + mi * 16 + rg;
#pragma unroll
                for (int r = 0; r < 4; ++r)
                    if (v0 + r < VOC) lm = fmaxf(lm, acc[mi][ni][r]);
            }
            lm = fmaxf(lm, __shfl_xor(lm, 16));
            lm = fmaxf(lm, __shfl_xor(lm, 32));
            float s = 0.0f;
#pragma unroll
            for (int mi = 0; mi < 4; ++mi) {
                int v0 = mt * 128 + wm * 64 + mi * 16 + rg;
#pragma unroll
                for (int r = 0; r < 4; ++r)
                    if (v0 + r < VOC) s += expf(acc[mi][ni][r] - lm);
            }
            s += __shfl_xor(s, 16);
            s += __shfl_xor(s, 32);
            if (lane < 16) {
                redm[wm][wn * 64 + ni * 16 + lane] = lm;
                reds[wm][wn * 64 + ni * 16 + lane] = s;
            }
        }
        __syncthreads();
        if (tid < 128) {
            float m0_ = redm[0][tid], m1_ = redm[1][tid];
            float m = fmaxf(m0_, m1_);
            float s = reds[0][tid] * expf(m0_ - m) + reds[1][tid] * expf(m1_ - m);
            int n = nt * 128 + tid;
            q0[(size_t)n * NTMP + mt] = m;
            q3[(size_t)n * NTMP + mt] = s;
        }
    }
    if constexpr (EPI == 4) {           // gc fp32 [b][VOCP2], only n<32 valid
#pragma unroll
        for (int mi = 0; mi < 4; ++mi) {
            int m0 = mt * 128 + wm * 64 + mi * 16 + rg;
#pragma unroll
            for (int ni = 0; ni < 4; ++ni) {
                int n = nt * 128 + wn * 64 + ni * 16 + cl;
                if (n < 32) {
                    float4 v;
                    v.x = acc[mi][ni][0]; v.y = acc[mi][ni][1];
                    v.z = acc[mi][ni][2]; v.w = acc[mi][ni][3];
                    *(float4*)(q0 + (size_t)n * VOCP2 + m0) = v;
                }
            }
        }
    }
    if constexpr (EPI == 5) {           // ks fp32 [b][KSN], n<32, m<KSN
#pragma unroll
        for (int mi = 0; mi < 4; ++mi) {
            int m0 = mt * 128 + wm * 64 + mi * 16 + rg;
#pragma unroll
            for (int ni = 0; ni < 4; ++ni) {
                int n = nt * 128 + wn * 64 + ni * 16 + cl;
                if (n < 32 && m0 < KSN) {
                    float4 v;
                    v.x = acc[mi][ni][0]; v.y = acc[mi][ni][1];
                    v.z = acc[mi][ni][2]; v.w = acc[mi][ni][3];
                    *(float4*)(q0 + (size_t)n * KSN + m0) = v;
                }
            }
        }
    }
}

// ================================================= 256x256-tile gate GEMM, BK=32, triple-buffer,
// counted vmcnt(4) across barriers (T3/T4), setprio (T5), XCD-chunked swizzle (T1).
// 512 threads = 8 waves (2M x 4N); per-wave output 128x64 = acc[8][4] fragments.
// LDS 96 KB: A slots 3 x 16KB @0, B slots 3 x 16KB @49152. 64B rows, swizzle
// slot s ^ ((r&3)^((r>>2)&3)) (even 16B-granule class distribution -> conflict-free).
// Correctness ledger: tile t+2 staged during tile t into slot (t+2)%3 (freed at
// barrier(t-1)); boundary vmcnt(4) = tile t+1's 4 stage-instrs landed, t+2's stay
// in flight across the barrier. Epilogue: gate = sigmoid(acc + gc) -> u8 g8.
__global__ __launch_bounds__(512, 2) void gemm_gate8(
    const u16* __restrict__ A,      // A34 [VOCP2][1536]
    const u16* __restrict__ B,      // BG  [2048][1536]
    const float* __restrict__ gc2,  // [32][VOCP2]
    unsigned char* __restrict__ g8) // [2048][VOCP2]
{
    constexpr int K = 1536, NT = K / 32;          // 48 K-tiles
    __shared__ __align__(16) char smem[98304];
    const int tid = threadIdx.x;
    const int lane = tid & 63;
    const int w = tid >> 6;
    const int wm = w >> 2;          // 0..1: M rows wm*128
    const int wn = w & 3;           // 0..3: N cols wn*64
    const int lrow = lane & 15;
    const int g = lane >> 4;        // K 16B-chunk select

    // XCD-chunked bijective block swizzle: 1568 = 8 * 196
    int bid = blockIdx.x;
    int wg = (bid & 7) * 196 + (bid >> 3);
    int mt = wg >> 3;               // 0..195
    int nt = wg & 7;                // 0..7
    const size_t arow0 = (size_t)mt * 256;
    const size_t brow0 = (size_t)nt * 256;

#define SWZ(r) (((r) & 3) ^ (((r) >> 2) & 3))
    auto stageA = [&](int t) {
        char* dst = smem + (t % 3) * 16384;
        int kt = t * 32;
#pragma unroll
        for (int q = 0; q < 2; ++q) {
            int flat = q * 512 + tid;
            int row = flat >> 2, s = flat & 3;
            int ss = s ^ SWZ(row);
            gload_lds16(A + (arow0 + row) * 1536 + kt + ss * 8, dst + flat * 16);
        }
    };
    auto stageB = [&](int t) {
        char* dst = smem + 49152 + (t % 3) * 16384;
        int kt = t * 32;
#pragma unroll
        for (int q = 0; q < 2; ++q) {
            int flat = q * 512 + tid;
            int row = flat >> 2, s = flat & 3;
            int ss = s ^ SWZ(row);
            gload_lds16(B + (brow0 + row) * 1536 + kt + ss * 8, dst + flat * 16);
        }
    };

    f32x4 acc[8][4];
#pragma unroll
    for (int i = 0; i < 8; ++i)
#pragma unroll
        for (int j = 0; j < 4; ++j) acc[i][j] = (f32x4){0.f, 0.f, 0.f, 0.f};

    // prologue: tiles 0,1 (A0,B0,A1,B1 -> 8 stage-instrs)
    stageA(0); stageB(0); stageA(1); stageB(1);
    asm volatile("s_waitcnt vmcnt(4)" ::: "memory");   // tile 0 landed
    __builtin_amdgcn_sched_barrier(0);
    __builtin_amdgcn_s_barrier();

    auto tile_body = [&](int t, bool prefetch) {
        char* Ab = smem + (t % 3) * 16384;
        char* Bb = smem + 49152 + (t % 3) * 16384;
        // ---- phase 1: stage A(t+2), read B0-3 + A0-3, 16 MFMA
        if (prefetch) stageA(t + 2);
        bf16x8 bf[4], af[4];
#pragma unroll
        for (int ni = 0; ni < 4; ++ni) {
            int r = wn * 64 + ni * 16 + lrow;
            bf[ni] = *(const bf16x8*)(Bb + r * 64 + (g ^ SWZ(r)) * 16);
        }
#pragma unroll
        for (int mi = 0; mi < 4; ++mi) {
            int r = wm * 128 + mi * 16 + lrow;
            af[mi] = *(const bf16x8*)(Ab + r * 64 + (g ^ SWZ(r)) * 16);
        }
        __builtin_amdgcn_s_setprio(1);
#pragma unroll
        for (int mi = 0; mi < 4; ++mi)
#pragma unroll
            for (int ni = 0; ni < 4; ++ni)
                acc[mi][ni] = __builtin_amdgcn_mfma_f32_16x16x32_bf16(af[mi], bf[ni], acc[mi][ni], 0, 0, 0);
        __builtin_amdgcn_s_setprio(0);
        // ---- phase 2: stage B(t+2), read A4-7 (B reused), 16 MFMA
        if (prefetch) stageB(t + 2);
#pragma unroll
        for (int mi = 0; mi < 4; ++mi) {
            int r = wm * 128 + 64 + mi * 16 + lrow;
            af[mi] = *(const bf16x8*)(Ab + r * 64 + (g ^ SWZ(r)) * 16);
        }
        __builtin_amdgcn_s_setprio(1);
#pragma unroll
        for (int mi = 0; mi < 4; ++mi)
#pragma unroll
            for (int ni = 0; ni < 4; ++ni)
                acc[4 + mi][ni] = __builtin_amdgcn_mfma_f32_16x16x32_bf16(af[mi], bf[ni], acc[4 + mi][ni], 0, 0, 0);
        __builtin_amdgcn_s_setprio(0);
    };

    for (int t = 0; t < NT - 2; ++t) {
        tile_body(t, true);
        asm volatile("s_waitcnt vmcnt(4)" ::: "memory");   // tile t+1 landed; t+2 in flight
        __builtin_amdgcn_sched_barrier(0);
        __builtin_amdgcn_s_barrier();
    }
    tile_body(NT - 2, false);
    asm volatile("s_waitcnt vmcnt(0)" ::: "memory");       // tile NT-1 landed
    __builtin_amdgcn_sched_barrier(0);
    __builtin_amdgcn_s_barrier();
    tile_body(NT - 1, false);

    // ---- epilogue: gate = sigmoid(acc + gc), pack 4 x u8
    const int rg = g << 2;
    const int b = nt * 4 + wn;                 // uniform per wave
    const float* gcrow = gc2 + (size_t)b * VOCP2;
#pragma unroll
    for (int a = 0; a < 8; ++a) {
        int v0 = mt * 256 + wm * 128 + (a >> 2) * 64 + (a & 3) * 16 + rg;
        float4 gcv = *(const float4*)(gcrow + v0);
#pragma unroll
        for (int ni = 0; ni < 4; ++ni) {
            int n = nt * 256 + wn * 64 + ni * 16 + lrow;
            unsigned pk = 0;
#pragma unroll
            for (int r = 0; r < 4; ++r) {
                float garg = acc[a][ni][r] + ((const float*)&gcv)[r];
                float gate = 1.0f / (1.0f + expf(-garg));
                pk |= ((unsigned)(int)(gate * 255.0f + 0.5f)) << (8 * r);
            }
            *(unsigned*)(g8 + (size_t)n * VOCP2 + v0) = pk;
        }
    }
#undef SWZ
}

// ------------------------------------------------- persistent MFMA GRU v4 (round-8, validated)
__global__ __launch_bounds__(256, 1) void k_gru_m4(const u16* __restrict__ WhhB,
                                                   const float* __restrict__ GI,
                                                   const float* __restrict__ bhh,
                                                   const u16* __restrict__ h0b,
                                                   u16* __restrict__ BG,
                                                   unsigned* __restrict__ flags) {
    __shared__ __align__(16) char smem[131072];
    const int tid = threadIdx.x;
    const int lane = tid & 63;
    const int w = tid >> 6;
    const int jb = blockIdx.x;            // 0..63
    const int j0 = jb * 16;
    const int jl = tid & 15, bp = tid >> 4;
    const int je = j0 + jl;
    const float bh0 = bhh[je], bh1 = bhh[1024 + je], bh2 = bhh[2048 + je];
    char* Bbase = smem + 98304 + w * 8192;

#pragma unroll
    for (int it = 0; it < 24; ++it) {
        int flat = (it * 4 + w) * 64 + lane;
        int r = flat >> 7, s = flat & 127;
        int ss = s ^ (r & 7);
        int gr = (r >> 4) * 1024 + j0 + (r & 15);
        gload_lds16(WhhB + (size_t)gr * 1024 + ss * 8, smem + (size_t)flat * 16);
    }

    float hpv[2];
#pragma unroll
    for (int rb = 0; rb < 2; ++rb)
        hpv[rb] = bf2f(h0b[(size_t)(bp * 2 + rb) * 1024 + je]);

    const int lrow = lane & 15;
    const int ksel = lane >> 4;

    for (int t = 0; t < 64; ++t) {
        const u16* hsrc = (t == 0) ? h0b : BG + (size_t)(t - 1) * 1536;
        const size_t hstr = (t == 0) ? 1024 : (size_t)64 * 1536;

        float gi0[2], gi1[2], gi2[2];
#pragma unroll
        for (int rb = 0; rb < 2; ++rb) {
            const float* gp = GI + ((size_t)((bp * 2 + rb) * 64 + t)) * 3072 + je;
            gi0[rb] = gp[0]; gi1[rb] = gp[1024]; gi2[rb] = gp[2048];
        }
        __builtin_amdgcn_sched_barrier(0);

        auto stageB = [&](int c) {
            char* dst = Bbase + (c & 1) * 4096;
            int kq0 = w * 256 + c * 64;
#pragma unroll
            for (int q = 0; q < 4; ++q) {
                int flat = q * 64 + lane;
                int r = flat >> 3, s = flat & 7;
                int ss = s ^ (r & 7);
                gload_lds16x<0x11>(hsrc + (size_t)r * hstr + kq0 + ss * 8,
                                   dst + (size_t)flat * 16);
            }
        };
        stageB(0); stageB(1);
        if (t == 0) {
            __syncthreads();
        } else {
            asm volatile("s_waitcnt vmcnt(4)" ::: "memory");
        }
        __builtin_amdgcn_sched_barrier(0);

        f32x4 acc[3][2];
#pragma unroll
        for (int mi = 0; mi < 3; ++mi)
#pragma unroll
            for (int ni = 0; ni < 2; ++ni) acc[mi][ni] = (f32x4){0.f, 0.f, 0.f, 0.f};

#pragma unroll
        for (int c = 0; c < 4; ++c) {
            char* Bb = Bbase + (c & 1) * 4096;
#pragma unroll
            for (int ks = 0; ks < 2; ++ks) {
                int kb = ks * 64 + ksel * 16;
                bf16x8 bfr[2];
#pragma unroll
                for (int ni = 0; ni < 2; ++ni) {
                    int br = ni * 16 + lrow;
                    bfr[ni] = *(const bf16x8*)(Bb + br * 128 + (kb ^ ((br & 7) << 4)));
                }
                int kA = w * 512 + c * 128 + kb;
#pragma unroll
                for (int mi = 0; mi < 3; ++mi) {
                    int ar = mi * 16 + lrow;
                    bf16x8 af = *(const bf16x8*)(smem + ar * 2048 + (kA ^ ((ar & 7) << 4)));
#pragma unroll
                    for (int ni = 0; ni < 2; ++ni)
                        acc[mi][ni] = __builtin_amdgcn_mfma_f32_16x16x32_bf16(af, bfr[ni], acc[mi][ni], 0, 0, 0);
                }
            }
            asm volatile("s_waitcnt lgkmcnt(0)" ::: "memory");
            __builtin_amdgcn_sched_barrier(0);
            if (c < 2) {
                stageB(c + 2);
                asm volatile("s_waitcnt vmcnt(4)" ::: "memory");
            } else if (c == 2) {
                asm volatile("s_waitcnt vmcnt(0)" ::: "memory");
            }
            __builtin_amdgcn_sched_barrier(0);
        }

        float (*epiw)[33] = (float(*)[33])Bbase;
        {
            const int rg = (lane >> 4) << 2;
#pragma unroll
            for (int mi = 0; mi < 3; ++mi)
#pragma unroll
                for (int ni = 0; ni < 2; ++ni) {
                    int m0 = mi * 16 + rg;
                    int cb = ni * 16 + lrow;
#pragma unroll
                    for (int r = 0; r < 4; ++r) epiw[m0 + r][cb] = acc[mi][ni][r];
                }
        }
        asm volatile("s_waitcnt lgkmcnt(0)" ::: "memory");
        __builtin_amdgcn_s_barrier();

#pragma unroll
        for (int rb = 0; rb < 2; ++rb) {
            int b = bp * 2 + rb;
            float s0 = 0.f, s1 = 0.f, s2 = 0.f;
#pragma unroll
            for (int ww = 0; ww < 4; ++ww) {
                float (*ep)[33] = (float(*)[33])(smem + 98304 + ww * 8192);
                s0 += ep[jl][b]; s1 += ep[16 + jl][b]; s2 += ep[32 + jl][b];
            }
            float rr = sigmoidf_(gi0[rb] + s0 + bh0);
            float zz = sigmoidf_(gi1[rb] + s1 + bh1);
            float nn = tanhf(gi2[rb] + rr * (s2 + bh2));
            float hnew = (1.0f - zz) * nn + zz * hpv[rb];
            hpv[rb] = hnew;
            store_u16_sc(BG + ((size_t)(b * 64 + t)) * 1536 + je, f2bf(hnew));
        }

        if (t < 63) {
            asm volatile("s_waitcnt vmcnt(0)" ::: "memory");
            __syncthreads();
            if (tid == 0)
                __hip_atomic_store(&flags[jb], (unsigned)(t + 1),
                                   __ATOMIC_RELAXED, __HIP_MEMORY_SCOPE_AGENT);
            unsigned tgt = (unsigned)(t + 1);
            while (true) {
                unsigned v = __hip_atomic_load(&flags[lane],
                                               __ATOMIC_RELAXED, __HIP_MEMORY_SCOPE_AGENT);
                if (__all(v >= tgt)) break;
                __builtin_amdgcn_s_sleep(1);
            }
            __builtin_amdgcn_sched_barrier(0);
        }
    }
}

// ------------------------------------------------- per-row lse from partials
__global__ __launch_bounds__(256) void k_lse(const float* __restrict__ pmax,
                                             const float* __restrict__ psum,
                                             float* __restrict__ lse) {
    int n = blockIdx.x;
    int t = threadIdx.x;
    __shared__ float sm[256];
    const float* pm = pmax + (size_t)n * NTMP;
    const float* ps = psum + (size_t)n * NTMP;
    float m = -1e30f;
    for (int p = t; p < NTM; p += 256) m = fmaxf(m, pm[p]);
    sm[t] = m;
    __syncthreads();
    for (int s = 128; s > 0; s >>= 1) { if (t < s) sm[t] = fmaxf(sm[t], sm[t + s]); __syncthreads(); }
    m = sm[0];
    __syncthreads();
    float s = 0.0f;
    for (int p = t; p < NTM; p += 256) s += ps[p] * expf(pm[p] - m);
    sm[t] = s;
    __syncthreads();
    for (int r = 128; r > 0; r >>= 1) { if (t < r) sm[t] += sm[t + r]; __syncthreads(); }
    if (t == 0) lse[n] = m + logf(sm[0]);
}

// ------------------------------------------------- final combine (fully coalesced)
__global__ __launch_bounds__(256) void k_final(const u16* __restrict__ Lb,
                                               const unsigned char* __restrict__ g8,
                                               const float* __restrict__ lse,
                                               const float* __restrict__ ks,
                                               const float* __restrict__ lsek,
                                               float* __restrict__ out) {
    int n = blockIdx.y;
    int b = n >> 6;
    float lsen = lse[n], lkb = lsek[b];
    int base = blockIdx.x * 2048;
#pragma unroll
    for (int i = 0; i < 8; ++i) {
        int v = base + i * 256 + threadIdx.x;
        if (v < VOC) {
            float L = bf2f(Lb[(size_t)n * VOCP + v]);
            float g = g8[(size_t)n * VOCP2 + v] * (1.0f / 255.0f);
            float kp = ((v >= 10 && v < 10 + KSN) ? ks[(size_t)b * KSN + (v - 10)] : 0.0f) - lkb;
            out[(size_t)n * VOC + v] = g * (L - lsen) + (1.0f - g) * kp;
        }
    }
}

// ---------------------------------------------------------------- launch
extern "C" void kernel_launch(void* const* d_in, const int* in_sizes, int n_in,
                              void* d_out, int out_size, void* d_ws, size_t ws_size,
                              hipStream_t stream) {
    const float* ses    = (const float*)d_in[0];
    const float* know   = (const float*)d_in[1];
    const int*   target = (const int*)d_in[2];
    const float* embed  = (const float*)d_in[3];
    const float* Wih    = (const float*)d_in[4];
    const float* Whh    = (const float*)d_in[5];
    const float* bih    = (const float*)d_in[6];
    const float* bhh    = (const float*)d_in[7];
    const float* sdw    = (const float*)d_in[8];
    const float* sdb    = (const float*)d_in[9];
    const float* dw     = (const float*)d_in[10];
    const float* siw    = (const float*)d_in[11];
    const float* ew     = (const float*)d_in[12];
    const float* eb     = (const float*)d_in[13];
    const float* W1     = (const float*)d_in[14];
    const float* W2     = (const float*)d_in[15];
    const float* W3     = (const float*)d_in[16];
    const float* W4     = (const float*)d_in[17];
    const float* kvw    = (const float*)d_in[18];

    char* ws = (char*)d_ws;
    size_t o = 0;
    auto alloc = [&](size_t bytes) { char* r = ws + o; o += (bytes + 255) & ~(size_t)255; return r; };
    u16*   Aemb  = (u16*)  alloc((size_t)VOCP * 512 * 2);
    u16*   A34   = (u16*)  alloc((size_t)VOCP2 * 1536 * 2);
    u16*   Adwew = (u16*)  alloc((size_t)1024 * 1536 * 2);
    u16*   Wihb  = (u16*)  alloc((size_t)3072 * 512 * 2);
    u16*   WhhB  = (u16*)  alloc((size_t)3072 * 1024 * 2);
    u16*   h0b   = (u16*)  alloc((size_t)32 * 1024 * 2);
    u16*   BG    = (u16*)  alloc((size_t)2048 * 1536 * 2);
    u16*   BL    = (u16*)  alloc((size_t)2048 * 512 * 2);
    float* GI    = (float*)alloc((size_t)2048 * 3072 * 4);
    float* h0    = (float*)alloc((size_t)32 * 1024 * 4);
    float* sesinf= (float*)alloc((size_t)32 * 1024 * 4);
    float* gc    = (float*)alloc((size_t)32 * VOCP2 * 4);
    float* ksb   = (float*)alloc((size_t)32 * KSN * 4);
    float* lsek  = (float*)alloc(256);
    float* lse   = (float*)alloc((size_t)2048 * 4);
    unsigned* flags = (unsigned*)alloc(256);
    float* pmax  = (float*)alloc((size_t)2048 * NTMP * 4);
    float* psum  = (float*)alloc((size_t)2048 * NTMP * 4);
    unsigned char* g8 = (unsigned char*)alloc((size_t)2048 * VOCP2);  // aliased: kvwb
    u16*   Lb    = (u16*)  alloc((size_t)2048 * VOCP * 2);            // aliased: Awk
    u16*   Bsk   = (u16*)  alloc((size_t)128 * 2048 * 2);
    float* out = (float*)d_out;

    u16*   kvwb  = (u16*)g8;       // 18.1 MB <= g8 (103 MB)
    u16*   Awk   = Lb;             // 50048*2048*2 == Lb size

    hipMemsetAsync(flags, 0, 256, stream);

    // weight conversions (early users of aliased buffers come first)
    k_cvt<<<dim3(VOC, 1), 256, 0, stream>>>(embed, Aemb, 512, 512, 512);
    k_cvt<<<dim3(VOC, 1), 256, 0, stream>>>(W3, A34, 1024, 1024, 1536);
    k_cvt<<<dim3(VOC, 1), 256, 0, stream>>>(W4, A34 + 1024, 512, 512, 1536);
    k_cvt<<<dim3(VOC, 1), 256, 0, stream>>>(W1, Awk, 1024, 1024, 2048);
    k_cvt<<<dim3(VOC, 1), 256, 0, stream>>>(W2, Awk + 1024, 1024, 1024, 2048);
    k_cvt<<<dim3(KSN, 1), 256, 0, stream>>>(kvw, kvwb, 1024, 1024, 1024);
    k_pad0<<<dim3(VOCP2 - VOC), 256, 0, stream>>>(Aemb, A34, Awk);
    k_padK<<<dim3(KSNP - KSN), 256, 0, stream>>>(kvwb);
    k_cvt<<<dim3(1024, 1), 256, 0, stream>>>(dw, Adwew, 1024, 1024, 1536);
    k_cvt<<<dim3(1024, 1), 256, 0, stream>>>(ew, Adwew + 1024, 512, 512, 1536);
    k_cvt<<<dim3(3072, 1), 256, 0, stream>>>(Wih, Wihb, 512, 512, 512);
    k_cvt<<<dim3(3072, 1), 256, 0, stream>>>(Whh, WhhB, 1024, 1024, 1024);
    k_bsk<<<dim3(128), 256, 0, stream>>>(ses, know, Bsk);

    k_gather<<<dim3(2048), 128, 0, stream>>>(embed, target, BG);
    k_h0_sesinf<<<dim3(32), 256, 0, stream>>>(ses, sdw, sdb, siw, h0, sesinf);
    k_cvt<<<dim3(32, 1), 256, 0, stream>>>(h0, h0b, 1024, 1024, 1024);

    // gc = [W1|W2] @ [ses|know]   (MFMA, n<32 valid, VOCP2 stride)
    gemm_bt<4><<<dim3(1, NTM), 256, 0, stream>>>(Awk, 2048, Bsk, 2048, 2048,
                                                 nullptr, nullptr, gc, nullptr, nullptr, nullptr);
    // ks = kvw @ know   (MFMA, B = know half of Bsk)
    gemm_bt<5><<<dim3(1, 69), 256, 0, stream>>>(kvwb, 1024, Bsk + 1024, 2048, 1024,
                                                nullptr, nullptr, ksb, nullptr, nullptr, nullptr);
    k_lseknow<<<dim3(32), 256, 0, stream>>>(ksb, lsek);

    // GI = TE @ Wih.T + bih
    gemm_bt<0><<<dim3(16, 24), 256, 0, stream>>>(Wihb, 512, BG + 1024, 1536, 512,
                                                 bih, nullptr, GI, nullptr, nullptr, nullptr);
    // GRU recurrence: persistent LDS-resident-weights MFMA kernel, fence-free barrier
    k_gru_m4<<<dim3(64), 256, 0, stream>>>(WhhB, GI, bhh, h0b, BG, flags);
    // MX (maxout) -> BL
    gemm_bt<1><<<dim3(16, 8), 256, 0, stream>>>(Adwew, 1536, BG, 1536, 1536,
                                                sesinf, eb, nullptr, BL, nullptr, nullptr);
    // gate GEMM -> g8  (256-tile, counted-vmcnt pipeline)
    gemm_gate8<<<dim3(1568), 512, 0, stream>>>(A34, BG, gc, g8);
    // logit GEMM -> Lb + partials
    gemm_bt<3><<<dim3(16, NTM), 256, 0, stream>>>(Aemb, 512, BL, 512, 512,
                                                  nullptr, nullptr, pmax, Lb, nullptr, psum);
    k_lse<<<dim3(2048), 256, 0, stream>>>(pmax, psum, lse);
    k_final<<<dim3(25, 2048), 256, 0, stream>>>(Lb, g8, lse, ksb, lsek, out);
}

// Round 10
// 1633.696 us; speedup vs baseline: 3.5524x; 1.0192x over previous
//
#include <hip/hip_runtime.h>

// Problem dims
constexpr int VOC  = 50005;
constexpr int VOCP = 50048;   // 391*128, padded vocab (128-tile GEMMs)
constexpr int VOCP2= 50176;   // 196*256, padded vocab (256-tile GEMM)
constexpr int NTM  = 391;     // vocab tiles (128) for 128-tile GEMMs
constexpr int NTMP = 400;     // padded partial stride
constexpr int KSN  = 8784;    // KNOW-1
constexpr int KSNP = 8832;    // 69*128
constexpr float NPAD = 41221.0f;

typedef unsigned short u16;
typedef __attribute__((ext_vector_type(4))) float f32x4;
typedef __attribute__((ext_vector_type(8))) short bf16x8;

__device__ __forceinline__ float dot4(float4 a, float4 b) {
    return a.x*b.x + a.y*b.y + a.z*b.z + a.w*b.w;
}
__device__ __forceinline__ float sigmoidf_(float x) { return 1.0f / (1.0f + expf(-x)); }
__device__ __forceinline__ u16 f2bf(float f) {
    unsigned x = __float_as_uint(f);
    return (u16)((x + 0x7FFFu + ((x >> 16) & 1u)) >> 16);
}
__device__ __forceinline__ float bf2f(u16 u) { return __uint_as_float(((unsigned)u) << 16); }
template<int AUX>
__device__ __forceinline__ void gload_lds16x(const void* g, void* l) {
    __builtin_amdgcn_global_load_lds((const __attribute__((address_space(1))) unsigned int*)g,
                                     (__attribute__((address_space(3))) unsigned int*)l, 16, 0, AUX);
}
__device__ __forceinline__ void gload_lds16(const void* g, void* l) { gload_lds16x<0>(g, l); }
// device-coherent u16 store (write-through to coherence point, cross-XCD visible)
__device__ __forceinline__ void store_u16_sc(u16* p, u16 v) {
    asm volatile("global_store_short %0, %1, off sc0 sc1" :: "v"(p), "v"((unsigned)v) : "memory");
}

// ---------------------------------------------------------------- cvt fp32 -> bf16 (strided)
__global__ __launch_bounds__(256) void k_cvt(const float* __restrict__ src, u16* __restrict__ dst,
                                             int ncols, int sld, int dld) {
    int row = blockIdx.x;
    int c = (blockIdx.y * 256 + threadIdx.x) * 4;
    if (c >= ncols) return;
    float4 v = *(const float4*)(src + (size_t)row * sld + c);
    unsigned lo = f2bf(v.x) | ((unsigned)f2bf(v.y) << 16);
    unsigned hi = f2bf(v.z) | ((unsigned)f2bf(v.w) << 16);
    *(uint2*)(dst + (size_t)row * dld + c) = make_uint2(lo, hi);
}

// zero pad rows 50005..50175 of A34 (VOCP2), 50005..50047 of Aemb / Awk (VOCP)
__global__ __launch_bounds__(256) void k_pad0(u16* __restrict__ Aemb, u16* __restrict__ A34,
                                              u16* __restrict__ Awk) {
    int r = VOC + blockIdx.x;            // 50005..50175
    unsigned* p3 = (unsigned*)(A34 + (size_t)r * 1536);
    for (int i = threadIdx.x; i < 768; i += 256) p3[i] = 0;
    if (r < VOCP) {
        unsigned* pe = (unsigned*)(Aemb + (size_t)r * 512);
        if (threadIdx.x < 256) pe[threadIdx.x] = 0;
        unsigned* pw = (unsigned*)(Awk + (size_t)r * 2048);
        for (int i = threadIdx.x; i < 1024; i += 256) pw[i] = 0;
    }
}
// zero pad rows 8784..8831 of kvwb
__global__ __launch_bounds__(256) void k_padK(u16* __restrict__ kvwb) {
    int r = KSN + blockIdx.x;
    unsigned* p = (unsigned*)(kvwb + (size_t)r * 1024);
    for (int i = threadIdx.x; i < 512; i += 256) p[i] = 0;
}

// build Bsk [128][2048] bf16: rows 0..31 = [ses|know], rows 32..127 = 0
__global__ __launch_bounds__(256) void k_bsk(const float* __restrict__ ses,
                                             const float* __restrict__ know,
                                             u16* __restrict__ Bsk) {
    int row = blockIdx.x;
    for (int c0 = threadIdx.x * 4; c0 < 2048; c0 += 1024) {
        uint2 val = make_uint2(0, 0);
        if (row < 32) {
            const float* srcp = (c0 < 1024) ? ses + (size_t)row * 1024 + c0
                                            : know + (size_t)row * 1024 + (c0 - 1024);
            float4 v = *(const float4*)srcp;
            val = make_uint2(f2bf(v.x) | ((unsigned)f2bf(v.y) << 16),
                             f2bf(v.z) | ((unsigned)f2bf(v.w) << 16));
        }
        *(uint2*)(Bsk + (size_t)row * 2048 + c0) = val;
    }
}

// ---------------------------------------------------------------- gather target embeddings -> BG[:,1024:1536] bf16
__global__ __launch_bounds__(128) void k_gather(const float* __restrict__ embed,
                                                const int* __restrict__ target,
                                                u16* __restrict__ BG) {
    int n = blockIdx.x;
    int row = target[n];
    int c = threadIdx.x * 4;
    float4 v = *(const float4*)(embed + (size_t)row * 512 + c);
    unsigned lo = f2bf(v.x) | ((unsigned)f2bf(v.y) << 16);
    unsigned hi = f2bf(v.z) | ((unsigned)f2bf(v.w) << 16);
    *(uint2*)(BG + (size_t)n * 1536 + 1024 + c) = make_uint2(lo, hi);
}

// ------------------------------------------------- h0 + ses_inf_vec (fp32, small)
__global__ __launch_bounds__(256) void k_h0_sesinf(const float* __restrict__ ses,
                                                   const float* __restrict__ sdw,
                                                   const float* __restrict__ sdb,
                                                   const float* __restrict__ siw,
                                                   float* __restrict__ h0,
                                                   float* __restrict__ sesinf) {
    int g = blockIdx.x * 256 + threadIdx.x;
    int b = g & 31;
    int jg = g >> 5;
    int j0 = jg * 4;
    const float4* s4 = (const float4*)(ses + (size_t)b * 1024);
    const float4* wa[4];
    const float4* wc[4];
#pragma unroll
    for (int r = 0; r < 4; ++r) {
        wa[r] = (const float4*)(sdw + (size_t)(j0 + r) * 1024);
        wc[r] = (const float4*)(siw + (size_t)(j0 + r) * 1024);
    }
    float a[4] = {0, 0, 0, 0}, c[4] = {0, 0, 0, 0};
    for (int kq = 0; kq < 256; ++kq) {
        float4 sv = s4[kq];
#pragma unroll
        for (int r = 0; r < 4; ++r) { a[r] += dot4(sv, wa[r][kq]); c[r] += dot4(sv, wc[r][kq]); }
    }
#pragma unroll
    for (int r = 0; r < 4; ++r) {
        h0[b * 1024 + j0 + r] = tanhf(a[r] + sdb[j0 + r]);
        sesinf[b * 1024 + j0 + r] = c[r];
    }
}

// ------------------------------------------------- lse of padded know scores
__global__ __launch_bounds__(256) void k_lseknow(const float* __restrict__ ks,
                                                 float* __restrict__ lsek) {
    int b = blockIdx.x;
    int t = threadIdx.x;
    __shared__ float sm[256];
    float m = -1e30f;
    for (int j = t; j < KSN; j += 256) m = fmaxf(m, ks[(size_t)b * KSN + j]);
    sm[t] = m;
    __syncthreads();
    for (int s = 128; s > 0; s >>= 1) { if (t < s) sm[t] = fmaxf(sm[t], sm[t + s]); __syncthreads(); }
    m = fmaxf(sm[0], 0.0f);
    __syncthreads();
    float s = 0.0f;
    for (int j = t; j < KSN; j += 256) s += expf(ks[(size_t)b * KSN + j] - m);
    sm[t] = s;
    __syncthreads();
    for (int r = 128; r > 0; r >>= 1) { if (t < r) sm[t] += sm[t + r]; __syncthreads(); }
    if (t == 0) lsek[b] = m + logf(sm[0] + NPAD * expf(0.0f - m));
}

// ================================================= templated bf16 MFMA GEMM (C[m][n] = A[m]·B[n]) 128-tile
// EPI 0: GI (+bias, fp32)  EPI 1: MX maxout  EPI 3: logits+partials
// EPI 4: gc fp32 [b][VOCP2] (n<32)  EPI 5: ks fp32 [b][KSN] (n<32, m<KSN)
template<int EPI>
__global__ __launch_bounds__(256) void gemm_bt(
    const u16* __restrict__ A, int lda,
    const u16* __restrict__ B, int ldb, int K,
    const float* __restrict__ p0, const float* __restrict__ p1,
    float* __restrict__ q0, u16* __restrict__ q1,
    unsigned char* __restrict__ q2, float* __restrict__ q3)
{
    __shared__ u16 Asm[128 * 64];
    __shared__ u16 Bsm[128 * 64];
    const int tid = threadIdx.x;
    const int lane = tid & 63;
    const int w = tid >> 6;
    const int wm = w >> 1, wn = w & 1;
    const int nt = blockIdx.x, mt = blockIdx.y;

    f32x4 acc[4][4];
#pragma unroll
    for (int i = 0; i < 4; ++i)
#pragma unroll
        for (int j = 0; j < 4; ++j) acc[i][j] = (f32x4){0.f, 0.f, 0.f, 0.f};

    for (int kt = 0; kt < K; kt += 64) {
#pragma unroll
        for (int p = 0; p < 4; ++p) {
            int flat = (w * 4 + p) * 64 + lane;       // 0..1023 16B-slots
            int row = flat >> 3, slot = flat & 7;
            int ss = slot ^ (row & 7);                // inverse-swizzled source slot
            gload_lds16(A + (size_t)(mt * 128 + row) * lda + kt + ss * 8, Asm + flat * 8);
            gload_lds16(B + (size_t)(nt * 128 + row) * ldb + kt + ss * 8, Bsm + flat * 8);
        }
        __syncthreads();
#pragma unroll
        for (int kc = 0; kc < 2; ++kc) {
            bf16x8 af[4], bfr[4];
#pragma unroll
            for (int mi = 0; mi < 4; ++mi) {
                int row = wm * 64 + mi * 16 + (lane & 15);
                int bcol = kc * 64 + ((lane >> 4) << 4);
                af[mi] = *(const bf16x8*)((const char*)Asm + row * 128 + (bcol ^ ((row & 7) << 4)));
            }
#pragma unroll
            for (int ni = 0; ni < 4; ++ni) {
                int row = wn * 64 + ni * 16 + (lane & 15);
                int bcol = kc * 64 + ((lane >> 4) << 4);
                bfr[ni] = *(const bf16x8*)((const char*)Bsm + row * 128 + (bcol ^ ((row & 7) << 4)));
            }
#pragma unroll
            for (int mi = 0; mi < 4; ++mi)
#pragma unroll
                for (int ni = 0; ni < 4; ++ni)
                    acc[mi][ni] = __builtin_amdgcn_mfma_f32_16x16x32_bf16(af[mi], bfr[ni], acc[mi][ni], 0, 0, 0);
        }
        __syncthreads();
    }

    const int cl = lane & 15;           // n offset within fragment
    const int rg = (lane >> 4) << 2;    // m base within fragment

    if constexpr (EPI == 0) {           // GI = TE@Wih.T + bih  (fp32 [n][3072])
#pragma unroll
        for (int mi = 0; mi < 4; ++mi) {
            int m0 = mt * 128 + wm * 64 + mi * 16 + rg;
            float4 bias = *(const float4*)(p0 + m0);
#pragma unroll
            for (int ni = 0; ni < 4; ++ni) {
                int n = nt * 128 + wn * 64 + ni * 16 + cl;
                float4 v;
                v.x = acc[mi][ni][0] + bias.x; v.y = acc[mi][ni][1] + bias.y;
                v.z = acc[mi][ni][2] + bias.z; v.w = acc[mi][ni][3] + bias.w;
                *(float4*)(q0 + (size_t)n * 3072 + m0) = v;
            }
        }
    }
    if constexpr (EPI == 1) {           // maxout -> BL bf16 [n][512]
#pragma unroll
        for (int mi = 0; mi < 4; ++mi) {
            int m0 = mt * 128 + wm * 64 + mi * 16 + rg;
            float4 eb4 = *(const float4*)(p1 + m0);
#pragma unroll
            for (int ni = 0; ni < 4; ++ni) {
                int n = nt * 128 + wn * 64 + ni * 16 + cl;
                int b = n >> 6;
                float v0 = acc[mi][ni][0] + p0[b * 1024 + m0 + 0] + eb4.x;
                float v1 = acc[mi][ni][1] + p0[b * 1024 + m0 + 1] + eb4.y;
                float v2 = acc[mi][ni][2] + p0[b * 1024 + m0 + 2] + eb4.z;
                float v3 = acc[mi][ni][3] + p0[b * 1024 + m0 + 3] + eb4.w;
                unsigned pk = f2bf(fmaxf(v0, v1)) | ((unsigned)f2bf(fmaxf(v2, v3)) << 16);
                *(unsigned*)(q1 + (size_t)n * 512 + (m0 >> 1)) = pk;
            }
        }
    }
    if constexpr (EPI == 3) {           // logits -> Lb bf16 [n][VOCP] + partial max/sumexp
        __shared__ float redm[2][128];
        __shared__ float reds[2][128];
#pragma unroll
        for (int mi = 0; mi < 4; ++mi) {
            int v0 = mt * 128 + wm * 64 + mi * 16 + rg;
#pragma unroll
            for (int ni = 0; ni < 4; ++ni) {
                int n = nt * 128 + wn * 64 + ni * 16 + cl;
                unsigned lo = f2bf(acc[mi][ni][0]) | ((unsigned)f2bf(acc[mi][ni][1]) << 16);
                unsigned hi = f2bf(acc[mi][ni][2]) | ((unsigned)f2bf(acc[mi][ni][3]) << 16);
                *(uint2*)(q1 + (size_t)n * VOCP + v0) = make_uint2(lo, hi);
            }
        }
#pragma unroll
        for (int ni = 0; ni < 4; ++ni) {
            float lm = -1e30f;
#pragma unroll
            for (int mi = 0; mi < 4; ++mi) {
                int v0 = mt * 128 + wm * 64 + mi * 16 + rg;
#pragma unroll
                for (int r = 0; r < 4; ++r)
                    if (v0 + r < VOC) lm = fmaxf(lm, acc[mi][ni][r]);
            }
            lm = fmaxf(lm, __shfl_xor(lm, 16));
            lm = fmaxf(lm, __shfl_xor(lm, 32));
            float s = 0.0f;
#pragma unroll
            for (int mi = 0; mi < 4; ++mi) {
                int v0 = mt * 128 + wm * 64 + mi * 16 + rg;
#pragma unroll
                for (int r = 0; r < 4; ++r)
                    if (v0 + r < VOC) s += expf(acc[mi][ni][r] - lm);
            }
            s += __shfl_xor(s, 16);
            s += __shfl_xor(s, 32);
            if (lane < 16) {
                redm[wm][wn * 64 + ni * 16 + lane] = lm;
                reds[wm][wn * 64 + ni * 16 + lane] = s;
            }
        }
        __syncthreads();
        if (tid < 128) {
            float m0_ = redm[0][tid], m1_ = redm[1][tid];
            float m = fmaxf(m0_, m1_);
            float s = reds[0][tid] * expf(m0_ - m) + reds[1][tid] * expf(m1_ - m);
            int n = nt * 128 + tid;
            q0[(size_t)n * NTMP + mt] = m;
            q3[(size_t)n * NTMP + mt] = s;
        }
    }
    if constexpr (EPI == 4) {           // gc fp32 [b][VOCP2], only n<32 valid
#pragma unroll
        for (int mi = 0; mi < 4; ++mi) {
            int m0 = mt * 128 + wm * 64 + mi * 16 + rg;
#pragma unroll
            for (int ni = 0; ni < 4; ++ni) {
                int n = nt * 128 + wn * 64 + ni * 16 + cl;
                if (n < 32) {
                    float4 v;
                    v.x = acc[mi][ni][0]; v.y = acc[mi][ni][1];
                    v.z = acc[mi][ni][2]; v.w = acc[mi][ni][3];
                    *(float4*)(q0 + (size_t)n * VOCP2 + m0) = v;
                }
            }
        }
    }
    if constexpr (EPI == 5) {           // ks fp32 [b][KSN], n<32, m<KSN
#pragma unroll
        for (int mi = 0; mi < 4; ++mi) {
            int m0 = mt * 128 + wm * 64 + mi * 16 + rg;
#pragma unroll
            for (int ni = 0; ni < 4; ++ni) {
                int n = nt * 128 + wn * 64 + ni * 16 + cl;
                if (n < 32 && m0 < KSN) {
                    float4 v;
                    v.x = acc[mi][ni][0]; v.y = acc[mi][ni][1];
                    v.z = acc[mi][ni][2]; v.w = acc[mi][ni][3];
                    *(float4*)(q0 + (size_t)n * KSN + m0) = v;
                }
            }
        }
    }
}

// ================================================= 256x256 8-phase gate GEMM (m201-style)
// BK=64, 2 dbufs x (2 A-halves + 2 B-halves) x 16KB = 128KB LDS. 512 threads = 8 waves
// (2M x 4N); per-wave output 128x64 = acc[8][4]. Half-tile layout [128 rows][64 cols]
// bf16, 128B rows, slot swizzle s ^ (r&7) (measured conflict-free in gemm_bt).
// Phase q computes M-quadrant q (16 MFMA); B reg-loaded once per K-tile (phase 0).
// Stage ledger (iter i: T0=2i buf0 P1-4, T1=2i+1 buf1 P5-8):
//   P1,P2: A(T1) -> buf1 A (dead since prev P8)   P3,P4: B(T0+2) -> buf0 B (dead since P1)
//   P5,P6: A(T0+2) -> buf0 A (dead since P4)      P7,P8: B(T1+2) -> buf1 B (dead since P5)
// vmcnt(4) at P4/P8 only (2 half-tiles stay in flight across barriers).
__global__ __launch_bounds__(512, 1) void gemm_gate8(
    const u16* __restrict__ A,      // A34 [VOCP2][1536]
    const u16* __restrict__ B,      // BG  [2048][1536]
    const float* __restrict__ gc2,  // [32][VOCP2]
    unsigned char* __restrict__ g8) // [2048][VOCP2]
{
    __shared__ __align__(16) char smem[131072];
    const int tid = threadIdx.x;
    const int lane = tid & 63;
    const int w = tid >> 6;
    const int wm = w >> 2;          // 0..1: M half
    const int wn = w & 3;           // 0..3: N quarter
    const int lrow = lane & 15;
    const int g = lane >> 4;

    // XCD-chunked bijective block swizzle: 1568 = 8 * 196
    int bid = blockIdx.x;
    int wg = (bid & 7) * 196 + (bid >> 3);
    int mt = wg >> 3;               // 0..195
    int nt = wg & 7;                // 0..7
    const size_t arow0 = (size_t)mt * 256;
    const size_t brow0 = (size_t)nt * 256;

    auto stageA = [&](int T, int h) {
        char* dst = smem + (T & 1) * 65536 + h * 16384;
        const u16* src = A + (arow0 + h * 128) * 1536 + T * 64;
#pragma unroll
        for (int q = 0; q < 2; ++q) {
            int flat = q * 512 + tid;
            int r = flat >> 3, s = flat & 7;
            int ss = s ^ (r & 7);
            gload_lds16(src + (size_t)r * 1536 + ss * 8, dst + flat * 16);
        }
    };
    auto stageB = [&](int T, int h) {
        char* dst = smem + (T & 1) * 65536 + 32768 + h * 16384;
        const u16* src = B + (brow0 + h * 128) * 1536 + T * 64;
#pragma unroll
        for (int q = 0; q < 2; ++q) {
            int flat = q * 512 + tid;
            int r = flat >> 3, s = flat & 7;
            int ss = s ^ (r & 7);
            gload_lds16(src + (size_t)r * 1536 + ss * 8, dst + flat * 16);
        }
    };

    f32x4 acc[8][4];
#pragma unroll
    for (int i = 0; i < 8; ++i)
#pragma unroll
        for (int j = 0; j < 4; ++j) acc[i][j] = (f32x4){0.f, 0.f, 0.f, 0.f};

    bf16x8 bf[4][2];
    auto loadB_ = [&](int d) {
        char* Bb = smem + d * 65536 + 32768 + (wn >> 1) * 16384;
#pragma unroll
        for (int ni = 0; ni < 4; ++ni) {
            int r = (wn & 1) * 64 + ni * 16 + lrow;
#pragma unroll
            for (int kk = 0; kk < 2; ++kk)
                bf[ni][kk] = *(const bf16x8*)(Bb + r * 128 + ((kk * 64 + g * 16) ^ ((r & 7) << 4)));
        }
    };

#define GPH(D, Q, LB, STG, VM)                                                        \
    {                                                                                 \
        if (LB) loadB_(D);                                                            \
        bf16x8 af[2][2];                                                              \
        char* Ab = smem + (D) * 65536 + wm * 16384;                                   \
        _Pragma("unroll") for (int mi = 0; mi < 2; ++mi) {                            \
            int r = ((Q) * 2 + mi) * 16 + lrow;                                       \
            _Pragma("unroll") for (int kk = 0; kk < 2; ++kk)                          \
                af[mi][kk] = *(const bf16x8*)(Ab + r * 128 +                          \
                                ((kk * 64 + g * 16) ^ ((r & 7) << 4)));               \
        }                                                                             \
        STG;                                                                          \
        __builtin_amdgcn_s_barrier();                                                 \
        asm volatile("s_waitcnt lgkmcnt(0)" ::: "memory");                            \
        __builtin_amdgcn_sched_barrier(0);                                            \
        __builtin_amdgcn_s_setprio(1);                                                \
        _Pragma("unroll") for (int kk = 0; kk < 2; ++kk)                              \
            _Pragma("unroll") for (int mi = 0; mi < 2; ++mi)                          \
                _Pragma("unroll") for (int ni = 0; ni < 4; ++ni)                      \
                    acc[(Q) * 2 + mi][ni] = __builtin_amdgcn_mfma_f32_16x16x32_bf16(  \
                        af[mi][kk], bf[ni][kk], acc[(Q) * 2 + mi][ni], 0, 0, 0);      \
        __builtin_amdgcn_s_setprio(0);                                                \
        VM;                                                                           \
        __builtin_amdgcn_s_barrier();                                                 \
    }
#define VM4 asm volatile("s_waitcnt vmcnt(4)" ::: "memory"); __builtin_amdgcn_sched_barrier(0)
#define VM0 asm volatile("s_waitcnt vmcnt(0)" ::: "memory"); __builtin_amdgcn_sched_barrier(0)
#define NOP (void)0

    // prologue: B(0) x2, A(0) x2, B(1) x2  (6 half-tiles, 12 loads)
    stageB(0, 0); stageB(0, 1); stageA(0, 0); stageA(0, 1); stageB(1, 0); stageB(1, 1);
    VM4;                                     // A(0),B(0) landed; B(1) may be in flight
    __builtin_amdgcn_s_barrier();

    for (int i = 0; i < 11; ++i) {           // tiles 0..21 computed, staged through 23
        int T0 = 2 * i, T1 = 2 * i + 1;
        GPH(0, 0, true,  stageA(T1, 0),     NOP);     // P1
        GPH(0, 1, false, stageA(T1, 1),     NOP);     // P2
        GPH(0, 2, false, stageB(T0 + 2, 0), NOP);     // P3
        GPH(0, 3, false, stageB(T0 + 2, 1), VM4);     // P4
        GPH(1, 0, true,  stageA(T0 + 2, 0), NOP);     // P5
        GPH(1, 1, false, stageA(T0 + 2, 1), NOP);     // P6
        GPH(1, 2, false, stageB(T1 + 2, 0), NOP);     // P7
        GPH(1, 3, false, stageB(T1 + 2, 1), VM4);     // P8
    }
    // peeled last iteration: T0=22, T1=23 (A(23) staged here; B(23) staged in i=10)
    GPH(0, 0, true,  stageA(23, 0), NOP);
    GPH(0, 1, false, stageA(23, 1), NOP);
    GPH(0, 2, false, NOP,           NOP);
    GPH(0, 3, false, NOP,           VM0);
    GPH(1, 0, true,  NOP,           NOP);
    GPH(1, 1, false, NOP,           NOP);
    GPH(1, 2, false, NOP,           NOP);
    GPH(1, 3, false, NOP,           NOP);
#undef GPH
#undef VM4
#undef VM0
#undef NOP

    // ---- epilogue: gate = sigmoid(acc + gc), pack 4 x u8
    const int rg = g << 2;
    const int b = nt * 4 + wn;               // uniform per wave
    const float* gcrow = gc2 + (size_t)b * VOCP2;
#pragma unroll
    for (int m = 0; m < 8; ++m) {
        int v0 = mt * 256 + wm * 128 + m * 16 + rg;
        float4 gcv = *(const float4*)(gcrow + v0);
#pragma unroll
        for (int ni = 0; ni < 4; ++ni) {
            int n = nt * 256 + wn * 64 + ni * 16 + lrow;
            unsigned pk = 0;
#pragma unroll
            for (int r = 0; r < 4; ++r) {
                float garg = acc[m][ni][r] + ((const float*)&gcv)[r];
                float gate = 1.0f / (1.0f + expf(-garg));
                pk |= ((unsigned)(int)(gate * 255.0f + 0.5f)) << (8 * r);
            }
            *(unsigned*)(g8 + (size_t)n * VOCP2 + v0) = pk;
        }
    }
}

// ------------------------------------------------- persistent MFMA GRU v4 (round-8, validated)
__global__ __launch_bounds__(256, 1) void k_gru_m4(const u16* __restrict__ WhhB,
                                                   const float* __restrict__ GI,
                                                   const float* __restrict__ bhh,
                                                   const u16* __restrict__ h0b,
                                                   u16* __restrict__ BG,
                                                   unsigned* __restrict__ flags) {
    __shared__ __align__(16) char smem[131072];
    const int tid = threadIdx.x;
    const int lane = tid & 63;
    const int w = tid >> 6;
    const int jb = blockIdx.x;            // 0..63
    const int j0 = jb * 16;
    const int jl = tid & 15, bp = tid >> 4;
    const int je = j0 + jl;
    const float bh0 = bhh[je], bh1 = bhh[1024 + je], bh2 = bhh[2048 + je];
    char* Bbase = smem + 98304 + w * 8192;

#pragma unroll
    for (int it = 0; it < 24; ++it) {
        int flat = (it * 4 + w) * 64 + lane;
        int r = flat >> 7, s = flat & 127;
        int ss = s ^ (r & 7);
        int gr = (r >> 4) * 1024 + j0 + (r & 15);
        gload_lds16(WhhB + (size_t)gr * 1024 + ss * 8, smem + (size_t)flat * 16);
    }

    float hpv[2];
#pragma unroll
    for (int rb = 0; rb < 2; ++rb)
        hpv[rb] = bf2f(h0b[(size_t)(bp * 2 + rb) * 1024 + je]);

    const int lrow = lane & 15;
    const int ksel = lane >> 4;

    for (int t = 0; t < 64; ++t) {
        const u16* hsrc = (t == 0) ? h0b : BG + (size_t)(t - 1) * 1536;
        const size_t hstr = (t == 0) ? 1024 : (size_t)64 * 1536;

        float gi0[2], gi1[2], gi2[2];
#pragma unroll
        for (int rb = 0; rb < 2; ++rb) {
            const float* gp = GI + ((size_t)((bp * 2 + rb) * 64 + t)) * 3072 + je;
            gi0[rb] = gp[0]; gi1[rb] = gp[1024]; gi2[rb] = gp[2048];
        }
        __builtin_amdgcn_sched_barrier(0);

        auto stageB = [&](int c) {
            char* dst = Bbase + (c & 1) * 4096;
            int kq0 = w * 256 + c * 64;
#pragma unroll
            for (int q = 0; q < 4; ++q) {
                int flat = q * 64 + lane;
                int r = flat >> 3, s = flat & 7;
                int ss = s ^ (r & 7);
                gload_lds16x<0x11>(hsrc + (size_t)r * hstr + kq0 + ss * 8,
                                   dst + (size_t)flat * 16);
            }
        };
        stageB(0); stageB(1);
        if (t == 0) {
            __syncthreads();
        } else {
            asm volatile("s_waitcnt vmcnt(4)" ::: "memory");
        }
        __builtin_amdgcn_sched_barrier(0);

        f32x4 acc[3][2];
#pragma unroll
        for (int mi = 0; mi < 3; ++mi)
#pragma unroll
            for (int ni = 0; ni < 2; ++ni) acc[mi][ni] = (f32x4){0.f, 0.f, 0.f, 0.f};

#pragma unroll
        for (int c = 0; c < 4; ++c) {
            char* Bb = Bbase + (c & 1) * 4096;
#pragma unroll
            for (int ks = 0; ks < 2; ++ks) {
                int kb = ks * 64 + ksel * 16;
                bf16x8 bfr[2];
#pragma unroll
                for (int ni = 0; ni < 2; ++ni) {
                    int br = ni * 16 + lrow;
                    bfr[ni] = *(const bf16x8*)(Bb + br * 128 + (kb ^ ((br & 7) << 4)));
                }
                int kA = w * 512 + c * 128 + kb;
#pragma unroll
                for (int mi = 0; mi < 3; ++mi) {
                    int ar = mi * 16 + lrow;
                    bf16x8 af = *(const bf16x8*)(smem + ar * 2048 + (kA ^ ((ar & 7) << 4)));
#pragma unroll
                    for (int ni = 0; ni < 2; ++ni)
                        acc[mi][ni] = __builtin_amdgcn_mfma_f32_16x16x32_bf16(af, bfr[ni], acc[mi][ni], 0, 0, 0);
                }
            }
            asm volatile("s_waitcnt lgkmcnt(0)" ::: "memory");
            __builtin_amdgcn_sched_barrier(0);
            if (c < 2) {
                stageB(c + 2);
                asm volatile("s_waitcnt vmcnt(4)" ::: "memory");
            } else if (c == 2) {
                asm volatile("s_waitcnt vmcnt(0)" ::: "memory");
            }
            __builtin_amdgcn_sched_barrier(0);
        }

        float (*epiw)[33] = (float(*)[33])Bbase;
        {
            const int rg = (lane >> 4) << 2;
#pragma unroll
            for (int mi = 0; mi < 3; ++mi)
#pragma unroll
                for (int ni = 0; ni < 2; ++ni) {
                    int m0 = mi * 16 + rg;
                    int cb = ni * 16 + lrow;
#pragma unroll
                    for (int r = 0; r < 4; ++r) epiw[m0 + r][cb] = acc[mi][ni][r];
                }
        }
        asm volatile("s_waitcnt lgkmcnt(0)" ::: "memory");
        __builtin_amdgcn_s_barrier();

#pragma unroll
        for (int rb = 0; rb < 2; ++rb) {
            int b = bp * 2 + rb;
            float s0 = 0.f, s1 = 0.f, s2 = 0.f;
#pragma unroll
            for (int ww = 0; ww < 4; ++ww) {
                float (*ep)[33] = (float(*)[33])(smem + 98304 + ww * 8192);
                s0 += ep[jl][b]; s1 += ep[16 + jl][b]; s2 += ep[32 + jl][b];
            }
            float rr = sigmoidf_(gi0[rb] + s0 + bh0);
            float zz = sigmoidf_(gi1[rb] + s1 + bh1);
            float nn = tanhf(gi2[rb] + rr * (s2 + bh2));
            float hnew = (1.0f - zz) * nn + zz * hpv[rb];
            hpv[rb] = hnew;
            store_u16_sc(BG + ((size_t)(b * 64 + t)) * 1536 + je, f2bf(hnew));
        }

        if (t < 63) {
            asm volatile("s_waitcnt vmcnt(0)" ::: "memory");
            __syncthreads();
            if (tid == 0)
                __hip_atomic_store(&flags[jb], (unsigned)(t + 1),
                                   __ATOMIC_RELAXED, __HIP_MEMORY_SCOPE_AGENT);
            unsigned tgt = (unsigned)(t + 1);
            while (true) {
                unsigned v = __hip_atomic_load(&flags[lane],
                                               __ATOMIC_RELAXED, __HIP_MEMORY_SCOPE_AGENT);
                if (__all(v >= tgt)) break;
                __builtin_amdgcn_s_sleep(1);
            }
            __builtin_amdgcn_sched_barrier(0);
        }
    }
}

// ------------------------------------------------- per-row lse from partials
__global__ __launch_bounds__(256) void k_lse(const float* __restrict__ pmax,
                                             const float* __restrict__ psum,
                                             float* __restrict__ lse) {
    int n = blockIdx.x;
    int t = threadIdx.x;
    __shared__ float sm[256];
    const float* pm = pmax + (size_t)n * NTMP;
    const float* ps = psum + (size_t)n * NTMP;
    float m = -1e30f;
    for (int p = t; p < NTM; p += 256) m = fmaxf(m, pm[p]);
    sm[t] = m;
    __syncthreads();
    for (int s = 128; s > 0; s >>= 1) { if (t < s) sm[t] = fmaxf(sm[t], sm[t + s]); __syncthreads(); }
    m = sm[0];
    __syncthreads();
    float s = 0.0f;
    for (int p = t; p < NTM; p += 256) s += ps[p] * expf(pm[p] - m);
    sm[t] = s;
    __syncthreads();
    for (int r = 128; r > 0; r >>= 1) { if (t < r) sm[t] += sm[t + r]; __syncthreads(); }
    if (t == 0) lse[n] = m + logf(sm[0]);
}

// ------------------------------------------------- final combine (fully coalesced)
__global__ __launch_bounds__(256) void k_final(const u16* __restrict__ Lb,
                                               const unsigned char* __restrict__ g8,
                                               const float* __restrict__ lse,
                                               const float* __restrict__ ks,
                                               const float* __restrict__ lsek,
                                               float* __restrict__ out) {
    int n = blockIdx.y;
    int b = n >> 6;
    float lsen = lse[n], lkb = lsek[b];
    int base = blockIdx.x * 2048;
#pragma unroll
    for (int i = 0; i < 8; ++i) {
        int v = base + i * 256 + threadIdx.x;
        if (v < VOC) {
            float L = bf2f(Lb[(size_t)n * VOCP + v]);
            float g = g8[(size_t)n * VOCP2 + v] * (1.0f / 255.0f);
            float kp = ((v >= 10 && v < 10 + KSN) ? ks[(size_t)b * KSN + (v - 10)] : 0.0f) - lkb;
            out[(size_t)n * VOC + v] = g * (L - lsen) + (1.0f - g) * kp;
        }
    }
}

// ---------------------------------------------------------------- launch
extern "C" void kernel_launch(void* const* d_in, const int* in_sizes, int n_in,
                              void* d_out, int out_size, void* d_ws, size_t ws_size,
                              hipStream_t stream) {
    const float* ses    = (const float*)d_in[0];
    const float* know   = (const float*)d_in[1];
    const int*   target = (const int*)d_in[2];
    const float* embed  = (const float*)d_in[3];
    const float* Wih    = (const float*)d_in[4];
    const float* Whh    = (const float*)d_in[5];
    const float* bih    = (const float*)d_in[6];
    const float* bhh    = (const float*)d_in[7];
    const float* sdw    = (const float*)d_in[8];
    const float* sdb    = (const float*)d_in[9];
    const float* dw     = (const float*)d_in[10];
    const float* siw    = (const float*)d_in[11];
    const float* ew     = (const float*)d_in[12];
    const float* eb     = (const float*)d_in[13];
    const float* W1     = (const float*)d_in[14];
    const float* W2     = (const float*)d_in[15];
    const float* W3     = (const float*)d_in[16];
    const float* W4     = (const float*)d_in[17];
    const float* kvw    = (const float*)d_in[18];

    char* ws = (char*)d_ws;
    size_t o = 0;
    auto alloc = [&](size_t bytes) { char* r = ws + o; o += (bytes + 255) & ~(size_t)255; return r; };
    u16*   Aemb  = (u16*)  alloc((size_t)VOCP * 512 * 2);
    u16*   A34   = (u16*)  alloc((size_t)VOCP2 * 1536 * 2);
    u16*   Adwew = (u16*)  alloc((size_t)1024 * 1536 * 2);
    u16*   Wihb  = (u16*)  alloc((size_t)3072 * 512 * 2);
    u16*   WhhB  = (u16*)  alloc((size_t)3072 * 1024 * 2);
    u16*   h0b   = (u16*)  alloc((size_t)32 * 1024 * 2);
    u16*   BG    = (u16*)  alloc((size_t)2048 * 1536 * 2);
    u16*   BL    = (u16*)  alloc((size_t)2048 * 512 * 2);
    float* GI    = (float*)alloc((size_t)2048 * 3072 * 4);
    float* h0    = (float*)alloc((size_t)32 * 1024 * 4);
    float* sesinf= (float*)alloc((size_t)32 * 1024 * 4);
    float* gc    = (float*)alloc((size_t)32 * VOCP2 * 4);
    float* ksb   = (float*)alloc((size_t)32 * KSN * 4);
    float* lsek  = (float*)alloc(256);
    float* lse   = (float*)alloc((size_t)2048 * 4);
    unsigned* flags = (unsigned*)alloc(256);
    float* pmax  = (float*)alloc((size_t)2048 * NTMP * 4);
    float* psum  = (float*)alloc((size_t)2048 * NTMP * 4);
    unsigned char* g8 = (unsigned char*)alloc((size_t)2048 * VOCP2);  // aliased: kvwb
    u16*   Lb    = (u16*)  alloc((size_t)2048 * VOCP * 2);            // aliased: Awk
    u16*   Bsk   = (u16*)  alloc((size_t)128 * 2048 * 2);
    float* out = (float*)d_out;

    u16*   kvwb  = (u16*)g8;       // 18.1 MB <= g8 (103 MB)
    u16*   Awk   = Lb;             // 50048*2048*2 == Lb size

    hipMemsetAsync(flags, 0, 256, stream);

    // weight conversions (early users of aliased buffers come first)
    k_cvt<<<dim3(VOC, 1), 256, 0, stream>>>(embed, Aemb, 512, 512, 512);
    k_cvt<<<dim3(VOC, 1), 256, 0, stream>>>(W3, A34, 1024, 1024, 1536);
    k_cvt<<<dim3(VOC, 1), 256, 0, stream>>>(W4, A34 + 1024, 512, 512, 1536);
    k_cvt<<<dim3(VOC, 1), 256, 0, stream>>>(W1, Awk, 1024, 1024, 2048);
    k_cvt<<<dim3(VOC, 1), 256, 0, stream>>>(W2, Awk + 1024, 1024, 1024, 2048);
    k_cvt<<<dim3(KSN, 1), 256, 0, stream>>>(kvw, kvwb, 1024, 1024, 1024);
    k_pad0<<<dim3(VOCP2 - VOC), 256, 0, stream>>>(Aemb, A34, Awk);
    k_padK<<<dim3(KSNP - KSN), 256, 0, stream>>>(kvwb);
    k_cvt<<<dim3(1024, 1), 256, 0, stream>>>(dw, Adwew, 1024, 1024, 1536);
    k_cvt<<<dim3(1024, 1), 256, 0, stream>>>(ew, Adwew + 1024, 512, 512, 1536);
    k_cvt<<<dim3(3072, 1), 256, 0, stream>>>(Wih, Wihb, 512, 512, 512);
    k_cvt<<<dim3(3072, 1), 256, 0, stream>>>(Whh, WhhB, 1024, 1024, 1024);
    k_bsk<<<dim3(128), 256, 0, stream>>>(ses, know, Bsk);

    k_gather<<<dim3(2048), 128, 0, stream>>>(embed, target, BG);
    k_h0_sesinf<<<dim3(32), 256, 0, stream>>>(ses, sdw, sdb, siw, h0, sesinf);
    k_cvt<<<dim3(32, 1), 256, 0, stream>>>(h0, h0b, 1024, 1024, 1024);

    // gc = [W1|W2] @ [ses|know]   (MFMA, n<32 valid, VOCP2 stride)
    gemm_bt<4><<<dim3(1, NTM), 256, 0, stream>>>(Awk, 2048, Bsk, 2048, 2048,
                                                 nullptr, nullptr, gc, nullptr, nullptr, nullptr);
    // ks = kvw @ know   (MFMA, B = know half of Bsk)
    gemm_bt<5><<<dim3(1, 69), 256, 0, stream>>>(kvwb, 1024, Bsk + 1024, 2048, 1024,
                                                nullptr, nullptr, ksb, nullptr, nullptr, nullptr);
    k_lseknow<<<dim3(32), 256, 0, stream>>>(ksb, lsek);

    // GI = TE @ Wih.T + bih
    gemm_bt<0><<<dim3(16, 24), 256, 0, stream>>>(Wihb, 512, BG + 1024, 1536, 512,
                                                 bih, nullptr, GI, nullptr, nullptr, nullptr);
    // GRU recurrence: persistent LDS-resident-weights MFMA kernel, fence-free barrier
    k_gru_m4<<<dim3(64), 256, 0, stream>>>(WhhB, GI, bhh, h0b, BG, flags);
    // MX (maxout) -> BL
    gemm_bt<1><<<dim3(16, 8), 256, 0, stream>>>(Adwew, 1536, BG, 1536, 1536,
                                                sesinf, eb, nullptr, BL, nullptr, nullptr);
    // gate GEMM -> g8  (256-tile, 8-phase counted-vmcnt pipeline)
    gemm_gate8<<<dim3(1568), 512, 0, stream>>>(A34, BG, gc, g8);
    // logit GEMM -> Lb + partials
    gemm_bt<3><<<dim3(16, NTM), 256, 0, stream>>>(Aemb, 512, BL, 512, 512,
                                                  nullptr, nullptr, pmax, Lb, nullptr, psum);
    k_lse<<<dim3(2048), 256, 0, stream>>>(pmax, psum, lse);
    k_final<<<dim3(25, 2048), 256, 0, stream>>>(Lb, g8, lse, ksb, lsek, out);
}

// Round 11
// 1569.009 us; speedup vs baseline: 3.6988x; 1.0412x over previous
//
#include <hip/hip_runtime.h>

// Problem dims
constexpr int VOC  = 50005;
constexpr int VOCP = 50048;   // 391*128, padded vocab (128-tile GEMMs)
constexpr int VOCP2= 50176;   // 196*256, padded vocab (256-tile GEMM)
constexpr int NTM  = 391;     // vocab tiles (128) for 128-tile GEMMs
constexpr int NTMP = 400;     // padded partial stride
constexpr int KSN  = 8784;    // KNOW-1
constexpr float NPAD = 41221.0f;

typedef unsigned short u16;
typedef __attribute__((ext_vector_type(4))) float f32x4;
typedef __attribute__((ext_vector_type(8))) short bf16x8;

__device__ __forceinline__ float dot4(float4 a, float4 b) {
    return a.x*b.x + a.y*b.y + a.z*b.z + a.w*b.w;
}
__device__ __forceinline__ float sigmoidf_(float x) { return 1.0f / (1.0f + expf(-x)); }
__device__ __forceinline__ u16 f2bf(float f) {
    unsigned x = __float_as_uint(f);
    return (u16)((x + 0x7FFFu + ((x >> 16) & 1u)) >> 16);
}
__device__ __forceinline__ float bf2f(u16 u) { return __uint_as_float(((unsigned)u) << 16); }
__device__ __forceinline__ bf16x8 pack8(float4 lo, float4 hi) {
    union { bf16x8 v; unsigned u[4]; } r;
    r.u[0] = f2bf(lo.x) | ((unsigned)f2bf(lo.y) << 16);
    r.u[1] = f2bf(lo.z) | ((unsigned)f2bf(lo.w) << 16);
    r.u[2] = f2bf(hi.x) | ((unsigned)f2bf(hi.y) << 16);
    r.u[3] = f2bf(hi.z) | ((unsigned)f2bf(hi.w) << 16);
    return r.v;
}
template<int AUX>
__device__ __forceinline__ void gload_lds16x(const void* g, void* l) {
    __builtin_amdgcn_global_load_lds((const __attribute__((address_space(1))) unsigned int*)g,
                                     (__attribute__((address_space(3))) unsigned int*)l, 16, 0, AUX);
}
__device__ __forceinline__ void gload_lds16(const void* g, void* l) { gload_lds16x<0>(g, l); }
// device-coherent u16 store (write-through to coherence point, cross-XCD visible)
__device__ __forceinline__ void store_u16_sc(u16* p, u16 v) {
    asm volatile("global_store_short %0, %1, off sc0 sc1" :: "v"(p), "v"((unsigned)v) : "memory");
}

// ---------------------------------------------------------------- cvt fp32 -> bf16 (strided)
__global__ __launch_bounds__(256) void k_cvt(const float* __restrict__ src, u16* __restrict__ dst,
                                             int ncols, int sld, int dld) {
    int row = blockIdx.x;
    int c = (blockIdx.y * 256 + threadIdx.x) * 4;
    if (c >= ncols) return;
    float4 v = *(const float4*)(src + (size_t)row * sld + c);
    unsigned lo = f2bf(v.x) | ((unsigned)f2bf(v.y) << 16);
    unsigned hi = f2bf(v.z) | ((unsigned)f2bf(v.w) << 16);
    *(uint2*)(dst + (size_t)row * dld + c) = make_uint2(lo, hi);
}

// zero pad rows 50005..50175 of A34 (VOCP2), 50005..50047 of Aemb (VOCP)
__global__ __launch_bounds__(256) void k_pad0(u16* __restrict__ Aemb, u16* __restrict__ A34) {
    int r = VOC + blockIdx.x;            // 50005..50175
    unsigned* p3 = (unsigned*)(A34 + (size_t)r * 1536);
    for (int i = threadIdx.x; i < 768; i += 256) p3[i] = 0;
    if (r < VOCP) {
        unsigned* pe = (unsigned*)(Aemb + (size_t)r * 512);
        if (threadIdx.x < 256) pe[threadIdx.x] = 0;
    }
}

// build Bsk [128][2048] bf16: rows 0..31 = [ses|know], rows 32..127 = 0
__global__ __launch_bounds__(256) void k_bsk(const float* __restrict__ ses,
                                             const float* __restrict__ know,
                                             u16* __restrict__ Bsk) {
    int row = blockIdx.x;
    for (int c0 = threadIdx.x * 4; c0 < 2048; c0 += 1024) {
        uint2 val = make_uint2(0, 0);
        if (row < 32) {
            const float* srcp = (c0 < 1024) ? ses + (size_t)row * 1024 + c0
                                            : know + (size_t)row * 1024 + (c0 - 1024);
            float4 v = *(const float4*)srcp;
            val = make_uint2(f2bf(v.x) | ((unsigned)f2bf(v.y) << 16),
                             f2bf(v.z) | ((unsigned)f2bf(v.w) << 16));
        }
        *(uint2*)(Bsk + (size_t)row * 2048 + c0) = val;
    }
}

// ---------------------------------------------------------------- gather target embeddings -> BG[:,1024:1536] bf16
__global__ __launch_bounds__(128) void k_gather(const float* __restrict__ embed,
                                                const int* __restrict__ target,
                                                u16* __restrict__ BG) {
    int n = blockIdx.x;
    int row = target[n];
    int c = threadIdx.x * 4;
    float4 v = *(const float4*)(embed + (size_t)row * 512 + c);
    unsigned lo = f2bf(v.x) | ((unsigned)f2bf(v.y) << 16);
    unsigned hi = f2bf(v.z) | ((unsigned)f2bf(v.w) << 16);
    *(uint2*)(BG + (size_t)n * 1536 + 1024 + c) = make_uint2(lo, hi);
}

// ------------------------------------------------- h0 + ses_inf_vec (fp32, small)
__global__ __launch_bounds__(256) void k_h0_sesinf(const float* __restrict__ ses,
                                                   const float* __restrict__ sdw,
                                                   const float* __restrict__ sdb,
                                                   const float* __restrict__ siw,
                                                   float* __restrict__ h0,
                                                   float* __restrict__ sesinf) {
    int g = blockIdx.x * 256 + threadIdx.x;
    int b = g & 31;
    int jg = g >> 5;
    int j0 = jg * 4;
    const float4* s4 = (const float4*)(ses + (size_t)b * 1024);
    const float4* wa[4];
    const float4* wc[4];
#pragma unroll
    for (int r = 0; r < 4; ++r) {
        wa[r] = (const float4*)(sdw + (size_t)(j0 + r) * 1024);
        wc[r] = (const float4*)(siw + (size_t)(j0 + r) * 1024);
    }
    float a[4] = {0, 0, 0, 0}, c[4] = {0, 0, 0, 0};
    for (int kq = 0; kq < 256; ++kq) {
        float4 sv = s4[kq];
#pragma unroll
        for (int r = 0; r < 4; ++r) { a[r] += dot4(sv, wa[r][kq]); c[r] += dot4(sv, wc[r][kq]); }
    }
#pragma unroll
    for (int r = 0; r < 4; ++r) {
        h0[b * 1024 + j0 + r] = tanhf(a[r] + sdb[j0 + r]);
        sesinf[b * 1024 + j0 + r] = c[r];
    }
}

// ------------------------------------------------- lse of padded know scores
__global__ __launch_bounds__(256) void k_lseknow(const float* __restrict__ ks,
                                                 float* __restrict__ lsek) {
    int b = blockIdx.x;
    int t = threadIdx.x;
    __shared__ float sm[256];
    float m = -1e30f;
    for (int j = t; j < KSN; j += 256) m = fmaxf(m, ks[(size_t)b * KSN + j]);
    sm[t] = m;
    __syncthreads();
    for (int s = 128; s > 0; s >>= 1) { if (t < s) sm[t] = fmaxf(sm[t], sm[t + s]); __syncthreads(); }
    m = fmaxf(sm[0], 0.0f);
    __syncthreads();
    float s = 0.0f;
    for (int j = t; j < KSN; j += 256) s += expf(ks[(size_t)b * KSN + j] - m);
    sm[t] = s;
    __syncthreads();
    for (int r = 128; r > 0; r >>= 1) { if (t < r) sm[t] += sm[t + r]; __syncthreads(); }
    if (t == 0) lsek[b] = m + logf(sm[0] + NPAD * expf(0.0f - m));
}

// ================================================= skinny-N=32 fp32-A MFMA GEMM (no cvt pass)
// MODE 0: gc[b][v] = ses[b]·W1[v] + know[b]·W2[v]  (A=[W1|W2] fp32 K=2048, out [32][VOCP2])
// MODE 1: ks[b][v] = know[b]·kvw[v]                (A=kvw fp32 K=1024, out [32][KSN])
// 128 threads = 2 waves x 32 vocab rows; fragments loaded direct from global fp32,
// converted in-register (identical rounding to the old cvt+GEMM path).
template<int MODE>
__global__ __launch_bounds__(128) void k_sk32(const float* __restrict__ A1,
                                              const float* __restrict__ A2,
                                              const u16* __restrict__ Bsk,
                                              float* __restrict__ outp) {
    const int lane = threadIdx.x & 63;
    const int w = threadIdx.x >> 6;
    const int lrow = lane & 15;
    const int kg = lane >> 4;
    constexpr int K = (MODE == 0) ? 2048 : 1024;
    constexpr int bc0 = (MODE == 0) ? 0 : 1024;
    const int rowmax = (MODE == 0) ? (VOC - 1) : (KSN - 1);
    const int vb = blockIdx.x * 64 + w * 32;
    const int r0 = min(vb + lrow, rowmax);
    const int r1 = min(vb + 16 + lrow, rowmax);
    f32x4 acc[2][2] = {{{0.f,0.f,0.f,0.f},{0.f,0.f,0.f,0.f}},
                       {{0.f,0.f,0.f,0.f},{0.f,0.f,0.f,0.f}}};
    for (int k0 = 0; k0 < K; k0 += 32) {
        int kc = k0 + kg * 8;
        const float* s0;
        const float* s1;
        if (MODE == 0 && k0 >= 1024) {
            s0 = A2 + (size_t)r0 * 1024 + (kc - 1024);
            s1 = A2 + (size_t)r1 * 1024 + (kc - 1024);
        } else {
            s0 = A1 + (size_t)r0 * 1024 + kc;
            s1 = A1 + (size_t)r1 * 1024 + kc;
        }
        bf16x8 af0 = pack8(*(const float4*)s0, *(const float4*)(s0 + 4));
        bf16x8 af1 = pack8(*(const float4*)s1, *(const float4*)(s1 + 4));
        bf16x8 b0 = *(const bf16x8*)(Bsk + (size_t)lrow * 2048 + bc0 + kc);
        bf16x8 b1 = *(const bf16x8*)(Bsk + (size_t)(16 + lrow) * 2048 + bc0 + kc);
        acc[0][0] = __builtin_amdgcn_mfma_f32_16x16x32_bf16(af0, b0, acc[0][0], 0, 0, 0);
        acc[0][1] = __builtin_amdgcn_mfma_f32_16x16x32_bf16(af0, b1, acc[0][1], 0, 0, 0);
        acc[1][0] = __builtin_amdgcn_mfma_f32_16x16x32_bf16(af1, b0, acc[1][0], 0, 0, 0);
        acc[1][1] = __builtin_amdgcn_mfma_f32_16x16x32_bf16(af1, b1, acc[1][1], 0, 0, 0);
    }
    const int rg = kg * 4;
#pragma unroll
    for (int mi = 0; mi < 2; ++mi)
#pragma unroll
        for (int ni = 0; ni < 2; ++ni)
#pragma unroll
            for (int r = 0; r < 4; ++r) {
                int v = vb + mi * 16 + rg + r;
                int b = ni * 16 + lrow;
                if (MODE == 0) outp[(size_t)b * VOCP2 + v] = acc[mi][ni][r];
                else if (v < KSN) outp[(size_t)b * KSN + v] = acc[mi][ni][r];
            }
}

// ================================================= templated bf16 MFMA GEMM (C[m][n] = A[m]·B[n]) 128-tile
// EPI 0: GI (+bias, fp32)  EPI 1: MX maxout  EPI 3: logits+partials
template<int EPI>
__global__ __launch_bounds__(256) void gemm_bt(
    const u16* __restrict__ A, int lda,
    const u16* __restrict__ B, int ldb, int K,
    const float* __restrict__ p0, const float* __restrict__ p1,
    float* __restrict__ q0, u16* __restrict__ q1,
    unsigned char* __restrict__ q2, float* __restrict__ q3)
{
    __shared__ u16 Asm[128 * 64];
    __shared__ u16 Bsm[128 * 64];
    const int tid = threadIdx.x;
    const int lane = tid & 63;
    const int w = tid >> 6;
    const int wm = w >> 1, wn = w & 1;
    const int nt = blockIdx.x, mt = blockIdx.y;

    f32x4 acc[4][4];
#pragma unroll
    for (int i = 0; i < 4; ++i)
#pragma unroll
        for (int j = 0; j < 4; ++j) acc[i][j] = (f32x4){0.f, 0.f, 0.f, 0.f};

    for (int kt = 0; kt < K; kt += 64) {
#pragma unroll
        for (int p = 0; p < 4; ++p) {
            int flat = (w * 4 + p) * 64 + lane;       // 0..1023 16B-slots
            int row = flat >> 3, slot = flat & 7;
            int ss = slot ^ (row & 7);                // inverse-swizzled source slot
            gload_lds16(A + (size_t)(mt * 128 + row) * lda + kt + ss * 8, Asm + flat * 8);
            gload_lds16(B + (size_t)(nt * 128 + row) * ldb + kt + ss * 8, Bsm + flat * 8);
        }
        __syncthreads();
#pragma unroll
        for (int kc = 0; kc < 2; ++kc) {
            bf16x8 af[4], bfr[4];
#pragma unroll
            for (int mi = 0; mi < 4; ++mi) {
                int row = wm * 64 + mi * 16 + (lane & 15);
                int bcol = kc * 64 + ((lane >> 4) << 4);
                af[mi] = *(const bf16x8*)((const char*)Asm + row * 128 + (bcol ^ ((row & 7) << 4)));
            }
#pragma unroll
            for (int ni = 0; ni < 4; ++ni) {
                int row = wn * 64 + ni * 16 + (lane & 15);
                int bcol = kc * 64 + ((lane >> 4) << 4);
                bfr[ni] = *(const bf16x8*)((const char*)Bsm + row * 128 + (bcol ^ ((row & 7) << 4)));
            }
#pragma unroll
            for (int mi = 0; mi < 4; ++mi)
#pragma unroll
                for (int ni = 0; ni < 4; ++ni)
                    acc[mi][ni] = __builtin_amdgcn_mfma_f32_16x16x32_bf16(af[mi], bfr[ni], acc[mi][ni], 0, 0, 0);
        }
        __syncthreads();
    }

    const int cl = lane & 15;           // n offset within fragment
    const int rg = (lane >> 4) << 2;    // m base within fragment

    if constexpr (EPI == 0) {           // GI = TE@Wih.T + bih  (fp32 [n][3072])
#pragma unroll
        for (int mi = 0; mi < 4; ++mi) {
            int m0 = mt * 128 + wm * 64 + mi * 16 + rg;
            float4 bias = *(const float4*)(p0 + m0);
#pragma unroll
            for (int ni = 0; ni < 4; ++ni) {
                int n = nt * 128 + wn * 64 + ni * 16 + cl;
                float4 v;
                v.x = acc[mi][ni][0] + bias.x; v.y = acc[mi][ni][1] + bias.y;
                v.z = acc[mi][ni][2] + bias.z; v.w = acc[mi][ni][3] + bias.w;
                *(float4*)(q0 + (size_t)n * 3072 + m0) = v;
            }
        }
    }
    if constexpr (EPI == 1) {           // maxout -> BL bf16 [n][512]
#pragma unroll
        for (int mi = 0; mi < 4; ++mi) {
            int m0 = mt * 128 + wm * 64 + mi * 16 + rg;
            float4 eb4 = *(const float4*)(p1 + m0);
#pragma unroll
            for (int ni = 0; ni < 4; ++ni) {
                int n = nt * 128 + wn * 64 + ni * 16 + cl;
                int b = n >> 6;
                float v0 = acc[mi][ni][0] + p0[b * 1024 + m0 + 0] + eb4.x;
                float v1 = acc[mi][ni][1] + p0[b * 1024 + m0 + 1] + eb4.y;
                float v2 = acc[mi][ni][2] + p0[b * 1024 + m0 + 2] + eb4.z;
                float v3 = acc[mi][ni][3] + p0[b * 1024 + m0 + 3] + eb4.w;
                unsigned pk = f2bf(fmaxf(v0, v1)) | ((unsigned)f2bf(fmaxf(v2, v3)) << 16);
                *(unsigned*)(q1 + (size_t)n * 512 + (m0 >> 1)) = pk;
            }
        }
    }
    if constexpr (EPI == 3) {           // logits -> Lb bf16 [n][VOCP] + partial max/sumexp
        __shared__ float redm[2][128];
        __shared__ float reds[2][128];
#pragma unroll
        for (int mi = 0; mi < 4; ++mi) {
            int v0 = mt * 128 + wm * 64 + mi * 16 + rg;
#pragma unroll
            for (int ni = 0; ni < 4; ++ni) {
                int n = nt * 128 + wn * 64 + ni * 16 + cl;
                unsigned lo = f2bf(acc[mi][ni][0]) | ((unsigned)f2bf(acc[mi][ni][1]) << 16);
                unsigned hi = f2bf(acc[mi][ni][2]) | ((unsigned)f2bf(acc[mi][ni][3]) << 16);
                *(uint2*)(q1 + (size_t)n * VOCP + v0) = make_uint2(lo, hi);
            }
        }
#pragma unroll
        for (int ni = 0; ni < 4; ++ni) {
            float lm = -1e30f;
#pragma unroll
            for (int mi = 0; mi < 4; ++mi) {
                int v0 = mt * 128 + wm * 64 + mi * 16 + rg;
#pragma unroll
                for (int r = 0; r < 4; ++r)
                    if (v0 + r < VOC) lm = fmaxf(lm, acc[mi][ni][r]);
            }
            lm = fmaxf(lm, __shfl_xor(lm, 16));
            lm = fmaxf(lm, __shfl_xor(lm, 32));
            float s = 0.0f;
#pragma unroll
            for (int mi = 0; mi < 4; ++mi) {
                int v0 = mt * 128 + wm * 64 + mi * 16 + rg;
#pragma unroll
                for (int r = 0; r < 4; ++r)
                    if (v0 + r < VOC) s += expf(acc[mi][ni][r] - lm);
            }
            s += __shfl_xor(s, 16);
            s += __shfl_xor(s, 32);
            if (lane < 16) {
                redm[wm][wn * 64 + ni * 16 + lane] = lm;
                reds[wm][wn * 64 + ni * 16 + lane] = s;
            }
        }
        __syncthreads();
        if (tid < 128) {
            float m0_ = redm[0][tid], m1_ = redm[1][tid];
            float m = fmaxf(m0_, m1_);
            float s = reds[0][tid] * expf(m0_ - m) + reds[1][tid] * expf(m1_ - m);
            int n = nt * 128 + tid;
            q0[(size_t)n * NTMP + mt] = m;
            q3[(size_t)n * NTMP + mt] = s;
        }
    }
}

// ================================================= 256x256 8-phase gate GEMM, minimal barriers.
// Same geometry/layout as r10 (BK=64, 2 dbufs x 2 halves x {A,B} x 16KB = 128KB LDS,
// 8 waves 2Mx4N, 128B rows, slot^(r&7) swizzle — measured conflict-free).
// CHANGE: only 4 barriers/iteration, at the real hazard boundaries:
//   P2|P3 (buf0-B WAR before B(T0+2) stage)   P4|P5 (buf1 RAW + buf0-A WAR) [vmcnt(4) first]
//   P6|P7 (buf1-B WAR before B(T1+2) stage)   P8|P1' (buf0 RAW)            [vmcnt(4) first]
// Between barriers waves skew up to 2 phases -> LDS read service overlaps other waves' MFMA.
// vmcnt ledger (steady state): at P4 wait leaves {P3,P4}=B(T0+2) in flight (prevP7,prevP8=B(T1),
// P1,P2=A(T1) landed); at P8 leaves {P7,P8}=B(T1+2) (P3..P6 landed). Last iter: vmcnt(0) at P4
// (A(23) staged only 2 phases before its P5 use).
__global__ __launch_bounds__(512, 1) void gemm_gate8(
    const u16* __restrict__ A,      // A34 [VOCP2][1536]
    const u16* __restrict__ B,      // BG  [2048][1536]
    const float* __restrict__ gc2,  // [32][VOCP2]
    unsigned char* __restrict__ g8) // [2048][VOCP2]
{
    __shared__ __align__(16) char smem[131072];
    const int tid = threadIdx.x;
    const int lane = tid & 63;
    const int w = tid >> 6;
    const int wm = w >> 2;          // 0..1: M half
    const int wn = w & 3;           // 0..3: N quarter
    const int lrow = lane & 15;
    const int g = lane >> 4;

    // XCD-chunked bijective block swizzle: 1568 = 8 * 196
    int bid = blockIdx.x;
    int wg = (bid & 7) * 196 + (bid >> 3);
    int mt = wg >> 3;               // 0..195
    int nt = wg & 7;                // 0..7
    const size_t arow0 = (size_t)mt * 256;
    const size_t brow0 = (size_t)nt * 256;

    auto stageA = [&](int T, int h) {
        char* dst = smem + (T & 1) * 65536 + h * 16384;
        const u16* src = A + (arow0 + h * 128) * 1536 + T * 64;
#pragma unroll
        for (int q = 0; q < 2; ++q) {
            int flat = q * 512 + tid;
            int r = flat >> 3, s = flat & 7;
            int ss = s ^ (r & 7);
            gload_lds16(src + (size_t)r * 1536 + ss * 8, dst + flat * 16);
        }
    };
    auto stageB = [&](int T, int h) {
        char* dst = smem + (T & 1) * 65536 + 32768 + h * 16384;
        const u16* src = B + (brow0 + h * 128) * 1536 + T * 64;
#pragma unroll
        for (int q = 0; q < 2; ++q) {
            int flat = q * 512 + tid;
            int r = flat >> 3, s = flat & 7;
            int ss = s ^ (r & 7);
            gload_lds16(src + (size_t)r * 1536 + ss * 8, dst + flat * 16);
        }
    };

    f32x4 acc[8][4];
#pragma unroll
    for (int i = 0; i < 8; ++i)
#pragma unroll
        for (int j = 0; j < 4; ++j) acc[i][j] = (f32x4){0.f, 0.f, 0.f, 0.f};

    bf16x8 bf[4][2];
    auto loadB_ = [&](int d) {
        char* Bb = smem + d * 65536 + 32768 + (wn >> 1) * 16384;
#pragma unroll
        for (int ni = 0; ni < 4; ++ni) {
            int r = (wn & 1) * 64 + ni * 16 + lrow;
#pragma unroll
            for (int kk = 0; kk < 2; ++kk)
                bf[ni][kk] = *(const bf16x8*)(Bb + r * 128 + ((kk * 64 + g * 16) ^ ((r & 7) << 4)));
        }
    };

#define GPH2(D, Q, LB, STG)                                                           \
    {                                                                                 \
        STG;                                                                          \
        if (LB) loadB_(D);                                                            \
        bf16x8 af[2][2];                                                              \
        char* Ab = smem + (D) * 65536 + wm * 16384;                                   \
        _Pragma("unroll") for (int mi = 0; mi < 2; ++mi) {                            \
            int r = ((Q) * 2 + mi) * 16 + lrow;                                       \
            _Pragma("unroll") for (int kk = 0; kk < 2; ++kk)                          \
                af[mi][kk] = *(const bf16x8*)(Ab + r * 128 +                          \
                                ((kk * 64 + g * 16) ^ ((r & 7) << 4)));               \
        }                                                                             \
        asm volatile("s_waitcnt lgkmcnt(0)" ::: "memory");                            \
        __builtin_amdgcn_sched_barrier(0);                                            \
        __builtin_amdgcn_s_setprio(1);                                                \
        _Pragma("unroll") for (int kk = 0; kk < 2; ++kk)                              \
            _Pragma("unroll") for (int mi = 0; mi < 2; ++mi)                          \
                _Pragma("unroll") for (int ni = 0; ni < 4; ++ni)                      \
                    acc[(Q) * 2 + mi][ni] = __builtin_amdgcn_mfma_f32_16x16x32_bf16(  \
                        af[mi][kk], bf[ni][kk], acc[(Q) * 2 + mi][ni], 0, 0, 0);      \
        __builtin_amdgcn_s_setprio(0);                                                \
    }
#define BARR  __builtin_amdgcn_sched_barrier(0); __builtin_amdgcn_s_barrier(); \
              __builtin_amdgcn_sched_barrier(0)
#define VM4 asm volatile("s_waitcnt vmcnt(4)" ::: "memory"); __builtin_amdgcn_sched_barrier(0)
#define VM0 asm volatile("s_waitcnt vmcnt(0)" ::: "memory"); __builtin_amdgcn_sched_barrier(0)
#define NOPX (void)0

    // prologue: B(0) x2, A(0) x2, B(1) x2  (6 half-tiles, 12 loads)
    stageB(0, 0); stageB(0, 1); stageA(0, 0); stageA(0, 1); stageB(1, 0); stageB(1, 1);
    VM4;                                     // A(0),B(0) landed; B(1) may be in flight
    BARR;

    for (int i = 0; i < 11; ++i) {           // tiles 0..21 computed, staged through 23
        int T0 = 2 * i, T1 = 2 * i + 1;
        GPH2(0, 0, true,  stageA(T1, 0));
        GPH2(0, 1, false, stageA(T1, 1));
        BARR;
        GPH2(0, 2, false, stageB(T0 + 2, 0));
        GPH2(0, 3, false, stageB(T0 + 2, 1));
        VM4; BARR;
        GPH2(1, 0, true,  stageA(T0 + 2, 0));
        GPH2(1, 1, false, stageA(T0 + 2, 1));
        BARR;
        GPH2(1, 2, false, stageB(T1 + 2, 0));
        GPH2(1, 3, false, stageB(T1 + 2, 1));
        VM4; BARR;
    }
    // peeled last iteration: T0=22, T1=23 (A(23) staged here; B(23) staged in i=10)
    GPH2(0, 0, true,  stageA(23, 0));
    GPH2(0, 1, false, stageA(23, 1));
    BARR;
    GPH2(0, 2, false, NOPX);
    GPH2(0, 3, false, NOPX);
    VM0; BARR;
    GPH2(1, 0, true,  NOPX);
    GPH2(1, 1, false, NOPX);
    GPH2(1, 2, false, NOPX);
    GPH2(1, 3, false, NOPX);
#undef GPH2
#undef BARR
#undef VM4
#undef VM0
#undef NOPX

    // ---- epilogue: gate = sigmoid(acc + gc), pack 4 x u8
    const int rg = g << 2;
    const int b = nt * 4 + wn;               // uniform per wave
    const float* gcrow = gc2 + (size_t)b * VOCP2;
#pragma unroll
    for (int m = 0; m < 8; ++m) {
        int v0 = mt * 256 + wm * 128 + m * 16 + rg;
        float4 gcv = *(const float4*)(gcrow + v0);
#pragma unroll
        for (int ni = 0; ni < 4; ++ni) {
            int n = nt * 256 + wn * 64 + ni * 16 + lrow;
            unsigned pk = 0;
#pragma unroll
            for (int r = 0; r < 4; ++r) {
                float garg = acc[m][ni][r] + ((const float*)&gcv)[r];
                float gate = 1.0f / (1.0f + expf(-garg));
                pk |= ((unsigned)(int)(gate * 255.0f + 0.5f)) << (8 * r);
            }
            *(unsigned*)(g8 + (size_t)n * VOCP2 + v0) = pk;
        }
    }
}

// ------------------------------------------------- persistent MFMA GRU v4 (round-8, validated)
__global__ __launch_bounds__(256, 1) void k_gru_m4(const u16* __restrict__ WhhB,
                                                   const float* __restrict__ GI,
                                                   const float* __restrict__ bhh,
                                                   const u16* __restrict__ h0b,
                                                   u16* __restrict__ BG,
                                                   unsigned* __restrict__ flags) {
    __shared__ __align__(16) char smem[131072];
    const int tid = threadIdx.x;
    const int lane = tid & 63;
    const int w = tid >> 6;
    const int jb = blockIdx.x;            // 0..63
    const int j0 = jb * 16;
    const int jl = tid & 15, bp = tid >> 4;
    const int je = j0 + jl;
    const float bh0 = bhh[je], bh1 = bhh[1024 + je], bh2 = bhh[2048 + je];
    char* Bbase = smem + 98304 + w * 8192;

#pragma unroll
    for (int it = 0; it < 24; ++it) {
        int flat = (it * 4 + w) * 64 + lane;
        int r = flat >> 7, s = flat & 127;
        int ss = s ^ (r & 7);
        int gr = (r >> 4) * 1024 + j0 + (r & 15);
        gload_lds16(WhhB + (size_t)gr * 1024 + ss * 8, smem + (size_t)flat * 16);
    }

    float hpv[2];
#pragma unroll
    for (int rb = 0; rb < 2; ++rb)
        hpv[rb] = bf2f(h0b[(size_t)(bp * 2 + rb) * 1024 + je]);

    const int lrow = lane & 15;
    const int ksel = lane >> 4;

    for (int t = 0; t < 64; ++t) {
        const u16* hsrc = (t == 0) ? h0b : BG + (size_t)(t - 1) * 1536;
        const size_t hstr = (t == 0) ? 1024 : (size_t)64 * 1536;

        float gi0[2], gi1[2], gi2[2];
#pragma unroll
        for (int rb = 0; rb < 2; ++rb) {
            const float* gp = GI + ((size_t)((bp * 2 + rb) * 64 + t)) * 3072 + je;
            gi0[rb] = gp[0]; gi1[rb] = gp[1024]; gi2[rb] = gp[2048];
        }
        __builtin_amdgcn_sched_barrier(0);

        auto stageB = [&](int c) {
            char* dst = Bbase + (c & 1) * 4096;
            int kq0 = w * 256 + c * 64;
#pragma unroll
            for (int q = 0; q < 4; ++q) {
                int flat = q * 64 + lane;
                int r = flat >> 3, s = flat & 7;
                int ss = s ^ (r & 7);
                gload_lds16x<0x11>(hsrc + (size_t)r * hstr + kq0 + ss * 8,
                                   dst + (size_t)flat * 16);
            }
        };
        stageB(0); stageB(1);
        if (t == 0) {
            __syncthreads();
        } else {
            asm volatile("s_waitcnt vmcnt(4)" ::: "memory");
        }
        __builtin_amdgcn_sched_barrier(0);

        f32x4 acc[3][2];
#pragma unroll
        for (int mi = 0; mi < 3; ++mi)
#pragma unroll
            for (int ni = 0; ni < 2; ++ni) acc[mi][ni] = (f32x4){0.f, 0.f, 0.f, 0.f};

#pragma unroll
        for (int c = 0; c < 4; ++c) {
            char* Bb = Bbase + (c & 1) * 4096;
#pragma unroll
            for (int ks = 0; ks < 2; ++ks) {
                int kb = ks * 64 + ksel * 16;
                bf16x8 bfr[2];
#pragma unroll
                for (int ni = 0; ni < 2; ++ni) {
                    int br = ni * 16 + lrow;
                    bfr[ni] = *(const bf16x8*)(Bb + br * 128 + (kb ^ ((br & 7) << 4)));
                }
                int kA = w * 512 + c * 128 + kb;
#pragma unroll
                for (int mi = 0; mi < 3; ++mi) {
                    int ar = mi * 16 + lrow;
                    bf16x8 af = *(const bf16x8*)(smem + ar * 2048 + (kA ^ ((ar & 7) << 4)));
#pragma unroll
                    for (int ni = 0; ni < 2; ++ni)
                        acc[mi][ni] = __builtin_amdgcn_mfma_f32_16x16x32_bf16(af, bfr[ni], acc[mi][ni], 0, 0, 0);
                }
            }
            asm volatile("s_waitcnt lgkmcnt(0)" ::: "memory");
            __builtin_amdgcn_sched_barrier(0);
            if (c < 2) {
                stageB(c + 2);
                asm volatile("s_waitcnt vmcnt(4)" ::: "memory");
            } else if (c == 2) {
                asm volatile("s_waitcnt vmcnt(0)" ::: "memory");
            }
            __builtin_amdgcn_sched_barrier(0);
        }

        float (*epiw)[33] = (float(*)[33])Bbase;
        {
            const int rg = (lane >> 4) << 2;
#pragma unroll
            for (int mi = 0; mi < 3; ++mi)
#pragma unroll
                for (int ni = 0; ni < 2; ++ni) {
                    int m0 = mi * 16 + rg;
                    int cb = ni * 16 + lrow;
#pragma unroll
                    for (int r = 0; r < 4; ++r) epiw[m0 + r][cb] = acc[mi][ni][r];
                }
        }
        asm volatile("s_waitcnt lgkmcnt(0)" ::: "memory");
        __builtin_amdgcn_s_barrier();

#pragma unroll
        for (int rb = 0; rb < 2; ++rb) {
            int b = bp * 2 + rb;
            float s0 = 0.f, s1 = 0.f, s2 = 0.f;
#pragma unroll
            for (int ww = 0; ww < 4; ++ww) {
                float (*ep)[33] = (float(*)[33])(smem + 98304 + ww * 8192);
                s0 += ep[jl][b]; s1 += ep[16 + jl][b]; s2 += ep[32 + jl][b];
            }
            float rr = sigmoidf_(gi0[rb] + s0 + bh0);
            float zz = sigmoidf_(gi1[rb] + s1 + bh1);
            float nn = tanhf(gi2[rb] + rr * (s2 + bh2));
            float hnew = (1.0f - zz) * nn + zz * hpv[rb];
            hpv[rb] = hnew;
            store_u16_sc(BG + ((size_t)(b * 64 + t)) * 1536 + je, f2bf(hnew));
        }

        if (t < 63) {
            asm volatile("s_waitcnt vmcnt(0)" ::: "memory");
            __syncthreads();
            if (tid == 0)
                __hip_atomic_store(&flags[jb], (unsigned)(t + 1),
                                   __ATOMIC_RELAXED, __HIP_MEMORY_SCOPE_AGENT);
            unsigned tgt = (unsigned)(t + 1);
            while (true) {
                unsigned v = __hip_atomic_load(&flags[lane],
                                               __ATOMIC_RELAXED, __HIP_MEMORY_SCOPE_AGENT);
                if (__all(v >= tgt)) break;
                __builtin_amdgcn_s_sleep(1);
            }
            __builtin_amdgcn_sched_barrier(0);
        }
    }
}

// ------------------------------------------------- per-row lse from partials
__global__ __launch_bounds__(256) void k_lse(const float* __restrict__ pmax,
                                             const float* __restrict__ psum,
                                             float* __restrict__ lse) {
    int n = blockIdx.x;
    int t = threadIdx.x;
    __shared__ float sm[256];
    const float* pm = pmax + (size_t)n * NTMP;
    const float* ps = psum + (size_t)n * NTMP;
    float m = -1e30f;
    for (int p = t; p < NTM; p += 256) m = fmaxf(m, pm[p]);
    sm[t] = m;
    __syncthreads();
    for (int s = 128; s > 0; s >>= 1) { if (t < s) sm[t] = fmaxf(sm[t], sm[t + s]); __syncthreads(); }
    m = sm[0];
    __syncthreads();
    float s = 0.0f;
    for (int p = t; p < NTM; p += 256) s += ps[p] * expf(pm[p] - m);
    sm[t] = s;
    __syncthreads();
    for (int r = 128; r > 0; r >>= 1) { if (t < r) sm[t] += sm[t + r]; __syncthreads(); }
    if (t == 0) lse[n] = m + logf(sm[0]);
}

// ------------------------------------------------- final combine (fully coalesced)
__global__ __launch_bounds__(256) void k_final(const u16* __restrict__ Lb,
                                               const unsigned char* __restrict__ g8,
                                               const float* __restrict__ lse,
                                               const float* __restrict__ ks,
                                               const float* __restrict__ lsek,
                                               float* __restrict__ out) {
    int n = blockIdx.y;
    int b = n >> 6;
    float lsen = lse[n], lkb = lsek[b];
    int base = blockIdx.x * 2048;
#pragma unroll
    for (int i = 0; i < 8; ++i) {
        int v = base + i * 256 + threadIdx.x;
        if (v < VOC) {
            float L = bf2f(Lb[(size_t)n * VOCP + v]);
            float g = g8[(size_t)n * VOCP2 + v] * (1.0f / 255.0f);
            float kp = ((v >= 10 && v < 10 + KSN) ? ks[(size_t)b * KSN + (v - 10)] : 0.0f) - lkb;
            out[(size_t)n * VOC + v] = g * (L - lsen) + (1.0f - g) * kp;
        }
    }
}

// ---------------------------------------------------------------- launch
extern "C" void kernel_launch(void* const* d_in, const int* in_sizes, int n_in,
                              void* d_out, int out_size, void* d_ws, size_t ws_size,
                              hipStream_t stream) {
    const float* ses    = (const float*)d_in[0];
    const float* know   = (const float*)d_in[1];
    const int*   target = (const int*)d_in[2];
    const float* embed  = (const float*)d_in[3];
    const float* Wih    = (const float*)d_in[4];
    const float* Whh    = (const float*)d_in[5];
    const float* bih    = (const float*)d_in[6];
    const float* bhh    = (const float*)d_in[7];
    const float* sdw    = (const float*)d_in[8];
    const float* sdb    = (const float*)d_in[9];
    const float* dw     = (const float*)d_in[10];
    const float* siw    = (const float*)d_in[11];
    const float* ew     = (const float*)d_in[12];
    const float* eb     = (const float*)d_in[13];
    const float* W1     = (const float*)d_in[14];
    const float* W2     = (const float*)d_in[15];
    const float* W3     = (const float*)d_in[16];
    const float* W4     = (const float*)d_in[17];
    const float* kvw    = (const float*)d_in[18];

    char* ws = (char*)d_ws;
    size_t o = 0;
    auto alloc = [&](size_t bytes) { char* r = ws + o; o += (bytes + 255) & ~(size_t)255; return r; };
    u16*   Aemb  = (u16*)  alloc((size_t)VOCP * 512 * 2);
    u16*   A34   = (u16*)  alloc((size_t)VOCP2 * 1536 * 2);
    u16*   Adwew = (u16*)  alloc((size_t)1024 * 1536 * 2);
    u16*   Wihb  = (u16*)  alloc((size_t)3072 * 512 * 2);
    u16*   WhhB  = (u16*)  alloc((size_t)3072 * 1024 * 2);
    u16*   h0b   = (u16*)  alloc((size_t)32 * 1024 * 2);
    u16*   BG    = (u16*)  alloc((size_t)2048 * 1536 * 2);
    u16*   BL    = (u16*)  alloc((size_t)2048 * 512 * 2);
    float* GI    = (float*)alloc((size_t)2048 * 3072 * 4);
    float* h0    = (float*)alloc((size_t)32 * 1024 * 4);
    float* sesinf= (float*)alloc((size_t)32 * 1024 * 4);
    float* gc    = (float*)alloc((size_t)32 * VOCP2 * 4);
    float* ksb   = (float*)alloc((size_t)32 * KSN * 4);
    float* lsek  = (float*)alloc(256);
    float* lse   = (float*)alloc((size_t)2048 * 4);
    unsigned* flags = (unsigned*)alloc(256);
    float* pmax  = (float*)alloc((size_t)2048 * NTMP * 4);
    float* psum  = (float*)alloc((size_t)2048 * NTMP * 4);
    unsigned char* g8 = (unsigned char*)alloc((size_t)2048 * VOCP2);
    u16*   Lb    = (u16*)  alloc((size_t)2048 * VOCP * 2);
    u16*   Bsk   = (u16*)  alloc((size_t)128 * 2048 * 2);
    float* out = (float*)d_out;

    hipMemsetAsync(flags, 0, 256, stream);

    // weight conversions (W1/W2/kvw no longer converted — consumed fp32 by k_sk32)
    k_cvt<<<dim3(VOC, 1), 256, 0, stream>>>(embed, Aemb, 512, 512, 512);
    k_cvt<<<dim3(VOC, 1), 256, 0, stream>>>(W3, A34, 1024, 1024, 1536);
    k_cvt<<<dim3(VOC, 1), 256, 0, stream>>>(W4, A34 + 1024, 512, 512, 1536);
    k_pad0<<<dim3(VOCP2 - VOC), 256, 0, stream>>>(Aemb, A34);
    k_cvt<<<dim3(1024, 1), 256, 0, stream>>>(dw, Adwew, 1024, 1024, 1536);
    k_cvt<<<dim3(1024, 1), 256, 0, stream>>>(ew, Adwew + 1024, 512, 512, 1536);
    k_cvt<<<dim3(3072, 1), 256, 0, stream>>>(Wih, Wihb, 512, 512, 512);
    k_cvt<<<dim3(3072, 1), 256, 0, stream>>>(Whh, WhhB, 1024, 1024, 1024);
    k_bsk<<<dim3(128), 256, 0, stream>>>(ses, know, Bsk);

    k_gather<<<dim3(2048), 128, 0, stream>>>(embed, target, BG);
    k_h0_sesinf<<<dim3(32), 256, 0, stream>>>(ses, sdw, sdb, siw, h0, sesinf);
    k_cvt<<<dim3(32, 1), 256, 0, stream>>>(h0, h0b, 1024, 1024, 1024);

    // gc = [ses|know]·[W1|W2]^T  (fp32-A skinny MFMA, VOCP2 stride)
    k_sk32<0><<<dim3(VOCP2 / 64), 128, 0, stream>>>(W1, W2, Bsk, gc);
    // ks = know·kvw^T
    k_sk32<1><<<dim3((KSN + 63) / 64), 128, 0, stream>>>(kvw, nullptr, Bsk, ksb);
    k_lseknow<<<dim3(32), 256, 0, stream>>>(ksb, lsek);

    // GI = TE @ Wih.T + bih
    gemm_bt<0><<<dim3(16, 24), 256, 0, stream>>>(Wihb, 512, BG + 1024, 1536, 512,
                                                 bih, nullptr, GI, nullptr, nullptr, nullptr);
    // GRU recurrence: persistent LDS-resident-weights MFMA kernel, fence-free barrier
    k_gru_m4<<<dim3(64), 256, 0, stream>>>(WhhB, GI, bhh, h0b, BG, flags);
    // MX (maxout) -> BL
    gemm_bt<1><<<dim3(16, 8), 256, 0, stream>>>(Adwew, 1536, BG, 1536, 1536,
                                                sesinf, eb, nullptr, BL, nullptr, nullptr);
    // gate GEMM -> g8  (256-tile, minimal-barrier 8-phase counted-vmcnt pipeline)
    gemm_gate8<<<dim3(1568), 512, 0, stream>>>(A34, BG, gc, g8);
    // logit GEMM -> Lb + partials
    gemm_bt<3><<<dim3(16, NTM), 256, 0, stream>>>(Aemb, 512, BL, 512, 512,
                                                  nullptr, nullptr, pmax, Lb, nullptr, psum);
    k_lse<<<dim3(2048), 256, 0, stream>>>(pmax, psum, lse);
    k_final<<<dim3(25, 2048), 256, 0, stream>>>(Lb, g8, lse, ksb, lsek, out);
}